// Round 1
// baseline (4013.464 us; speedup 1.0000x reference)
//
#include <hip/hip_runtime.h>
#include <stdint.h>

// ============================================================================
// DistributionLoss: sliced-Wasserstein pyramid loss, exact JAX-RNG replication.
// JAX_PARTITIONABLE=1 -> modern jax_threefry_partitionable=True semantics
// (default since jax 0.4.36). Set to 0 for the legacy "original" layout.
// ============================================================================
#define JAX_PARTITIONABLE 1

typedef unsigned int u32;
typedef unsigned long long u64;

// ---------------- threefry2x32 (20 rounds), matches jax exactly -------------
__device__ __forceinline__ uint2 tf2(uint2 k, u32 x0, u32 x1) {
  u32 ks0 = k.x, ks1 = k.y, ks2 = k.x ^ k.y ^ 0x1BD11BDAu;
  x0 += ks0; x1 += ks1;
#define TF_RND(R) { x0 += x1; x1 = (x1 << (R)) | (x1 >> (32 - (R))); x1 ^= x0; }
  TF_RND(13) TF_RND(15) TF_RND(26) TF_RND(6)
  x0 += ks1; x1 += ks2 + 1u;
  TF_RND(17) TF_RND(29) TF_RND(16) TF_RND(24)
  x0 += ks2; x1 += ks0 + 2u;
  TF_RND(13) TF_RND(15) TF_RND(26) TF_RND(6)
  x0 += ks0; x1 += ks1 + 3u;
  TF_RND(17) TF_RND(29) TF_RND(16) TF_RND(24)
  x0 += ks1; x1 += ks2 + 4u;
  TF_RND(13) TF_RND(15) TF_RND(26) TF_RND(6)
  x0 += ks2; x1 += ks0 + 5u;
#undef TF_RND
  return make_uint2(x0, x1);
}

// split(key, 3) -> kd, kw, kt
__device__ inline void split3(uint2 k, uint2* a, uint2* b, uint2* c) {
#if JAX_PARTITIONABLE
  *a = tf2(k, 0u, 0u); *b = tf2(k, 0u, 1u); *c = tf2(k, 0u, 2u);
#else
  uint2 p0 = tf2(k, 0u, 3u), p1 = tf2(k, 1u, 4u), p2 = tf2(k, 2u, 5u);
  // flat = [p0.x,p1.x,p2.x,p0.y,p1.y,p2.y] reshaped (3,2)
  *a = make_uint2(p0.x, p1.x); *b = make_uint2(p2.x, p0.y); *c = make_uint2(p1.y, p2.y);
#endif
}
// split(key) -> (new_key, subkey)
__device__ inline void split2(uint2 k, uint2* nk, uint2* sub) {
#if JAX_PARTITIONABLE
  *nk = tf2(k, 0u, 0u); *sub = tf2(k, 0u, 1u);
#else
  uint2 p0 = tf2(k, 0u, 2u), p1 = tf2(k, 1u, 3u);
  *nk = make_uint2(p0.x, p1.x); *sub = make_uint2(p0.y, p1.y);
#endif
}

// random_bits(key, 32, (192,)) element idx  (for normal(kd,(64,3)))
__device__ inline u32 normbits(uint2 kd, u32 idx) {
#if JAX_PARTITIONABLE
  uint2 o = tf2(kd, 0u, idx); return o.x ^ o.y;
#else
  if (idx < 96u) return tf2(kd, idx, idx + 96u).x;
  return tf2(kd, idx - 96u, idx).y;
#endif
}
// random_bits(subkey, 32, (n,)) element p (sort keys in permutation rounds)
__device__ inline u32 sortbits(uint2 sk, u32 p, u32 n) {
#if JAX_PARTITIONABLE
  uint2 o = tf2(sk, 0u, p); return o.x ^ o.y;
#else
  u32 h = n >> 1;
  if (p < h) return tf2(sk, p, p + h).x;
  return tf2(sk, p - h, p).y;
#endif
}

// ---------------- erfinv: Giles initial guess + 2 double Newton steps -------
__device__ inline double erfinv_d(double x) {
  double w = -log1p(-x * x);
  double p;
  if (w < 5.0) {
    w -= 2.5;
    p = 2.81022636e-08;
    p = 3.43273939e-07 + p * w;
    p = -3.5233877e-06 + p * w;
    p = -4.39150654e-06 + p * w;
    p = 0.00021858087 + p * w;
    p = -0.00125372503 + p * w;
    p = -0.00417768164 + p * w;
    p = 0.246640727 + p * w;
    p = 1.50140941 + p * w;
  } else {
    w = sqrt(w) - 3.0;
    p = -0.000200214257;
    p = 0.000100950558 + p * w;
    p = 0.00134934322 + p * w;
    p = -0.00367342844 + p * w;
    p = 0.00573950773 + p * w;
    p = -0.0076224613 + p * w;
    p = 0.00943887047 + p * w;
    p = 1.00167406 + p * w;
    p = 2.83297682 + p * w;
  }
  double y = p * x;
  for (int it = 0; it < 2; ++it) {
    double e = erf(y) - x;
    y -= e * 0.88622692545275801364 * exp(y * y);  // sqrt(pi)/2 * exp(y^2)
  }
  return y;
}

// ---------------- kernels ---------------------------------------------------

// keytab layout (uint2 entries):
//   [0..7]                 kd per level
//   [8 + (l-3)*6 + img*3 + r]  sort-round subkey (l=3..7, img 0/1, r 0..2)
__global__ void init_kernel(u32* hist, uint2* keytab) {
  for (int i = threadIdx.x; i < 8192; i += blockDim.x) hist[i] = 0u;
  if (threadIdx.x == 0) {
    uint2 base = make_uint2(0u, 42u);  // jax.random.key(42)
    for (int l = 0; l < 8; l++) {
      uint2 kl = tf2(base, 0u, (u32)l);  // fold_in(base, l)
      uint2 kd, kw, kt;
      split3(kl, &kd, &kw, &kt);
      keytab[l] = kd;
      if (l >= 3) {
        for (int img = 0; img < 2; img++) {
          uint2 kp = img ? kt : kw;
          for (int r = 0; r < 3; r++) {
            uint2 nk, sub;
            split2(kp, &nk, &sub);
            keytab[8 + (l - 3) * 6 + img * 3 + r] = sub;
            kp = nk;
          }
        }
      }
    }
  }
}

// directions: normal(kd,(64,3)) row-normalized; dirs[l][k][c]
__global__ void dirs_kernel(float* dirs, const uint2* keytab) {
  int t = threadIdx.x;  // 512 = 8 levels * 64 dirs
  int l = t >> 6, k = t & 63;
  uint2 kd = keytab[l];
  const float lo = -0.9999999403953552f;  // nextafterf(-1,0)
  float dv[3];
  for (int c = 0; c < 3; c++) {
    u32 idx = (u32)(k * 3 + c);
    u32 bits = normbits(kd, idx);
    float f = __uint_as_float((bits >> 9) | 0x3f800000u) - 1.0f;  // [0,1)
    float u = f * 2.0f + lo;           // (maxval-minval) rounds to 2.0f in f32
    if (u < lo) u = lo;
    float e = (float)erfinv_d((double)u);
    dv[c] = 1.4142135f * e;            // float32(sqrt(2)) * erfinv(u)
  }
  float nrm = sqrtf(dv[0] * dv[0] + dv[1] * dv[1] + dv[2] * dv[2]);
  for (int c = 0; c < 3; c++) dirs[l * 192 + k * 3 + c] = dv[c] / nrm;
}

__global__ void hist_kernel(u32* hist, const uint2* keytab, int subidx, u32 n, int BB) {
  __shared__ u32 lh[8192];
  int NB = 1 << BB;
  for (int i = threadIdx.x; i < NB; i += blockDim.x) lh[i] = 0u;
  __syncthreads();
  uint2 sk = keytab[subidx];
  u32 stride = gridDim.x * blockDim.x;
  for (u32 p = blockIdx.x * blockDim.x + threadIdx.x; p < n; p += stride) {
    u32 b = sortbits(sk, p, n) >> (32 - BB);
    atomicAdd(&lh[b], 1u);
  }
  __syncthreads();
  for (int i = threadIdx.x; i < NB; i += blockDim.x)
    if (lh[i]) atomicAdd(&hist[i], lh[i]);
}

// exclusive scan of hist[0..NB) -> base, cursor; zero hist for next pass.
__global__ void scan_kernel(u32* hist, u32* base, u32* cursor, int NB, u32 n) {
  __shared__ u32 part[1024];
  int tid = threadIdx.x;
  int chunk = (NB + 1023) >> 10;
  int s = tid * chunk, e = s + chunk;
  if (e > NB) e = NB;
  u32 sum = 0;
  for (int i = s; i < e; i++) sum += hist[i];
  part[tid] = sum;
  __syncthreads();
  for (int off = 1; off < 1024; off <<= 1) {
    u32 v = (tid >= off) ? part[tid - off] : 0u;
    __syncthreads();
    part[tid] += v;
    __syncthreads();
  }
  u32 run = part[tid] - sum;  // exclusive base of this thread's chunk
  for (int i = s; i < e; i++) {
    u32 h = hist[i];
    base[i] = run;
    cursor[i] = run;
    run += h;
    hist[i] = 0u;
  }
  if (tid == 0) base[NB] = n;
}

// scatter records rec[slot] = (low_bits << 2PB) | (p << PB) | v
__global__ void scatter_kernel(u64* rec, const u32* x, u32* cursor, const u32* base,
                               const uint2* keytab, int subidx, u32 n, int BB, int PB,
                               int round1, int sel) {
  u32 p = blockIdx.x * blockDim.x + threadIdx.x;
  if (p >= n) return;
  uint2 sk = keytab[subidx];
  u32 bits = sortbits(sk, p, n);
  u32 b = bits >> (32 - BB);
  if (sel && base[b] >= 4096u) return;  // rank >= 4096: not needed
  u32 v = round1 ? p : x[p];
  u32 low = bits & ((1u << (32 - BB)) - 1u);
  u64 key = ((u64)low << (2 * PB)) | ((u64)p << PB) | (u64)v;
  u32 slot = atomicAdd(&cursor[b], 1u);
  rec[slot] = key;
}

// per-bucket bitonic sort; write carried values in rank order.
__global__ void bucket_kernel(const u64* rec, const u32* base, u32* out, int PB,
                              int sel, u32 outcap) {
  __shared__ u64 kk[2048];
  u32 b = blockIdx.x;
  u32 s = base[b], e = base[b + 1];
  if (sel && s >= outcap) return;
  u32 m = e - s;
  if (m == 0) return;
  if (m > 2048u) m = 2048u;  // probabilistically impossible
  u32 S = 1;
  while (S < m) S <<= 1;
  for (u32 i = threadIdx.x; i < S; i += blockDim.x)
    kk[i] = (i < m) ? rec[s + i] : 0xFFFFFFFFFFFFFFFFull;
  __syncthreads();
  for (u32 k2 = 2; k2 <= S; k2 <<= 1) {
    for (u32 j = k2 >> 1; j > 0; j >>= 1) {
      for (u32 i = threadIdx.x; i < S; i += blockDim.x) {
        u32 ixj = i ^ j;
        if (ixj > i) {
          bool up = ((i & k2) == 0);
          u64 a = kk[i], c = kk[ixj];
          if ((a > c) == up) { kk[i] = c; kk[ixj] = a; }
        }
      }
      __syncthreads();
    }
  }
  u64 vmask = ((u64)1 << PB) - 1;
  for (u32 i = threadIdx.x; i < m; i += blockDim.x) {
    u32 q = s + i;
    if (sel && q >= outcap) continue;
    out[q] = (u32)(kk[i] & vmask);
  }
}

// gather sampled pixels (bilinear align_corners from the 2048x2048 source).
__global__ void gather_kernel(const float* wimg, const float* timg, const u32* idx,
                              float* pix) {
  int t = blockIdx.x * blockDim.x + threadIdx.x;  // 8*2*4096
  if (t >= 65536) return;
  int j = t & 4095;
  int img = (t >> 12) & 1;
  int l = t >> 13;
  int s = 16 << l;
  long long n = (long long)s * s;
  int M = (n < 4096) ? (int)n : 4096;
  if (j >= M) return;
  u32 p = (l < 3) ? (u32)j : idx[((l - 3) * 2 + img) * 4096 + j];
  const float* src = img ? timg : wimg;
  float o0, o1, o2;
  if (l == 7) {
    o0 = src[p];
    o1 = src[4194304 + p];
    o2 = src[8388608 + p];
  } else {
    u32 y = p / (u32)s, xq = p % (u32)s;
    float delta = 2047.0f / (float)(s - 1);
    float yc = (float)y * delta, xc = (float)xq * delta;
    int y0 = (int)floorf(yc); if (y0 > 2047) y0 = 2047;
    int x0 = (int)floorf(xc); if (x0 > 2047) x0 = 2047;
    int y1 = y0 + 1; if (y1 > 2047) y1 = 2047;
    int x1 = x0 + 1; if (x1 > 2047) x1 = 2047;
    float wy = yc - (float)y0, wx = xc - (float)x0;
    float out3[3];
    for (int c = 0; c < 3; c++) {
      const float* b = src + (size_t)c * 4194304;
      float v00 = b[y0 * 2048 + x0], v01 = b[y0 * 2048 + x1];
      float v10 = b[y1 * 2048 + x0], v11 = b[y1 * 2048 + x1];
      float r0 = v00 * (1.0f - wy) + v10 * wy;
      float r1 = v01 * (1.0f - wy) + v11 * wy;
      out3[c] = r0 * (1.0f - wx) + r1 * wx;
    }
    o0 = out3[0]; o1 = out3[1]; o2 = out3[2];
  }
  float* dst = pix + ((size_t)(l * 2 + img) * 4096 + j) * 3;
  dst[0] = o0; dst[1] = o1; dst[2] = o2;
}

// one block per (level, direction): project both images, sort, partial SSD.
__global__ void swd_kernel(const float* pix, const float* dirs, double* partials) {
  __shared__ float sw[4096];
  __shared__ float st[4096];
  __shared__ double red[256];
  int b = blockIdx.x;
  int l = b >> 6, k = b & 63;
  int s = 16 << l;
  long long nn = (long long)s * s;
  int M = (nn < 4096) ? (int)nn : 4096;
  int tid = threadIdx.x;        // 512
  int half = tid >> 8, t = tid & 255;
  float d0 = dirs[l * 192 + k * 3 + 0];
  float d1 = dirs[l * 192 + k * 3 + 1];
  float d2 = dirs[l * 192 + k * 3 + 2];
  float* A = half ? st : sw;
  const float* P = pix + (size_t)(l * 2 + half) * 4096 * 3;
  const float INF = __uint_as_float(0x7f800000u);
  for (int j = t; j < 4096; j += 256)
    A[j] = (j < M) ? (P[j * 3] * d0 + P[j * 3 + 1] * d1 + P[j * 3 + 2] * d2) : INF;
  __syncthreads();
  for (int k2 = 2; k2 <= 4096; k2 <<= 1) {
    for (int j = k2 >> 1; j > 0; j >>= 1) {
      for (int i = t; i < 4096; i += 256) {
        int ixj = i ^ j;
        if (ixj > i) {
          bool up = ((i & k2) == 0);
          float a = A[i], c = A[ixj];
          if ((a > c) == up) { A[i] = c; A[ixj] = a; }
        }
      }
      __syncthreads();
    }
  }
  if (half == 0) {
    double sum = 0.0;
    for (int j = t; j < M; j += 256) {
      double df = (double)sw[j] - (double)st[j];
      sum += df * df;
    }
    red[t] = sum;
  }
  __syncthreads();
  if (tid == 0) {
    double s2 = 0.0;
    for (int i = 0; i < 256; i++) s2 += red[i];
    partials[b] = s2;
  }
}

__global__ void final_kernel(const double* partials, float* out) {
  if (threadIdx.x == 0 && blockIdx.x == 0) {
    double tot = 0.0;
    for (int l = 0; l < 8; l++) {
      int s = 16 << l;
      long long nn = (long long)s * s;
      int M = (nn < 4096) ? (int)nn : 4096;
      double sm = 0.0;
      for (int k = 0; k < 64; k++) sm += partials[l * 64 + k];
      tot += sm / (64.0 * (double)M);
    }
    out[0] = (float)tot;
  }
}

// ---------------- launch -----------------------------------------------------
extern "C" void kernel_launch(void* const* d_in, const int* in_sizes, int n_in,
                              void* d_out, int out_size, void* d_ws, size_t ws_size,
                              hipStream_t stream) {
  const float* wimg = (const float*)d_in[0];
  const float* timg = (const float*)d_in[1];
  float* out = (float*)d_out;
  char* ws = (char*)d_ws;

  size_t off = 0;
  auto alloc = [&](size_t bytes) -> void* {
    void* p = ws + off;
    off = (off + bytes + 255) & ~(size_t)255;
    return p;
  };
  u64* rec    = (u64*)alloc(4194304ull * 8);   // 33.5 MB
  u32* xarr   = (u32*)alloc(4194304ull * 4);   // 16.8 MB
  u32* hist   = (u32*)alloc(8192 * 4);
  u32* basep  = (u32*)alloc(8200 * 4);
  u32* cur    = (u32*)alloc(8192 * 4);
  uint2* keyt = (uint2*)alloc(64 * 8);
  u32* idx    = (u32*)alloc(5ull * 2 * 4096 * 4);
  float* pix  = (float*)alloc(8ull * 2 * 4096 * 3 * 4);
  float* dirs = (float*)alloc(8ull * 64 * 3 * 4);
  double* part = (double*)alloc(512 * 8);
  (void)ws_size; (void)in_sizes; (void)n_in; (void)out_size;

  hipLaunchKernelGGL(init_kernel, dim3(1), dim3(256), 0, stream, hist, keyt);
  hipLaunchKernelGGL(dirs_kernel, dim3(1), dim3(512), 0, stream, dirs, keyt);

  for (int l = 3; l < 8; l++) {
    u32 s = 16u << l;
    u32 n = s * s;
    int PB = 2 * (l + 4);       // log2(n)
    int BB = PB - 9;            // avg 512 per bucket
    int NB = 1 << BB;
    int R = (l == 7) ? 3 : 2;   // ceil(3*ln(n)/ln(2^32-1))
    for (int img = 0; img < 2; img++) {
      for (int r = 1; r <= R; r++) {
        int sel = (r == R) ? 1 : 0;
        int subidx = 8 + (l - 3) * 6 + img * 3 + (r - 1);
        u32 hblocks = n / 4096; if (hblocks == 0) hblocks = 1;
        hipLaunchKernelGGL(hist_kernel, dim3(hblocks), dim3(256), 0, stream,
                           hist, keyt, subidx, n, BB);
        hipLaunchKernelGGL(scan_kernel, dim3(1), dim3(1024), 0, stream,
                           hist, basep, cur, NB, n);
        hipLaunchKernelGGL(scatter_kernel, dim3((n + 255) / 256), dim3(256), 0, stream,
                           rec, xarr, cur, basep, keyt, subidx, n, BB, PB,
                           (r == 1) ? 1 : 0, sel);
        u32* outp = sel ? (idx + ((size_t)(l - 3) * 2 + img) * 4096) : xarr;
        hipLaunchKernelGGL(bucket_kernel, dim3(NB), dim3(256), 0, stream,
                           rec, basep, outp, PB, sel, sel ? 4096u : n);
      }
    }
  }

  hipLaunchKernelGGL(gather_kernel, dim3(256), dim3(256), 0, stream,
                     wimg, timg, idx, pix);
  hipLaunchKernelGGL(swd_kernel, dim3(512), dim3(512), 0, stream, pix, dirs, part);
  hipLaunchKernelGGL(final_kernel, dim3(1), dim3(1), 0, stream, part, out);
}

// Round 2
// 2710.997 us; speedup vs baseline: 1.4804x; 1.4804x over previous
//
#include <hip/hip_runtime.h>
#include <stdint.h>

// ============================================================================
// DistributionLoss: SWD pyramid loss, exact JAX-RNG replication.
// Round 2: replace full permutation sorts with rank-inversion selection.
// ============================================================================
#define JAX_PARTITIONABLE 1

typedef unsigned int u32;
typedef unsigned long long u64;

#define HSLICES 8
#define HSTRIDE 32768       // per-slice histogram stride (>= max 2*NB)
#define RECCAP  4194304u    // rec capacity in u64 entries
#define CAP     512         // max bucket entries in rankfind

// ---------------- threefry2x32 (20 rounds), matches jax exactly -------------
__device__ __forceinline__ uint2 tf2(uint2 k, u32 x0, u32 x1) {
  u32 ks0 = k.x, ks1 = k.y, ks2 = k.x ^ k.y ^ 0x1BD11BDAu;
  x0 += ks0; x1 += ks1;
#define TF_RND(R) { x0 += x1; x1 = (x1 << (R)) | (x1 >> (32 - (R))); x1 ^= x0; }
  TF_RND(13) TF_RND(15) TF_RND(26) TF_RND(6)
  x0 += ks1; x1 += ks2 + 1u;
  TF_RND(17) TF_RND(29) TF_RND(16) TF_RND(24)
  x0 += ks2; x1 += ks0 + 2u;
  TF_RND(13) TF_RND(15) TF_RND(26) TF_RND(6)
  x0 += ks0; x1 += ks1 + 3u;
  TF_RND(17) TF_RND(29) TF_RND(16) TF_RND(24)
  x0 += ks1; x1 += ks2 + 4u;
  TF_RND(13) TF_RND(15) TF_RND(26) TF_RND(6)
  x0 += ks2; x1 += ks0 + 5u;
#undef TF_RND
  return make_uint2(x0, x1);
}

__device__ inline void split3(uint2 k, uint2* a, uint2* b, uint2* c) {
#if JAX_PARTITIONABLE
  *a = tf2(k, 0u, 0u); *b = tf2(k, 0u, 1u); *c = tf2(k, 0u, 2u);
#else
  uint2 p0 = tf2(k, 0u, 3u), p1 = tf2(k, 1u, 4u), p2 = tf2(k, 2u, 5u);
  *a = make_uint2(p0.x, p1.x); *b = make_uint2(p2.x, p0.y); *c = make_uint2(p1.y, p2.y);
#endif
}
__device__ inline void split2(uint2 k, uint2* nk, uint2* sub) {
#if JAX_PARTITIONABLE
  *nk = tf2(k, 0u, 0u); *sub = tf2(k, 0u, 1u);
#else
  uint2 p0 = tf2(k, 0u, 2u), p1 = tf2(k, 1u, 3u);
  *nk = make_uint2(p0.x, p1.x); *sub = make_uint2(p0.y, p1.y);
#endif
}
__device__ inline u32 normbits(uint2 kd, u32 idx) {
#if JAX_PARTITIONABLE
  uint2 o = tf2(kd, 0u, idx); return o.x ^ o.y;
#else
  if (idx < 96u) return tf2(kd, idx, idx + 96u).x;
  return tf2(kd, idx - 96u, idx).y;
#endif
}
__device__ inline u32 sortbits(uint2 sk, u32 p, u32 n) {
#if JAX_PARTITIONABLE
  uint2 o = tf2(sk, 0u, p); return o.x ^ o.y;
#else
  u32 h = n >> 1;
  if (p < h) return tf2(sk, p, p + h).x;
  return tf2(sk, p - h, p).y;
#endif
}

// ---------------- erfinv ----------------------------------------------------
__device__ inline double erfinv_d(double x) {
  double w = -log1p(-x * x);
  double p;
  if (w < 5.0) {
    w -= 2.5;
    p = 2.81022636e-08;
    p = 3.43273939e-07 + p * w;
    p = -3.5233877e-06 + p * w;
    p = -4.39150654e-06 + p * w;
    p = 0.00021858087 + p * w;
    p = -0.00125372503 + p * w;
    p = -0.00417768164 + p * w;
    p = 0.246640727 + p * w;
    p = 1.50140941 + p * w;
  } else {
    w = sqrt(w) - 3.0;
    p = -0.000200214257;
    p = 0.000100950558 + p * w;
    p = 0.00134934322 + p * w;
    p = -0.00367342844 + p * w;
    p = 0.00573950773 + p * w;
    p = -0.0076224613 + p * w;
    p = 0.00943887047 + p * w;
    p = 1.00167406 + p * w;
    p = 2.83297682 + p * w;
  }
  double y = p * x;
  for (int it = 0; it < 2; ++it) {
    double e = erf(y) - x;
    y -= e * 0.88622692545275801364 * exp(y * y);
  }
  return y;
}

// ---------------- kernels ---------------------------------------------------

// keytab: [0..7] kd per level; [8 + (l-3)*6 + img*3 + (r-1)] sort subkeys
__global__ void init_kernel(u32* hist, uint2* keytab) {
  for (int i = blockIdx.x * blockDim.x + threadIdx.x; i < HSLICES * HSTRIDE;
       i += gridDim.x * blockDim.x)
    hist[i] = 0u;
  if (blockIdx.x == 0 && threadIdx.x == 0) {
    uint2 base = make_uint2(0u, 42u);
    for (int l = 0; l < 8; l++) {
      uint2 kl = tf2(base, 0u, (u32)l);
      uint2 kd, kw, kt;
      split3(kl, &kd, &kw, &kt);
      keytab[l] = kd;
      if (l >= 3) {
        for (int img = 0; img < 2; img++) {
          uint2 kp = img ? kt : kw;
          for (int r = 0; r < 3; r++) {
            uint2 nk, sub;
            split2(kp, &nk, &sub);
            keytab[8 + (l - 3) * 6 + img * 3 + r] = sub;
            kp = nk;
          }
        }
      }
    }
  }
}

__global__ void dirs_kernel(float* dirs, const uint2* keytab) {
  int t = threadIdx.x;  // 512 = 8 levels * 64 dirs
  int l = t >> 6, k = t & 63;
  uint2 kd = keytab[l];
  const float lo = -0.9999999403953552f;
  float dv[3];
  for (int c = 0; c < 3; c++) {
    u32 bits = normbits(kd, (u32)(k * 3 + c));
    float f = __uint_as_float((bits >> 9) | 0x3f800000u) - 1.0f;
    float u = f * 2.0f + lo;
    if (u < lo) u = lo;
    dv[c] = 1.4142135f * (float)erfinv_d((double)u);
  }
  float nrm = sqrtf(dv[0] * dv[0] + dv[1] * dv[1] + dv[2] * dv[2]);
  for (int c = 0; c < 3; c++) dirs[l * 192 + k * 3 + c] = dv[c] / nrm;
}

// histogram of key high bits, sliced to reduce atomic contention
__global__ void hist_kernel(u32* hist, const uint2* keytab, int sub0, u32 n,
                            int BB, int NB) {
  int img = blockIdx.y;
  uint2 sk = keytab[sub0 + img * 3];
  u32* h = hist + (u32)(blockIdx.x & (HSLICES - 1)) * HSTRIDE + (u32)img * NB;
  u32 stride = gridDim.x * blockDim.x;
  for (u32 q = blockIdx.x * blockDim.x + threadIdx.x; q < n; q += stride) {
    u32 b = sortbits(sk, q, n) >> (32 - BB);
    atomicAdd(&h[b], 1u);
  }
}

// sum slices -> cnt, zero hist slices, zero flags
__global__ void reduce_kernel(u32* hist, u32* cnt, u32* flag, int NB2) {
  int i = blockIdx.x * blockDim.x + threadIdx.x;
  if (i >= NB2) return;
  u32 c = 0;
  for (int s = 0; s < HSLICES; s++) {
    c += hist[s * HSTRIDE + i];
    hist[s * HSTRIDE + i] = 0u;
  }
  cnt[i] = c;
  flag[i] = 0u;
}

// single block: scan cnt -> per-image base (LDS); locate target ranks -> bucket,
// local rank; flag buckets; compact-scan flagged counts -> cbase/cur.
__global__ void __launch_bounds__(1024) plan_kernel(
    const u32* cnt, u32* flag, u32* cbase, u32* cur, const u32* T, u32* tb,
    u32* lrarr, int NB, u32 n, int first) {
  __shared__ u32 sBase[32768];
  __shared__ u32 part[1024];
  int NB2 = 2 * NB;
  int tid = threadIdx.x;
  int chunk = (NB2 + 1023) >> 10;
  int s = tid * chunk, e = s + chunk;
  if (e > NB2) e = NB2;
  if (s > NB2) s = NB2;
  // phase 1: exclusive scan of cnt into sBase (per-image adjusted)
  u32 sum = 0;
  for (int i = s; i < e; i++) sum += cnt[i];
  part[tid] = sum;
  __syncthreads();
  for (int off = 1; off < 1024; off <<= 1) {
    u32 v = (tid >= off) ? part[tid - off] : 0u;
    __syncthreads();
    part[tid] += v;
    __syncthreads();
  }
  u32 run = part[tid] - sum;
  for (int i = s; i < e; i++) {
    sBase[i] = run - ((i >= NB) ? n : 0u);
    run += cnt[i];
  }
  __syncthreads();
  // phase 2: per-target binary search
  for (int r = tid; r < 8192; r += 1024) {
    int img = r >> 12;
    u32 t = first ? (u32)(r & 4095) : T[r];
    const u32* B = sBase + img * NB;
    int lo = 0, hi = NB - 1;
    while (lo < hi) {
      int mid = (lo + hi + 1) >> 1;
      lo = (B[mid] <= t) ? mid : lo;
      hi = (B[mid] <= t) ? hi : (mid - 1);
    }
    tb[r] = (u32)(img * NB + lo);
    lrarr[r] = t - B[lo];
    flag[img * NB + lo] = 1u;
  }
  __syncthreads();
  // phase 3: compact exclusive scan over flagged bucket counts
  u32 vs = 0;
  for (int i = s; i < e; i++) vs += flag[i] ? cnt[i] : 0u;
  part[tid] = vs;
  __syncthreads();
  for (int off = 1; off < 1024; off <<= 1) {
    u32 v = (tid >= off) ? part[tid - off] : 0u;
    __syncthreads();
    part[tid] += v;
    __syncthreads();
  }
  u32 run2 = part[tid] - vs;
  for (int i = s; i < e; i++) {
    cbase[i] = run2;
    cur[i] = run2;
    run2 += flag[i] ? cnt[i] : 0u;
  }
}

// scatter (key, position) of flagged buckets into compact per-bucket storage
__global__ void scatter2_kernel(u64* rec, u32* cur, const u32* flag,
                                const uint2* keytab, int sub0, u32 n, int BB,
                                int NB) {
  int img = blockIdx.y;
  uint2 sk = keytab[sub0 + img * 3];
  u32 stride = gridDim.x * blockDim.x;
  for (u32 q = blockIdx.x * blockDim.x + threadIdx.x; q < n; q += stride) {
    u32 bits = sortbits(sk, q, n);
    u32 gb = (u32)img * NB + (bits >> (32 - BB));
    if (!flag[gb]) continue;
    u32 slot = atomicAdd(&cur[gb], 1u);
    if (slot < RECCAP) rec[slot] = ((u64)bits << 32) | (u64)q;
  }
}

// one block per target: find element with local rank lr in its bucket
__global__ void __launch_bounds__(256) rankfind_kernel(
    const u64* rec, const u32* tb, const u32* lrarr, const u32* cbase,
    const u32* cur, u32* out) {
  __shared__ u64 kk[CAP];
  int r = blockIdx.x;
  u32 gb = tb[r];
  u32 s0 = cbase[gb];
  u32 m = cur[gb] - s0;
  if (m > CAP) m = CAP;
  for (u32 i = threadIdx.x; i < m; i += blockDim.x) kk[i] = rec[s0 + i];
  __syncthreads();
  u32 lr = lrarr[r];
  for (u32 i = threadIdx.x; i < m; i += blockDim.x) {
    u64 me = kk[i];
    u32 c = 0;
    for (u32 j = 0; j < m; j++) c += (kk[j] < me) ? 1u : 0u;
    if (c == lr) out[r] = (u32)(me & 0xffffffffu);
  }
}

// gather sampled pixels (bilinear align_corners from 2048x2048 source)
__global__ void gather_kernel(const float* wimg, const float* timg,
                              const u32* idx, float* pix) {
  int t = blockIdx.x * blockDim.x + threadIdx.x;
  if (t >= 65536) return;
  int j = t & 4095;
  int img = (t >> 12) & 1;
  int l = t >> 13;
  int s = 16 << l;
  long long n = (long long)s * s;
  int M = (n < 4096) ? (int)n : 4096;
  if (j >= M) return;
  u32 p = (l < 3) ? (u32)j : idx[((l - 3) * 2 + img) * 4096 + j];
  const float* src = img ? timg : wimg;
  float o0, o1, o2;
  if (l == 7) {
    o0 = src[p];
    o1 = src[4194304 + p];
    o2 = src[8388608 + p];
  } else {
    u32 y = p / (u32)s, xq = p % (u32)s;
    float delta = 2047.0f / (float)(s - 1);
    float yc = (float)y * delta, xc = (float)xq * delta;
    int y0 = (int)floorf(yc); if (y0 > 2047) y0 = 2047;
    int x0 = (int)floorf(xc); if (x0 > 2047) x0 = 2047;
    int y1 = y0 + 1; if (y1 > 2047) y1 = 2047;
    int x1 = x0 + 1; if (x1 > 2047) x1 = 2047;
    float wy = yc - (float)y0, wx = xc - (float)x0;
    float out3[3];
    for (int c = 0; c < 3; c++) {
      const float* b = src + (size_t)c * 4194304;
      float v00 = b[y0 * 2048 + x0], v01 = b[y0 * 2048 + x1];
      float v10 = b[y1 * 2048 + x0], v11 = b[y1 * 2048 + x1];
      float r0 = v00 * (1.0f - wy) + v10 * wy;
      float r1 = v01 * (1.0f - wy) + v11 * wy;
      out3[c] = r0 * (1.0f - wx) + r1 * wx;
    }
    o0 = out3[0]; o1 = out3[1]; o2 = out3[2];
  }
  float* dst = pix + ((size_t)(l * 2 + img) * 4096 + j) * 3;
  dst[0] = o0; dst[1] = o1; dst[2] = o2;
}

// one block per (level, direction): project, bitonic sort, partial SSD
__global__ void swd_kernel(const float* pix, const float* dirs, double* partials) {
  __shared__ float sw[4096];
  __shared__ float st[4096];
  __shared__ double red[256];
  int b = blockIdx.x;
  int l = b >> 6, k = b & 63;
  int s = 16 << l;
  long long nn = (long long)s * s;
  int M = (nn < 4096) ? (int)nn : 4096;
  int tid = threadIdx.x;  // 512
  int half = tid >> 8, t = tid & 255;
  float d0 = dirs[l * 192 + k * 3 + 0];
  float d1 = dirs[l * 192 + k * 3 + 1];
  float d2 = dirs[l * 192 + k * 3 + 2];
  float* A = half ? st : sw;
  const float* P = pix + (size_t)(l * 2 + half) * 4096 * 3;
  const float INF = __uint_as_float(0x7f800000u);
  for (int j = t; j < 4096; j += 256)
    A[j] = (j < M) ? (P[j * 3] * d0 + P[j * 3 + 1] * d1 + P[j * 3 + 2] * d2) : INF;
  __syncthreads();
  for (int k2 = 2; k2 <= 4096; k2 <<= 1) {
    for (int j = k2 >> 1; j > 0; j >>= 1) {
      for (int i = t; i < 4096; i += 256) {
        int ixj = i ^ j;
        if (ixj > i) {
          bool up = ((i & k2) == 0);
          float a = A[i], c = A[ixj];
          if ((a > c) == up) { A[i] = c; A[ixj] = a; }
        }
      }
      __syncthreads();
    }
  }
  if (half == 0) {
    double sum = 0.0;
    for (int j = t; j < M; j += 256) {
      double df = (double)sw[j] - (double)st[j];
      sum += df * df;
    }
    red[t] = sum;
  }
  __syncthreads();
  if (tid == 0) {
    double s2 = 0.0;
    for (int i = 0; i < 256; i++) s2 += red[i];
    partials[b] = s2;
  }
}

__global__ void final_kernel(const double* partials, float* out) {
  if (threadIdx.x == 0 && blockIdx.x == 0) {
    double tot = 0.0;
    for (int l = 0; l < 8; l++) {
      int s = 16 << l;
      long long nn = (long long)s * s;
      int M = (nn < 4096) ? (int)nn : 4096;
      double sm = 0.0;
      for (int k = 0; k < 64; k++) sm += partials[l * 64 + k];
      tot += sm / (64.0 * (double)M);
    }
    out[0] = (float)tot;
  }
}

// ---------------- launch -----------------------------------------------------
extern "C" void kernel_launch(void* const* d_in, const int* in_sizes, int n_in,
                              void* d_out, int out_size, void* d_ws, size_t ws_size,
                              hipStream_t stream) {
  const float* wimg = (const float*)d_in[0];
  const float* timg = (const float*)d_in[1];
  float* out = (float*)d_out;
  char* ws = (char*)d_ws;

  size_t off = 0;
  auto alloc = [&](size_t bytes) -> void* {
    void* p = ws + off;
    off = (off + bytes + 255) & ~(size_t)255;
    return p;
  };
  u64* rec    = (u64*)alloc((size_t)RECCAP * 8);        // 33.5 MB
  u32* hist   = (u32*)alloc((size_t)HSLICES * HSTRIDE * 4);  // 1 MB
  u32* cnt    = (u32*)alloc(32768 * 4);
  u32* flag   = (u32*)alloc(32768 * 4);
  u32* cbase  = (u32*)alloc(32768 * 4);
  u32* cur    = (u32*)alloc(32768 * 4);
  uint2* keyt = (uint2*)alloc(64 * 8);
  u32* T      = (u32*)alloc(8192 * 4);
  u32* tb     = (u32*)alloc(8192 * 4);
  u32* lrarr  = (u32*)alloc(8192 * 4);
  u32* idx    = (u32*)alloc(5ull * 8192 * 4);
  float* pix  = (float*)alloc(8ull * 2 * 4096 * 3 * 4);
  float* dirs = (float*)alloc(8ull * 64 * 3 * 4);
  double* part = (double*)alloc(512 * 8);
  (void)ws_size; (void)in_sizes; (void)n_in; (void)out_size;

  hipLaunchKernelGGL(init_kernel, dim3(64), dim3(256), 0, stream, hist, keyt);
  hipLaunchKernelGGL(dirs_kernel, dim3(1), dim3(512), 0, stream, dirs, keyt);

  for (int l = 3; l < 8; l++) {
    u32 sdim = 16u << l;
    u32 n = sdim * sdim;
    int log2n = 2 * (l + 4);
    int BB = log2n - 7;
    if (BB > 14) BB = 14;
    int NB = 1 << BB, NB2 = 2 * NB;
    int R = (l == 7) ? 3 : 2;
    u32 nbx = n / 4096;
    if (nbx > 512) nbx = 512;
    if (nbx == 0) nbx = 1;
    for (int jr = R; jr >= 1; jr--) {
      int first = (jr == R) ? 1 : 0;
      int sub0 = 8 + (l - 3) * 6 + (jr - 1);
      hipLaunchKernelGGL(hist_kernel, dim3(nbx, 2), dim3(256), 0, stream,
                         hist, keyt, sub0, n, BB, NB);
      hipLaunchKernelGGL(reduce_kernel, dim3((NB2 + 255) / 256), dim3(256), 0,
                         stream, hist, cnt, flag, NB2);
      hipLaunchKernelGGL(plan_kernel, dim3(1), dim3(1024), 0, stream,
                         cnt, flag, cbase, cur, T, tb, lrarr, NB, n, first);
      hipLaunchKernelGGL(scatter2_kernel, dim3(nbx, 2), dim3(256), 0, stream,
                         rec, cur, flag, keyt, sub0, n, BB, NB);
      u32* outp = (jr == 1) ? (idx + (size_t)(l - 3) * 8192) : T;
      hipLaunchKernelGGL(rankfind_kernel, dim3(8192), dim3(256), 0, stream,
                         rec, tb, lrarr, cbase, cur, outp);
    }
  }

  hipLaunchKernelGGL(gather_kernel, dim3(256), dim3(256), 0, stream,
                     wimg, timg, idx, pix);
  hipLaunchKernelGGL(swd_kernel, dim3(512), dim3(512), 0, stream, pix, dirs, part);
  hipLaunchKernelGGL(final_kernel, dim3(1), dim3(1), 0, stream, part, out);
}

// Round 3
// 2279.102 us; speedup vs baseline: 1.7610x; 1.1895x over previous
//
#include <hip/hip_runtime.h>
#include <stdint.h>

// ============================================================================
// DistributionLoss: SWD pyramid loss, exact JAX-RNG replication.
// Round 3: zero-global-atomic selection pipeline (histmat rows + colscan +
// LDS-cursor scatter), O(m) sub-radix rankfind, single-dispatch L3.
// ============================================================================
#define JAX_PARTITIONABLE 1

typedef unsigned int u32;
typedef unsigned long long u64;

#define RECCAP  4194304u    // rec capacity (u64 entries)
#define CAP     512         // max bucket entries in rankfind
#define MAXNB   16384       // max buckets per image (64KB LDS)

// ---------------- threefry2x32 (20 rounds), matches jax exactly -------------
__device__ __forceinline__ uint2 tf2(uint2 k, u32 x0, u32 x1) {
  u32 ks0 = k.x, ks1 = k.y, ks2 = k.x ^ k.y ^ 0x1BD11BDAu;
  x0 += ks0; x1 += ks1;
#define TF_RND(R) { x0 += x1; x1 = (x1 << (R)) | (x1 >> (32 - (R))); x1 ^= x0; }
  TF_RND(13) TF_RND(15) TF_RND(26) TF_RND(6)
  x0 += ks1; x1 += ks2 + 1u;
  TF_RND(17) TF_RND(29) TF_RND(16) TF_RND(24)
  x0 += ks2; x1 += ks0 + 2u;
  TF_RND(13) TF_RND(15) TF_RND(26) TF_RND(6)
  x0 += ks0; x1 += ks1 + 3u;
  TF_RND(17) TF_RND(29) TF_RND(16) TF_RND(24)
  x0 += ks1; x1 += ks2 + 4u;
  TF_RND(13) TF_RND(15) TF_RND(26) TF_RND(6)
  x0 += ks2; x1 += ks0 + 5u;
#undef TF_RND
  return make_uint2(x0, x1);
}

__device__ inline void split3(uint2 k, uint2* a, uint2* b, uint2* c) {
#if JAX_PARTITIONABLE
  *a = tf2(k, 0u, 0u); *b = tf2(k, 0u, 1u); *c = tf2(k, 0u, 2u);
#else
  uint2 p0 = tf2(k, 0u, 3u), p1 = tf2(k, 1u, 4u), p2 = tf2(k, 2u, 5u);
  *a = make_uint2(p0.x, p1.x); *b = make_uint2(p2.x, p0.y); *c = make_uint2(p1.y, p2.y);
#endif
}
__device__ inline void split2(uint2 k, uint2* nk, uint2* sub) {
#if JAX_PARTITIONABLE
  *nk = tf2(k, 0u, 0u); *sub = tf2(k, 0u, 1u);
#else
  uint2 p0 = tf2(k, 0u, 2u), p1 = tf2(k, 1u, 3u);
  *nk = make_uint2(p0.x, p1.x); *sub = make_uint2(p0.y, p1.y);
#endif
}
__device__ inline u32 normbits(uint2 kd, u32 idx) {
#if JAX_PARTITIONABLE
  uint2 o = tf2(kd, 0u, idx); return o.x ^ o.y;
#else
  if (idx < 96u) return tf2(kd, idx, idx + 96u).x;
  return tf2(kd, idx - 96u, idx).y;
#endif
}
__device__ inline u32 sortbits(uint2 sk, u32 p, u32 n) {
#if JAX_PARTITIONABLE
  uint2 o = tf2(sk, 0u, p); return o.x ^ o.y;
#else
  u32 h = n >> 1;
  if (p < h) return tf2(sk, p, p + h).x;
  return tf2(sk, p - h, p).y;
#endif
}

// ---------------- erfinv ----------------------------------------------------
__device__ inline double erfinv_d(double x) {
  double w = -log1p(-x * x);
  double p;
  if (w < 5.0) {
    w -= 2.5;
    p = 2.81022636e-08;
    p = 3.43273939e-07 + p * w;
    p = -3.5233877e-06 + p * w;
    p = -4.39150654e-06 + p * w;
    p = 0.00021858087 + p * w;
    p = -0.00125372503 + p * w;
    p = -0.00417768164 + p * w;
    p = 0.246640727 + p * w;
    p = 1.50140941 + p * w;
  } else {
    w = sqrt(w) - 3.0;
    p = -0.000200214257;
    p = 0.000100950558 + p * w;
    p = 0.00134934322 + p * w;
    p = -0.00367342844 + p * w;
    p = 0.00573950773 + p * w;
    p = -0.0076224613 + p * w;
    p = 0.00943887047 + p * w;
    p = 1.00167406 + p * w;
    p = 2.83297682 + p * w;
  }
  double y = p * x;
  for (int it = 0; it < 2; ++it) {
    double e = erf(y) - x;
    y -= e * 0.88622692545275801364 * exp(y * y);
  }
  return y;
}

// ---------------- kernels ---------------------------------------------------

// keytab: [0..7] kd per level; [8 + (l-3)*6 + img*3 + (r-1)] sort subkeys
__global__ void init_kernel(uint2* keytab) {
  if (threadIdx.x == 0) {
    uint2 base = make_uint2(0u, 42u);
    for (int l = 0; l < 8; l++) {
      uint2 kl = tf2(base, 0u, (u32)l);
      uint2 kd, kw, kt;
      split3(kl, &kd, &kw, &kt);
      keytab[l] = kd;
      if (l >= 3) {
        for (int img = 0; img < 2; img++) {
          uint2 kp = img ? kt : kw;
          for (int r = 0; r < 3; r++) {
            uint2 nk, sub;
            split2(kp, &nk, &sub);
            keytab[8 + (l - 3) * 6 + img * 3 + r] = sub;
            kp = nk;
          }
        }
      }
    }
  }
}

__global__ void dirs_kernel(float* dirs, const uint2* keytab) {
  int t = threadIdx.x;  // 512 = 8 levels * 64 dirs
  int l = t >> 6, k = t & 63;
  uint2 kd = keytab[l];
  const float lo = -0.9999999403953552f;
  float dv[3];
  for (int c = 0; c < 3; c++) {
    u32 bits = normbits(kd, (u32)(k * 3 + c));
    float f = __uint_as_float((bits >> 9) | 0x3f800000u) - 1.0f;
    float u = f * 2.0f + lo;
    if (u < lo) u = lo;
    dv[c] = 1.4142135f * (float)erfinv_d((double)u);
  }
  float nrm = sqrtf(dv[0] * dv[0] + dv[1] * dv[1] + dv[2] * dv[2]);
  for (int c = 0; c < 3; c++) dirs[l * 192 + k * 3 + c] = dv[c] / nrm;
}

// per-block LDS histogram, flushed to a private row of histmat (no atomics)
__global__ void __launch_bounds__(256) hist_kernel(
    u32* histmat, const uint2* keytab, int sub0, u32 n, int BB, int NB,
    int NB2, u32 chunk) {
  __shared__ u32 lh[MAXNB];
  int blk = blockIdx.x, img = blockIdx.y;
  for (int b = threadIdx.x; b < NB; b += 256) lh[b] = 0u;
  __syncthreads();
  uint2 sk = keytab[sub0 + img * 3];
  u32 q0 = (u32)blk * chunk, q1 = q0 + chunk;
  if (q1 > n) q1 = n;
  for (u32 q = q0 + threadIdx.x; q < q1; q += 256) {
    u32 b = sortbits(sk, q, n) >> (32 - BB);
    atomicAdd(&lh[b], 1u);
  }
  __syncthreads();
  u32* row = histmat + (size_t)blk * NB2 + (size_t)img * NB;
  for (int b = threadIdx.x; b < NB; b += 256) row[b] = lh[b];
}

// per-bucket exclusive scan across blocks -> offT; totals -> cnt (coalesced)
__global__ void __launch_bounds__(256) colscan_kernel(
    const u32* histmat, u32* offT, u32* cnt, int NB2, int nblk) {
  int gb = blockIdx.x * 256 + threadIdx.x;
  if (gb >= NB2) return;
  u32 run = 0;
  for (int blk = 0; blk < nblk; blk++) {
    offT[(size_t)blk * NB2 + gb] = run;
    run += histmat[(size_t)blk * NB2 + gb];
  }
  cnt[gb] = run;
}

// single block: rank-scan cnt, locate targets, flag buckets (bit31 of sBase),
// compact-scan flagged -> fbase (0xFFFFFFFF sentinel for unflagged).
__global__ void __launch_bounds__(1024) plan_kernel(
    const u32* cnt, u32* fbase, const u32* T, u32* tb, u32* lrarr,
    int NB, u32 n, int first) {
  __shared__ u32 sBase[2 * MAXNB];   // 128KB (gfx950 LDS = 160KB)
  __shared__ u32 part[1024];
  const u32 MASK = 0x7fffffffu;
  int NB2 = 2 * NB;
  int tid = threadIdx.x;
  int chunk = (NB2 + 1023) >> 10;
  int s = tid * chunk, e = s + chunk;
  if (e > NB2) e = NB2;
  if (s > NB2) s = NB2;
  // phase 1: exclusive scan of cnt into sBase (per-image adjusted)
  u32 sum = 0;
  for (int i = s; i < e; i++) sum += cnt[i];
  part[tid] = sum;
  __syncthreads();
  for (int off = 1; off < 1024; off <<= 1) {
    u32 v = (tid >= off) ? part[tid - off] : 0u;
    __syncthreads();
    part[tid] += v;
    __syncthreads();
  }
  u32 run = part[tid] - sum;
  for (int i = s; i < e; i++) {
    sBase[i] = run - ((i >= NB) ? n : 0u);
    run += cnt[i];
  }
  __syncthreads();
  // phase 2: per-target binary search; flag bucket via bit31
  for (int r = tid; r < 8192; r += 1024) {
    int img = r >> 12;
    u32 t = first ? (u32)(r & 4095) : T[r];
    const u32* B = sBase + img * NB;
    int lo = 0, hi = NB - 1;
    while (lo < hi) {
      int mid = (lo + hi + 1) >> 1;
      if ((B[mid] & MASK) <= t) lo = mid; else hi = mid - 1;
    }
    tb[r] = (u32)(img * NB + lo);
    lrarr[r] = t - (B[lo] & MASK);
    atomicOr(&sBase[img * NB + lo], 0x80000000u);
  }
  __syncthreads();
  // phase 3: compact exclusive scan over flagged bucket counts -> fbase
  u32 vs = 0;
  for (int i = s; i < e; i++) vs += (sBase[i] >> 31) ? cnt[i] : 0u;
  part[tid] = vs;
  __syncthreads();
  for (int off = 1; off < 1024; off <<= 1) {
    u32 v = (tid >= off) ? part[tid - off] : 0u;
    __syncthreads();
    part[tid] += v;
    __syncthreads();
  }
  u32 run2 = part[tid] - vs;
  for (int i = s; i < e; i++) {
    if (sBase[i] >> 31) {
      fbase[i] = run2;
      run2 += cnt[i];
    } else {
      fbase[i] = 0xFFFFFFFFu;
    }
  }
}

// scatter flagged-bucket elements to compact storage via LDS cursors only
__global__ void __launch_bounds__(256) scatter_kernel(
    u64* rec, const u32* offT, const u32* fbase, const uint2* keytab,
    int sub0, u32 n, int BB, int NB, int NB2, u32 chunk) {
  __shared__ u32 cursor[MAXNB];
  int blk = blockIdx.x, img = blockIdx.y;
  const u32* orow = offT + (size_t)blk * NB2 + (size_t)img * NB;
  const u32* frow = fbase + (size_t)img * NB;
  for (int b = threadIdx.x; b < NB; b += 256) {
    u32 fb = frow[b];
    cursor[b] = (fb == 0xFFFFFFFFu) ? 0xFFFFFFFFu : fb + orow[b];
  }
  __syncthreads();
  uint2 sk = keytab[sub0 + img * 3];
  u32 q0 = (u32)blk * chunk, q1 = q0 + chunk;
  if (q1 > n) q1 = n;
  for (u32 q = q0 + threadIdx.x; q < q1; q += 256) {
    u32 bits = sortbits(sk, q, n);
    u32 b = bits >> (32 - BB);
    if (cursor[b] != 0xFFFFFFFFu) {
      u32 slot = atomicAdd(&cursor[b], 1u);
      if (slot < RECCAP) rec[slot] = ((u64)bits << 32) | (u64)q;
    }
  }
}

// one block per target: O(m) sub-radix rank find within bucket
__global__ void __launch_bounds__(256) rankfind_kernel(
    const u64* rec, const u32* tb, const u32* lrarr, const u32* fbase,
    const u32* cnt, u32* out, int BB) {
  __shared__ u64 kk[CAP];
  __shared__ u32 sh[256];
  __shared__ u32 ssb;
  __shared__ u32 sexcl;
  int r = blockIdx.x;
  int tid = threadIdx.x;
  u32 gb = tb[r];
  u32 lr = lrarr[r];
  u32 s0 = fbase[gb];
  u32 m = cnt[gb];
  if (m > CAP) m = CAP;
  int shamt = 24 - BB;  // sub-byte just below bucket bits
  for (u32 i = tid; i < m; i += 256) kk[i] = rec[s0 + i];
  sh[tid] = 0u;
  __syncthreads();
  for (u32 i = tid; i < m; i += 256)
    atomicAdd(&sh[((u32)(kk[i] >> 32) >> shamt) & 255u], 1u);
  __syncthreads();
  // inclusive scan over 256 entries
  u32 own = sh[tid];
  for (int off = 1; off < 256; off <<= 1) {
    u32 v = (tid >= off) ? sh[tid - off] : 0u;
    __syncthreads();
    sh[tid] += v;
    __syncthreads();
  }
  u32 incl = sh[tid];
  u32 excl = incl - own;
  if (own > 0u && excl <= lr && lr < incl) { ssb = (u32)tid; sexcl = excl; }
  __syncthreads();
  u32 sb = ssb;
  u32 lr2 = lr - sexcl;
  for (u32 i = tid; i < m; i += 256) {
    if ((((u32)(kk[i] >> 32) >> shamt) & 255u) == sb) {
      u64 me = kk[i];
      u32 c = 0;
      for (u32 j = 0; j < m; j++) {
        u64 kj = kk[j];
        if (((((u32)(kj >> 32)) >> shamt) & 255u) == sb && kj < me) c++;
      }
      if (c == lr2) out[r] = (u32)(me & 0xffffffffu);
    }
  }
}

// L3 (n=16384): both permutation rounds via full in-LDS bitonic sorts
__global__ void __launch_bounds__(1024) l3_kernel(const uint2* keytab, u32* idx) {
  __shared__ u64 arr[16384];  // 128KB
  __shared__ u32 sT[4096];    // 16KB
  int img = blockIdx.x;
  int tid = threadIdx.x;
  const u32 n = 16384u;
  for (int jr = 2; jr >= 1; jr--) {
    uint2 sk = keytab[8 + img * 3 + (jr - 1)];
    for (u32 i = tid; i < n; i += 1024)
      arr[i] = ((u64)sortbits(sk, i, n) << 32) | (u64)i;
    __syncthreads();
    for (u32 k2 = 2; k2 <= n; k2 <<= 1) {
      for (u32 j = k2 >> 1; j > 0; j >>= 1) {
        for (u32 i = tid; i < n; i += 1024) {
          u32 ixj = i ^ j;
          if (ixj > i) {
            bool up = ((i & k2) == 0);
            u64 a = arr[i], c = arr[ixj];
            if ((a > c) == up) { arr[i] = c; arr[ixj] = a; }
          }
        }
        __syncthreads();
      }
    }
    if (jr == 2) {
      for (int r2 = tid; r2 < 4096; r2 += 1024) sT[r2] = (u32)arr[r2];
    } else {
      for (int r2 = tid; r2 < 4096; r2 += 1024)
        idx[img * 4096 + r2] = (u32)arr[sT[r2]];
    }
    __syncthreads();
  }
}

// gather sampled pixels (bilinear align_corners from 2048x2048 source)
__global__ void gather_kernel(const float* wimg, const float* timg,
                              const u32* idx, float* pix) {
  int t = blockIdx.x * blockDim.x + threadIdx.x;
  if (t >= 65536) return;
  int j = t & 4095;
  int img = (t >> 12) & 1;
  int l = t >> 13;
  int s = 16 << l;
  long long n = (long long)s * s;
  int M = (n < 4096) ? (int)n : 4096;
  if (j >= M) return;
  u32 p = (l < 3) ? (u32)j : idx[((l - 3) * 2 + img) * 4096 + j];
  const float* src = img ? timg : wimg;
  float o0, o1, o2;
  if (l == 7) {
    o0 = src[p];
    o1 = src[4194304 + p];
    o2 = src[8388608 + p];
  } else {
    u32 y = p / (u32)s, xq = p % (u32)s;
    float delta = 2047.0f / (float)(s - 1);
    float yc = (float)y * delta, xc = (float)xq * delta;
    int y0 = (int)floorf(yc); if (y0 > 2047) y0 = 2047;
    int x0 = (int)floorf(xc); if (x0 > 2047) x0 = 2047;
    int y1 = y0 + 1; if (y1 > 2047) y1 = 2047;
    int x1 = x0 + 1; if (x1 > 2047) x1 = 2047;
    float wy = yc - (float)y0, wx = xc - (float)x0;
    float out3[3];
    for (int c = 0; c < 3; c++) {
      const float* b = src + (size_t)c * 4194304;
      float v00 = b[y0 * 2048 + x0], v01 = b[y0 * 2048 + x1];
      float v10 = b[y1 * 2048 + x0], v11 = b[y1 * 2048 + x1];
      float r0 = v00 * (1.0f - wy) + v10 * wy;
      float r1 = v01 * (1.0f - wy) + v11 * wy;
      out3[c] = r0 * (1.0f - wx) + r1 * wx;
    }
    o0 = out3[0]; o1 = out3[1]; o2 = out3[2];
  }
  float* dst = pix + ((size_t)(l * 2 + img) * 4096 + j) * 3;
  dst[0] = o0; dst[1] = o1; dst[2] = o2;
}

// one block per (level, direction): project, bitonic sort, partial SSD
__global__ void swd_kernel(const float* pix, const float* dirs, double* partials) {
  __shared__ float sw[4096];
  __shared__ float st[4096];
  __shared__ double red[256];
  int b = blockIdx.x;
  int l = b >> 6, k = b & 63;
  int s = 16 << l;
  long long nn = (long long)s * s;
  int M = (nn < 4096) ? (int)nn : 4096;
  int tid = threadIdx.x;  // 512
  int half = tid >> 8, t = tid & 255;
  float d0 = dirs[l * 192 + k * 3 + 0];
  float d1 = dirs[l * 192 + k * 3 + 1];
  float d2 = dirs[l * 192 + k * 3 + 2];
  float* A = half ? st : sw;
  const float* P = pix + (size_t)(l * 2 + half) * 4096 * 3;
  const float INF = __uint_as_float(0x7f800000u);
  for (int j = t; j < 4096; j += 256)
    A[j] = (j < M) ? (P[j * 3] * d0 + P[j * 3 + 1] * d1 + P[j * 3 + 2] * d2) : INF;
  __syncthreads();
  for (int k2 = 2; k2 <= 4096; k2 <<= 1) {
    for (int j = k2 >> 1; j > 0; j >>= 1) {
      for (int i = t; i < 4096; i += 256) {
        int ixj = i ^ j;
        if (ixj > i) {
          bool up = ((i & k2) == 0);
          float a = A[i], c = A[ixj];
          if ((a > c) == up) { A[i] = c; A[ixj] = a; }
        }
      }
      __syncthreads();
    }
  }
  if (half == 0) {
    double sum = 0.0;
    for (int j = t; j < M; j += 256) {
      double df = (double)sw[j] - (double)st[j];
      sum += df * df;
    }
    red[t] = sum;
  }
  __syncthreads();
  if (tid == 0) {
    double s2 = 0.0;
    for (int i = 0; i < 256; i++) s2 += red[i];
    partials[b] = s2;
  }
}

__global__ void final_kernel(const double* partials, float* out) {
  if (threadIdx.x == 0 && blockIdx.x == 0) {
    double tot = 0.0;
    for (int l = 0; l < 8; l++) {
      int s = 16 << l;
      long long nn = (long long)s * s;
      int M = (nn < 4096) ? (int)nn : 4096;
      double sm = 0.0;
      for (int k = 0; k < 64; k++) sm += partials[l * 64 + k];
      tot += sm / (64.0 * (double)M);
    }
    out[0] = (float)tot;
  }
}

// ---------------- launch -----------------------------------------------------
extern "C" void kernel_launch(void* const* d_in, const int* in_sizes, int n_in,
                              void* d_out, int out_size, void* d_ws, size_t ws_size,
                              hipStream_t stream) {
  const float* wimg = (const float*)d_in[0];
  const float* timg = (const float*)d_in[1];
  float* out = (float*)d_out;
  char* ws = (char*)d_ws;

  size_t off = 0;
  auto alloc = [&](size_t bytes) -> void* {
    void* p = ws + off;
    off = (off + bytes + 255) & ~(size_t)255;
    return p;
  };
  u64* rec     = (u64*)alloc((size_t)RECCAP * 8);            // 33.5 MB
  u32* histmat = (u32*)alloc(64ull * 2 * MAXNB * 4);         // 8 MB
  u32* offT    = (u32*)alloc(64ull * 2 * MAXNB * 4);         // 8 MB
  u32* cnt     = (u32*)alloc(2 * MAXNB * 4);
  u32* fbase   = (u32*)alloc(2 * MAXNB * 4);
  uint2* keyt  = (uint2*)alloc(64 * 8);
  u32* T       = (u32*)alloc(8192 * 4);
  u32* tb      = (u32*)alloc(8192 * 4);
  u32* lrarr   = (u32*)alloc(8192 * 4);
  u32* idx     = (u32*)alloc(5ull * 8192 * 4);
  float* pix   = (float*)alloc(8ull * 2 * 4096 * 3 * 4);
  float* dirs  = (float*)alloc(8ull * 64 * 3 * 4);
  double* part = (double*)alloc(512 * 8);
  (void)ws_size; (void)in_sizes; (void)n_in; (void)out_size;

  hipLaunchKernelGGL(init_kernel, dim3(1), dim3(64), 0, stream, keyt);
  hipLaunchKernelGGL(dirs_kernel, dim3(1), dim3(512), 0, stream, dirs, keyt);

  // L3 special: full in-LDS sorts, one dispatch
  hipLaunchKernelGGL(l3_kernel, dim3(2), dim3(1024), 0, stream, keyt, idx);

  // L4..L7 general pipeline
  for (int l = 4; l < 8; l++) {
    u32 sdim = 16u << l;
    u32 n = sdim * sdim;
    int BB, nblk;
    if (l == 7)      { BB = 14; nblk = 64; }
    else if (l == 6) { BB = 13; nblk = 32; }
    else if (l == 5) { BB = 12; nblk = 16; }
    else             { BB = 10; nblk = 8;  }
    int NB = 1 << BB, NB2 = 2 * NB;
    u32 chunk = (n + (u32)nblk - 1) / (u32)nblk;
    int R = (l == 7) ? 3 : 2;
    for (int jr = R; jr >= 1; jr--) {
      int first = (jr == R) ? 1 : 0;
      int sub0 = 8 + (l - 3) * 6 + (jr - 1);
      hipLaunchKernelGGL(hist_kernel, dim3(nblk, 2), dim3(256), 0, stream,
                         histmat, keyt, sub0, n, BB, NB, NB2, chunk);
      hipLaunchKernelGGL(colscan_kernel, dim3((NB2 + 255) / 256), dim3(256), 0,
                         stream, histmat, offT, cnt, NB2, nblk);
      hipLaunchKernelGGL(plan_kernel, dim3(1), dim3(1024), 0, stream,
                         cnt, fbase, T, tb, lrarr, NB, n, first);
      hipLaunchKernelGGL(scatter_kernel, dim3(nblk, 2), dim3(256), 0, stream,
                         rec, offT, fbase, keyt, sub0, n, BB, NB, NB2, chunk);
      u32* outp = (jr == 1) ? (idx + (size_t)(l - 3) * 8192) : T;
      hipLaunchKernelGGL(rankfind_kernel, dim3(8192), dim3(256), 0, stream,
                         rec, tb, lrarr, fbase, cnt, outp, BB);
    }
  }

  hipLaunchKernelGGL(gather_kernel, dim3(256), dim3(256), 0, stream,
                     wimg, timg, idx, pix);
  hipLaunchKernelGGL(swd_kernel, dim3(512), dim3(512), 0, stream, pix, dirs, part);
  hipLaunchKernelGGL(final_kernel, dim3(1), dim3(1), 0, stream, part, out);
}

// Round 4
// 1185.955 us; speedup vs baseline: 3.3842x; 1.9217x over previous
//
#include <hip/hip_runtime.h>
#include <stdint.h>

// ============================================================================
// DistributionLoss: SWD pyramid loss, exact JAX-RNG replication.
// Round 4: batched multi-level selection pipeline (3 super-rounds, 19
// dispatches total), L3 through the general pipeline, faster swd bitonic.
// ============================================================================
#define JAX_PARTITIONABLE 1

typedef unsigned int u32;
typedef unsigned short u16;
typedef unsigned long long u64;

#define CAP     512         // max bucket entries in rankfind
#define MAXNB   16384       // max buckets per image (64KB LDS)

// ---------------- threefry2x32 (20 rounds), matches jax exactly -------------
__device__ __forceinline__ uint2 tf2(uint2 k, u32 x0, u32 x1) {
  u32 ks0 = k.x, ks1 = k.y, ks2 = k.x ^ k.y ^ 0x1BD11BDAu;
  x0 += ks0; x1 += ks1;
#define TF_RND(R) { x0 += x1; x1 = (x1 << (R)) | (x1 >> (32 - (R))); x1 ^= x0; }
  TF_RND(13) TF_RND(15) TF_RND(26) TF_RND(6)
  x0 += ks1; x1 += ks2 + 1u;
  TF_RND(17) TF_RND(29) TF_RND(16) TF_RND(24)
  x0 += ks2; x1 += ks0 + 2u;
  TF_RND(13) TF_RND(15) TF_RND(26) TF_RND(6)
  x0 += ks0; x1 += ks1 + 3u;
  TF_RND(17) TF_RND(29) TF_RND(16) TF_RND(24)
  x0 += ks1; x1 += ks2 + 4u;
  TF_RND(13) TF_RND(15) TF_RND(26) TF_RND(6)
  x0 += ks2; x1 += ks0 + 5u;
#undef TF_RND
  return make_uint2(x0, x1);
}

__device__ inline void split3(uint2 k, uint2* a, uint2* b, uint2* c) {
#if JAX_PARTITIONABLE
  *a = tf2(k, 0u, 0u); *b = tf2(k, 0u, 1u); *c = tf2(k, 0u, 2u);
#else
  uint2 p0 = tf2(k, 0u, 3u), p1 = tf2(k, 1u, 4u), p2 = tf2(k, 2u, 5u);
  *a = make_uint2(p0.x, p1.x); *b = make_uint2(p2.x, p0.y); *c = make_uint2(p1.y, p2.y);
#endif
}
__device__ inline void split2(uint2 k, uint2* nk, uint2* sub) {
#if JAX_PARTITIONABLE
  *nk = tf2(k, 0u, 0u); *sub = tf2(k, 0u, 1u);
#else
  uint2 p0 = tf2(k, 0u, 2u), p1 = tf2(k, 1u, 3u);
  *nk = make_uint2(p0.x, p1.x); *sub = make_uint2(p0.y, p1.y);
#endif
}
__device__ inline u32 normbits(uint2 kd, u32 idx) {
#if JAX_PARTITIONABLE
  uint2 o = tf2(kd, 0u, idx); return o.x ^ o.y;
#else
  if (idx < 96u) return tf2(kd, idx, idx + 96u).x;
  return tf2(kd, idx - 96u, idx).y;
#endif
}
__device__ inline u32 sortbits(uint2 sk, u32 p, u32 n) {
#if JAX_PARTITIONABLE
  uint2 o = tf2(sk, 0u, p); return o.x ^ o.y;
#else
  u32 h = n >> 1;
  if (p < h) return tf2(sk, p, p + h).x;
  return tf2(sk, p - h, p).y;
#endif
}

// ---------------- erfinv ----------------------------------------------------
__device__ inline double erfinv_d(double x) {
  double w = -log1p(-x * x);
  double p;
  if (w < 5.0) {
    w -= 2.5;
    p = 2.81022636e-08;
    p = 3.43273939e-07 + p * w;
    p = -3.5233877e-06 + p * w;
    p = -4.39150654e-06 + p * w;
    p = 0.00021858087 + p * w;
    p = -0.00125372503 + p * w;
    p = -0.00417768164 + p * w;
    p = 0.246640727 + p * w;
    p = 1.50140941 + p * w;
  } else {
    w = sqrt(w) - 3.0;
    p = -0.000200214257;
    p = 0.000100950558 + p * w;
    p = 0.00134934322 + p * w;
    p = -0.00367342844 + p * w;
    p = 0.00573950773 + p * w;
    p = -0.0076224613 + p * w;
    p = 0.00943887047 + p * w;
    p = 1.00167406 + p * w;
    p = 2.83297682 + p * w;
  }
  double y = p * x;
  for (int it = 0; it < 2; ++it) {
    double e = erf(y) - x;
    y -= e * 0.88622692545275801364 * exp(y * y);
  }
  return y;
}

// ---------------- batched pipeline descriptors ------------------------------
struct Item {
  u32 n, chunk;
  int BB, NB, nblk;
  u32 hm_off;     // u16-element offset into histmat/offT
  u32 cnt_off;    // u32-element offset into cnt/fbase
  u32 rec_off;    // u64-element offset into rec
  u32 rec_cap;
  u32 blk_start;  // hist/scatter grid.x prefix
  u32 col_start;  // colscan grid.x prefix
  int sub_base;   // keytab index: 8 + lev*6 + (jr-1); +img*3 at runtime
  int first;      // targets are ranks 0..4095 (first round)
  int out_is_idx; // final round -> write idx, else write T
  u32 t_off;      // per-level offset into T/tb/lrarr (lev*8192)
  u32 out_off;    // per-level offset into idx (lev*8192)
};
struct Batch { int nitems; Item it[5]; };

__device__ inline int find_item_blk(const Batch& bt, u32 bx) {
  int it = 0;
  for (int i = 1; i < bt.nitems; i++) if (bx >= bt.it[i].blk_start) it = i;
  return it;
}
__device__ inline int find_item_col(const Batch& bt, u32 bx) {
  int it = 0;
  for (int i = 1; i < bt.nitems; i++) if (bx >= bt.it[i].col_start) it = i;
  return it;
}

// ---------------- kernels ---------------------------------------------------

// keytab: [0..7] kd per level; [8 + lev*6 + img*3 + (r-1)] sort subkeys.
// Also computes the 8*64 unit directions.
__global__ void __launch_bounds__(512) setup_kernel(uint2* keytab, float* dirs) {
  __shared__ uint2 kt[64];
  if (threadIdx.x == 0) {
    uint2 base = make_uint2(0u, 42u);
    for (int l = 0; l < 8; l++) {
      uint2 kl = tf2(base, 0u, (u32)l);
      uint2 kd, kw, kt3;
      split3(kl, &kd, &kw, &kt3);
      kt[l] = kd;
      if (l >= 3) {
        for (int img = 0; img < 2; img++) {
          uint2 kp = img ? kt3 : kw;
          for (int r = 0; r < 3; r++) {
            uint2 nk, sub;
            split2(kp, &nk, &sub);
            kt[8 + (l - 3) * 6 + img * 3 + r] = sub;
            kp = nk;
          }
        }
      }
    }
  }
  __syncthreads();
  if (threadIdx.x < 38) keytab[threadIdx.x] = kt[threadIdx.x];
  int t = threadIdx.x;  // 512 = 8 levels * 64 dirs
  int l = t >> 6, k = t & 63;
  uint2 kd = kt[l];
  const float lo = -0.9999999403953552f;
  float dv[3];
  for (int c = 0; c < 3; c++) {
    u32 bits = normbits(kd, (u32)(k * 3 + c));
    float f = __uint_as_float((bits >> 9) | 0x3f800000u) - 1.0f;
    float u = f * 2.0f + lo;
    if (u < lo) u = lo;
    dv[c] = 1.4142135f * (float)erfinv_d((double)u);
  }
  float nrm = sqrtf(dv[0] * dv[0] + dv[1] * dv[1] + dv[2] * dv[2]);
  for (int c = 0; c < 3; c++) dirs[l * 192 + k * 3 + c] = dv[c] / nrm;
}

// per-block LDS histogram, flushed to a private u16 row (no global atomics)
__global__ void __launch_bounds__(256) bhist_kernel(
    u16* histmat, const uint2* keytab, Batch bt) {
  __shared__ u32 lh[MAXNB];
  int item = find_item_blk(bt, blockIdx.x);
  const Item P = bt.it[item];
  int blk = (int)blockIdx.x - (int)P.blk_start;
  int img = blockIdx.y;
  for (int b = threadIdx.x; b < P.NB; b += 256) lh[b] = 0u;
  __syncthreads();
  uint2 sk = keytab[P.sub_base + img * 3];
  u32 q0 = (u32)blk * P.chunk, q1 = q0 + P.chunk;
  if (q1 > P.n) q1 = P.n;
  for (u32 q = q0 + threadIdx.x; q < q1; q += 256) {
    u32 b = sortbits(sk, q, P.n) >> (32 - P.BB);
    atomicAdd(&lh[b], 1u);
  }
  __syncthreads();
  u16* row = histmat + P.hm_off + ((size_t)blk * 2 + img) * P.NB;
  for (int b = threadIdx.x; b < P.NB; b += 256) row[b] = (u16)lh[b];
}

// per-bucket exclusive scan across blocks -> offT (u16); totals -> cnt (u32)
__global__ void __launch_bounds__(256) bcolscan_kernel(
    const u16* histmat, u16* offT, u32* cnt, Batch bt) {
  int item = find_item_col(bt, blockIdx.x);
  const Item P = bt.it[item];
  int NB2 = 2 * P.NB;
  int gb = ((int)blockIdx.x - (int)P.col_start) * 256 + threadIdx.x;
  if (gb >= NB2) return;
  u32 run = 0;
  for (int blk = 0; blk < P.nblk; blk++) {
    size_t ix = P.hm_off + (size_t)blk * NB2 + gb;
    offT[ix] = (u16)run;
    run += histmat[ix];
  }
  cnt[P.cnt_off + gb] = run;
}

// one block per item: rank-scan cnt, locate targets, flag buckets (bit31),
// compact-scan flagged -> fbase (0xFFFFFFFF sentinel for unflagged).
__global__ void __launch_bounds__(1024) bplan_kernel(
    const u32* cnt, u32* fbase, const u32* Tbuf, u32* tb, u32* lrarr,
    Batch bt) {
  __shared__ u32 sBase[2 * MAXNB];   // 128KB
  __shared__ u32 part[1024];
  const u32 MASK = 0x7fffffffu;
  const Item P = bt.it[blockIdx.x];
  int NB = P.NB, NB2 = 2 * NB;
  u32 n = P.n;
  const u32* cntp = cnt + P.cnt_off;
  int tid = threadIdx.x;
  int chunk = (NB2 + 1023) >> 10;
  int s = tid * chunk, e = s + chunk;
  if (e > NB2) e = NB2;
  if (s > NB2) s = NB2;
  // phase 1: exclusive scan of cnt into sBase (per-image adjusted)
  u32 sum = 0;
  for (int i = s; i < e; i++) sum += cntp[i];
  part[tid] = sum;
  __syncthreads();
  for (int off = 1; off < 1024; off <<= 1) {
    u32 v = (tid >= off) ? part[tid - off] : 0u;
    __syncthreads();
    part[tid] += v;
    __syncthreads();
  }
  u32 run = part[tid] - sum;
  for (int i = s; i < e; i++) {
    sBase[i] = run - ((i >= NB) ? n : 0u);
    run += cntp[i];
  }
  __syncthreads();
  // phase 2: per-target binary search; flag bucket via bit31
  for (int r = tid; r < 8192; r += 1024) {
    int img = r >> 12;
    u32 t = P.first ? (u32)(r & 4095) : Tbuf[P.t_off + r];
    const u32* B = sBase + img * NB;
    int lo = 0, hi = NB - 1;
    while (lo < hi) {
      int mid = (lo + hi + 1) >> 1;
      if ((B[mid] & MASK) <= t) lo = mid; else hi = mid - 1;
    }
    tb[P.t_off + r] = (u32)(img * NB + lo);
    lrarr[P.t_off + r] = t - (B[lo] & MASK);
    atomicOr(&sBase[img * NB + lo], 0x80000000u);
  }
  __syncthreads();
  // phase 3: compact exclusive scan over flagged bucket counts -> fbase
  u32 vs = 0;
  for (int i = s; i < e; i++) vs += (sBase[i] >> 31) ? cntp[i] : 0u;
  part[tid] = vs;
  __syncthreads();
  for (int off = 1; off < 1024; off <<= 1) {
    u32 v = (tid >= off) ? part[tid - off] : 0u;
    __syncthreads();
    part[tid] += v;
    __syncthreads();
  }
  u32 run2 = part[tid] - vs;
  for (int i = s; i < e; i++) {
    if (sBase[i] >> 31) {
      fbase[P.cnt_off + i] = run2;
      run2 += cntp[i];
    } else {
      fbase[P.cnt_off + i] = 0xFFFFFFFFu;
    }
  }
}

// scatter flagged-bucket elements to compact storage via LDS cursors only
__global__ void __launch_bounds__(256) bscatter_kernel(
    u64* rec, const u16* offT, const u32* fbase, const uint2* keytab,
    Batch bt) {
  __shared__ u32 cursor[MAXNB];
  int item = find_item_blk(bt, blockIdx.x);
  const Item P = bt.it[item];
  int blk = (int)blockIdx.x - (int)P.blk_start;
  int img = blockIdx.y;
  int NB2 = 2 * P.NB;
  const u16* orow = offT + P.hm_off + (size_t)blk * NB2 + (size_t)img * P.NB;
  const u32* frow = fbase + P.cnt_off + (size_t)img * P.NB;
  for (int b = threadIdx.x; b < P.NB; b += 256) {
    u32 fb = frow[b];
    cursor[b] = (fb == 0xFFFFFFFFu) ? 0xFFFFFFFFu : P.rec_off + fb + orow[b];
  }
  __syncthreads();
  uint2 sk = keytab[P.sub_base + img * 3];
  u32 limit = P.rec_off + P.rec_cap;
  u32 q0 = (u32)blk * P.chunk, q1 = q0 + P.chunk;
  if (q1 > P.n) q1 = P.n;
  for (u32 q = q0 + threadIdx.x; q < q1; q += 256) {
    u32 bits = sortbits(sk, q, P.n);
    u32 b = bits >> (32 - P.BB);
    if (cursor[b] != 0xFFFFFFFFu) {
      u32 slot = atomicAdd(&cursor[b], 1u);
      if (slot < limit) rec[slot] = ((u64)bits << 32) | (u64)q;
    }
  }
}

// one block per (target, item): O(m) sub-radix rank find within bucket
__global__ void __launch_bounds__(256) brankfind_kernel(
    const u64* rec, const u32* tb, const u32* lrarr, const u32* fbase,
    const u32* cnt, u32* Tbuf, u32* idx, Batch bt) {
  __shared__ u64 kk[CAP];
  __shared__ u32 sh[256];
  __shared__ u32 ssb;
  __shared__ u32 sexcl;
  const Item P = bt.it[blockIdx.y];
  int r = blockIdx.x;
  int tid = threadIdx.x;
  u32 gb = tb[P.t_off + r];
  u32 lr = lrarr[P.t_off + r];
  u32 s0 = P.rec_off + fbase[P.cnt_off + gb];
  u32 m = cnt[P.cnt_off + gb];
  if (m > CAP) m = CAP;
  int shamt = 24 - P.BB;  // sub-byte just below bucket bits
  for (u32 i = tid; i < m; i += 256) kk[i] = rec[s0 + i];
  sh[tid] = 0u;
  __syncthreads();
  for (u32 i = tid; i < m; i += 256)
    atomicAdd(&sh[((u32)(kk[i] >> 32) >> shamt) & 255u], 1u);
  __syncthreads();
  u32 own = sh[tid];
  for (int off = 1; off < 256; off <<= 1) {
    u32 v = (tid >= off) ? sh[tid - off] : 0u;
    __syncthreads();
    sh[tid] += v;
    __syncthreads();
  }
  u32 incl = sh[tid];
  u32 excl = incl - own;
  if (own > 0u && excl <= lr && lr < incl) { ssb = (u32)tid; sexcl = excl; }
  __syncthreads();
  u32 sb = ssb;
  u32 lr2 = lr - sexcl;
  u32* outp = P.out_is_idx ? (idx + P.out_off) : (Tbuf + P.t_off);
  for (u32 i = tid; i < m; i += 256) {
    if ((((u32)(kk[i] >> 32) >> shamt) & 255u) == sb) {
      u64 me = kk[i];
      u32 c = 0;
      for (u32 j = 0; j < m; j++) {
        u64 kj = kk[j];
        if (((((u32)(kj >> 32)) >> shamt) & 255u) == sb && kj < me) c++;
      }
      if (c == lr2) outp[r] = (u32)(me & 0xffffffffu);
    }
  }
}

// gather sampled pixels (bilinear align_corners from 2048x2048 source)
__global__ void gather_kernel(const float* wimg, const float* timg,
                              const u32* idx, float* pix) {
  int t = blockIdx.x * blockDim.x + threadIdx.x;
  if (t >= 65536) return;
  int j = t & 4095;
  int img = (t >> 12) & 1;
  int l = t >> 13;
  int s = 16 << l;
  long long n = (long long)s * s;
  int M = (n < 4096) ? (int)n : 4096;
  if (j >= M) return;
  u32 p = (l < 3) ? (u32)j : idx[((l - 3) * 2 + img) * 4096 + j];
  const float* src = img ? timg : wimg;
  float o0, o1, o2;
  if (l == 7) {
    o0 = src[p];
    o1 = src[4194304 + p];
    o2 = src[8388608 + p];
  } else {
    u32 y = p / (u32)s, xq = p % (u32)s;
    float delta = 2047.0f / (float)(s - 1);
    float yc = (float)y * delta, xc = (float)xq * delta;
    int y0 = (int)floorf(yc); if (y0 > 2047) y0 = 2047;
    int x0 = (int)floorf(xc); if (x0 > 2047) x0 = 2047;
    int y1 = y0 + 1; if (y1 > 2047) y1 = 2047;
    int x1 = x0 + 1; if (x1 > 2047) x1 = 2047;
    float wy = yc - (float)y0, wx = xc - (float)x0;
    float out3[3];
    for (int c = 0; c < 3; c++) {
      const float* b = src + (size_t)c * 4194304;
      float v00 = b[y0 * 2048 + x0], v01 = b[y0 * 2048 + x1];
      float v10 = b[y1 * 2048 + x0], v11 = b[y1 * 2048 + x1];
      float r0 = v00 * (1.0f - wy) + v10 * wy;
      float r1 = v01 * (1.0f - wy) + v11 * wy;
      out3[c] = r0 * (1.0f - wx) + r1 * wx;
    }
    o0 = out3[0]; o1 = out3[1]; o2 = out3[2];
  }
  float* dst = pix + ((size_t)(l * 2 + img) * 4096 + j) * 3;
  dst[0] = o0; dst[1] = o1; dst[2] = o2;
}

// one block per (level, direction): project, bitonic sort, partial SSD.
// 1024 threads: 512 per array; j>=8 via LDS pair-steps, j=4,2,1 in registers.
__global__ void __launch_bounds__(1024) swd_kernel(
    const float* pix, const float* dirs, double* partials) {
  __shared__ float sw[4096];
  __shared__ float st[4096];
  __shared__ double wred[16];
  int b = blockIdx.x;
  int l = b >> 6, k = b & 63;
  int sdim = 16 << l;
  long long nn = (long long)sdim * sdim;
  int M = (nn < 4096) ? (int)nn : 4096;
  int tid = threadIdx.x;  // 1024
  int half = tid >> 9, t = tid & 511;
  float d0 = dirs[l * 192 + k * 3 + 0];
  float d1 = dirs[l * 192 + k * 3 + 1];
  float d2 = dirs[l * 192 + k * 3 + 2];
  float* A = half ? st : sw;
  const float* P = pix + (size_t)(l * 2 + half) * 4096 * 3;
  const float INF = __uint_as_float(0x7f800000u);
  for (int j = t; j < 4096; j += 512)
    A[j] = (j < M) ? (P[j * 3] * d0 + P[j * 3 + 1] * d1 + P[j * 3 + 2] * d2) : INF;
  __syncthreads();
#define CE(x, y, up) { if ((v[x] > v[y]) == (up)) { float tt = v[x]; v[x] = v[y]; v[y] = tt; } }
  for (u32 k2 = 2; k2 <= 4096; k2 <<= 1) {
    for (u32 j = k2 >> 1; j >= 8; j >>= 1) {
      for (u32 p = t; p < 2048; p += 512) {
        u32 i = ((p & ~(j - 1)) << 1) | (p & (j - 1));
        u32 ix = i | j;
        bool up = ((i & k2) == 0);
        float a = A[i], c = A[ix];
        if ((a > c) == up) { A[i] = c; A[ix] = a; }
      }
      __syncthreads();
    }
    // register tail: j = min(4, k2/2) .. 1; each thread owns 8 contiguous
    {
      u32 base = (u32)t * 8;
      float v[8];
      #pragma unroll
      for (int a = 0; a < 8; a++) v[a] = A[base + a];
      if (k2 == 2) {
        CE(0, 1, true) CE(2, 3, false) CE(4, 5, true) CE(6, 7, false)
      } else if (k2 == 4) {
        CE(0, 2, true) CE(1, 3, true) CE(4, 6, false) CE(5, 7, false)
        CE(0, 1, true) CE(2, 3, true) CE(4, 5, false) CE(6, 7, false)
      } else {
        bool up = ((base & k2) == 0);
        CE(0, 4, up) CE(1, 5, up) CE(2, 6, up) CE(3, 7, up)
        CE(0, 2, up) CE(1, 3, up) CE(4, 6, up) CE(5, 7, up)
        CE(0, 1, up) CE(2, 3, up) CE(4, 5, up) CE(6, 7, up)
      }
      #pragma unroll
      for (int a = 0; a < 8; a++) A[base + a] = v[a];
      __syncthreads();
    }
  }
#undef CE
  double sum = 0.0;
  if (half == 0) {
    for (int j = t; j < M; j += 512) {
      double df = (double)sw[j] - (double)st[j];
      sum += df * df;
    }
  }
  for (int off = 32; off >= 1; off >>= 1) sum += __shfl_down(sum, off);
  if ((tid & 63) == 0) wred[tid >> 6] = sum;
  __syncthreads();
  if (tid == 0) {
    double s2 = 0.0;
    for (int i = 0; i < 16; i++) s2 += wred[i];
    partials[b] = s2;
  }
}

__global__ void final_kernel(const double* partials, float* out) {
  if (threadIdx.x == 0 && blockIdx.x == 0) {
    double tot = 0.0;
    for (int l = 0; l < 8; l++) {
      int s = 16 << l;
      long long nn = (long long)s * s;
      int M = (nn < 4096) ? (int)nn : 4096;
      double sm = 0.0;
      for (int k = 0; k < 64; k++) sm += partials[l * 64 + k];
      tot += sm / (64.0 * (double)M);
    }
    out[0] = (float)tot;
  }
}

// ---------------- launch -----------------------------------------------------
extern "C" void kernel_launch(void* const* d_in, const int* in_sizes, int n_in,
                              void* d_out, int out_size, void* d_ws, size_t ws_size,
                              hipStream_t stream) {
  const float* wimg = (const float*)d_in[0];
  const float* timg = (const float*)d_in[1];
  float* out = (float*)d_out;
  char* ws = (char*)d_ws;

  // per-level static tables (lev 0..4 = pyramid levels 3..7)
  static const u32 Ln[5]    = {16384u, 65536u, 262144u, 1048576u, 4194304u};
  static const int LBB[5]   = {7, 9, 11, 13, 14};
  static const int LNB[5]   = {128, 512, 2048, 8192, 16384};
  static const int Lnblk[5] = {4, 8, 16, 32, 64};
  static const u32 Lhm[5]   = {0u, 1024u, 9216u, 74752u, 599040u};      // u16 elems
  static const u32 Lcnt[5]  = {0u, 256u, 1280u, 5376u, 21760u};          // u32 elems
  static const u32 Lrec[5]  = {0u, 32768u, 163840u, 688128u, 1998848u};  // u64 elems
  static const u32 Lcap[5]  = {32768u, 131072u, 524288u, 1310720u, 2621440u};
  const u32 HM_TOTAL = 2696192u;   // Σ nblk*NB2
  const u32 CNT_TOTAL = 54528u;    // Σ NB2
  const u32 REC_TOTAL = 4620288u;  // Σ caps

  size_t off = 0;
  auto alloc = [&](size_t bytes) -> void* {
    void* p = ws + off;
    off = (off + bytes + 255) & ~(size_t)255;
    return p;
  };
  u64* rec     = (u64*)alloc((size_t)REC_TOTAL * 8);   // 36.96 MB
  u16* histmat = (u16*)alloc((size_t)HM_TOTAL * 2);    // 5.39 MB
  u16* offT    = (u16*)alloc((size_t)HM_TOTAL * 2);    // 5.39 MB
  u32* cnt     = (u32*)alloc((size_t)CNT_TOTAL * 4);
  u32* fbase   = (u32*)alloc((size_t)CNT_TOTAL * 4);
  uint2* keyt  = (uint2*)alloc(64 * 8);
  u32* T       = (u32*)alloc(5ull * 8192 * 4);
  u32* tb      = (u32*)alloc(5ull * 8192 * 4);
  u32* lrarr   = (u32*)alloc(5ull * 8192 * 4);
  u32* idx     = (u32*)alloc(5ull * 8192 * 4);
  float* pix   = (float*)alloc(8ull * 2 * 4096 * 3 * 4);
  float* dirs  = (float*)alloc(8ull * 64 * 3 * 4);
  double* part = (double*)alloc(512 * 8);
  (void)ws_size; (void)in_sizes; (void)n_in; (void)out_size;

  hipLaunchKernelGGL(setup_kernel, dim3(1), dim3(512), 0, stream, keyt, dirs);

  // 3 super-rounds; within each: bhist -> bcolscan -> bplan -> bscatter -> brankfind
  for (int sr = 0; sr < 3; sr++) {
    Batch bt;
    int m = 0;
    u32 bs = 0, cs = 0;
    for (int lev = 0; lev < 5; lev++) {
      int R = (lev == 4) ? 3 : 2;
      int jr = R - sr;
      if (jr < 1) continue;
      Item& I = bt.it[m++];
      I.n = Ln[lev]; I.chunk = Ln[lev] / (u32)Lnblk[lev];
      I.BB = LBB[lev]; I.NB = LNB[lev]; I.nblk = Lnblk[lev];
      I.hm_off = Lhm[lev]; I.cnt_off = Lcnt[lev];
      I.rec_off = Lrec[lev]; I.rec_cap = Lcap[lev];
      I.blk_start = bs; bs += (u32)Lnblk[lev];
      I.col_start = cs; cs += (u32)((2 * LNB[lev] + 255) / 256);
      I.sub_base = 8 + lev * 6 + (jr - 1);
      I.first = (jr == R) ? 1 : 0;
      I.out_is_idx = (jr == 1) ? 1 : 0;
      I.t_off = (u32)lev * 8192u;
      I.out_off = (u32)lev * 8192u;
    }
    bt.nitems = m;
    hipLaunchKernelGGL(bhist_kernel, dim3(bs, 2), dim3(256), 0, stream,
                       histmat, keyt, bt);
    hipLaunchKernelGGL(bcolscan_kernel, dim3(cs), dim3(256), 0, stream,
                       histmat, offT, cnt, bt);
    hipLaunchKernelGGL(bplan_kernel, dim3(m), dim3(1024), 0, stream,
                       cnt, fbase, T, tb, lrarr, bt);
    hipLaunchKernelGGL(bscatter_kernel, dim3(bs, 2), dim3(256), 0, stream,
                       rec, offT, fbase, keyt, bt);
    hipLaunchKernelGGL(brankfind_kernel, dim3(8192, m), dim3(256), 0, stream,
                       rec, tb, lrarr, fbase, cnt, T, idx, bt);
  }

  hipLaunchKernelGGL(gather_kernel, dim3(256), dim3(256), 0, stream,
                     wimg, timg, idx, pix);
  hipLaunchKernelGGL(swd_kernel, dim3(512), dim3(1024), 0, stream,
                     pix, dirs, part);
  hipLaunchKernelGGL(final_kernel, dim3(1), dim3(1), 0, stream, part, out);
}

// Round 5
// 951.966 us; speedup vs baseline: 4.2160x; 1.2458x over previous
//
#include <hip/hip_runtime.h>
#include <stdint.h>

// ============================================================================
// DistributionLoss: SWD pyramid loss, exact JAX-RNG replication.
// Round 5: wave-per-target rankfind (64-lane sub-radix select, shfl scan),
// replacing the block-per-target version (123us -> ~10us per dispatch).
// ============================================================================
#define JAX_PARTITIONABLE 1

typedef unsigned int u32;
typedef unsigned short u16;
typedef unsigned long long u64;

#define CAP     512         // max bucket entries in rankfind
#define MAXNB   16384       // max buckets per image (64KB LDS)

// ---------------- threefry2x32 (20 rounds), matches jax exactly -------------
__device__ __forceinline__ uint2 tf2(uint2 k, u32 x0, u32 x1) {
  u32 ks0 = k.x, ks1 = k.y, ks2 = k.x ^ k.y ^ 0x1BD11BDAu;
  x0 += ks0; x1 += ks1;
#define TF_RND(R) { x0 += x1; x1 = (x1 << (R)) | (x1 >> (32 - (R))); x1 ^= x0; }
  TF_RND(13) TF_RND(15) TF_RND(26) TF_RND(6)
  x0 += ks1; x1 += ks2 + 1u;
  TF_RND(17) TF_RND(29) TF_RND(16) TF_RND(24)
  x0 += ks2; x1 += ks0 + 2u;
  TF_RND(13) TF_RND(15) TF_RND(26) TF_RND(6)
  x0 += ks0; x1 += ks1 + 3u;
  TF_RND(17) TF_RND(29) TF_RND(16) TF_RND(24)
  x0 += ks1; x1 += ks2 + 4u;
  TF_RND(13) TF_RND(15) TF_RND(26) TF_RND(6)
  x0 += ks2; x1 += ks0 + 5u;
#undef TF_RND
  return make_uint2(x0, x1);
}

__device__ inline void split3(uint2 k, uint2* a, uint2* b, uint2* c) {
#if JAX_PARTITIONABLE
  *a = tf2(k, 0u, 0u); *b = tf2(k, 0u, 1u); *c = tf2(k, 0u, 2u);
#else
  uint2 p0 = tf2(k, 0u, 3u), p1 = tf2(k, 1u, 4u), p2 = tf2(k, 2u, 5u);
  *a = make_uint2(p0.x, p1.x); *b = make_uint2(p2.x, p0.y); *c = make_uint2(p1.y, p2.y);
#endif
}
__device__ inline void split2(uint2 k, uint2* nk, uint2* sub) {
#if JAX_PARTITIONABLE
  *nk = tf2(k, 0u, 0u); *sub = tf2(k, 0u, 1u);
#else
  uint2 p0 = tf2(k, 0u, 2u), p1 = tf2(k, 1u, 3u);
  *nk = make_uint2(p0.x, p1.x); *sub = make_uint2(p0.y, p1.y);
#endif
}
__device__ inline u32 normbits(uint2 kd, u32 idx) {
#if JAX_PARTITIONABLE
  uint2 o = tf2(kd, 0u, idx); return o.x ^ o.y;
#else
  if (idx < 96u) return tf2(kd, idx, idx + 96u).x;
  return tf2(kd, idx - 96u, idx).y;
#endif
}
__device__ inline u32 sortbits(uint2 sk, u32 p, u32 n) {
#if JAX_PARTITIONABLE
  uint2 o = tf2(sk, 0u, p); return o.x ^ o.y;
#else
  u32 h = n >> 1;
  if (p < h) return tf2(sk, p, p + h).x;
  return tf2(sk, p - h, p).y;
#endif
}

// ---------------- erfinv ----------------------------------------------------
__device__ inline double erfinv_d(double x) {
  double w = -log1p(-x * x);
  double p;
  if (w < 5.0) {
    w -= 2.5;
    p = 2.81022636e-08;
    p = 3.43273939e-07 + p * w;
    p = -3.5233877e-06 + p * w;
    p = -4.39150654e-06 + p * w;
    p = 0.00021858087 + p * w;
    p = -0.00125372503 + p * w;
    p = -0.00417768164 + p * w;
    p = 0.246640727 + p * w;
    p = 1.50140941 + p * w;
  } else {
    w = sqrt(w) - 3.0;
    p = -0.000200214257;
    p = 0.000100950558 + p * w;
    p = 0.00134934322 + p * w;
    p = -0.00367342844 + p * w;
    p = 0.00573950773 + p * w;
    p = -0.0076224613 + p * w;
    p = 0.00943887047 + p * w;
    p = 1.00167406 + p * w;
    p = 2.83297682 + p * w;
  }
  double y = p * x;
  for (int it = 0; it < 2; ++it) {
    double e = erf(y) - x;
    y -= e * 0.88622692545275801364 * exp(y * y);
  }
  return y;
}

// ---------------- batched pipeline descriptors ------------------------------
struct Item {
  u32 n, chunk;
  int BB, NB, nblk;
  u32 hm_off;     // u16-element offset into histmat/offT
  u32 cnt_off;    // u32-element offset into cnt/fbase
  u32 rec_off;    // u64-element offset into rec
  u32 rec_cap;
  u32 blk_start;  // hist/scatter grid.x prefix
  u32 col_start;  // colscan grid.x prefix
  int sub_base;   // keytab index: 8 + lev*6 + (jr-1); +img*3 at runtime
  int first;      // targets are ranks 0..4095 (first round)
  int out_is_idx; // final round -> write idx, else write T
  u32 t_off;      // per-level offset into T/tb/lrarr (lev*8192)
  u32 out_off;    // per-level offset into idx (lev*8192)
};
struct Batch { int nitems; Item it[5]; };

__device__ inline int find_item_blk(const Batch& bt, u32 bx) {
  int it = 0;
  for (int i = 1; i < bt.nitems; i++) if (bx >= bt.it[i].blk_start) it = i;
  return it;
}
__device__ inline int find_item_col(const Batch& bt, u32 bx) {
  int it = 0;
  for (int i = 1; i < bt.nitems; i++) if (bx >= bt.it[i].col_start) it = i;
  return it;
}

// ---------------- kernels ---------------------------------------------------

// keytab: [0..7] kd per level; [8 + lev*6 + img*3 + (r-1)] sort subkeys.
// Also computes the 8*64 unit directions.
__global__ void __launch_bounds__(512) setup_kernel(uint2* keytab, float* dirs) {
  __shared__ uint2 kt[64];
  if (threadIdx.x == 0) {
    uint2 base = make_uint2(0u, 42u);
    for (int l = 0; l < 8; l++) {
      uint2 kl = tf2(base, 0u, (u32)l);
      uint2 kd, kw, kt3;
      split3(kl, &kd, &kw, &kt3);
      kt[l] = kd;
      if (l >= 3) {
        for (int img = 0; img < 2; img++) {
          uint2 kp = img ? kt3 : kw;
          for (int r = 0; r < 3; r++) {
            uint2 nk, sub;
            split2(kp, &nk, &sub);
            kt[8 + (l - 3) * 6 + img * 3 + r] = sub;
            kp = nk;
          }
        }
      }
    }
  }
  __syncthreads();
  if (threadIdx.x < 38) keytab[threadIdx.x] = kt[threadIdx.x];
  int t = threadIdx.x;  // 512 = 8 levels * 64 dirs
  int l = t >> 6, k = t & 63;
  uint2 kd = kt[l];
  const float lo = -0.9999999403953552f;
  float dv[3];
  for (int c = 0; c < 3; c++) {
    u32 bits = normbits(kd, (u32)(k * 3 + c));
    float f = __uint_as_float((bits >> 9) | 0x3f800000u) - 1.0f;
    float u = f * 2.0f + lo;
    if (u < lo) u = lo;
    dv[c] = 1.4142135f * (float)erfinv_d((double)u);
  }
  float nrm = sqrtf(dv[0] * dv[0] + dv[1] * dv[1] + dv[2] * dv[2]);
  for (int c = 0; c < 3; c++) dirs[l * 192 + k * 3 + c] = dv[c] / nrm;
}

// per-block LDS histogram, flushed to a private u16 row (no global atomics)
__global__ void __launch_bounds__(256) bhist_kernel(
    u16* histmat, const uint2* keytab, Batch bt) {
  __shared__ u32 lh[MAXNB];
  int item = find_item_blk(bt, blockIdx.x);
  const Item P = bt.it[item];
  int blk = (int)blockIdx.x - (int)P.blk_start;
  int img = blockIdx.y;
  for (int b = threadIdx.x; b < P.NB; b += 256) lh[b] = 0u;
  __syncthreads();
  uint2 sk = keytab[P.sub_base + img * 3];
  u32 q0 = (u32)blk * P.chunk, q1 = q0 + P.chunk;
  if (q1 > P.n) q1 = P.n;
  for (u32 q = q0 + threadIdx.x; q < q1; q += 256) {
    u32 b = sortbits(sk, q, P.n) >> (32 - P.BB);
    atomicAdd(&lh[b], 1u);
  }
  __syncthreads();
  u16* row = histmat + P.hm_off + ((size_t)blk * 2 + img) * P.NB;
  for (int b = threadIdx.x; b < P.NB; b += 256) row[b] = (u16)lh[b];
}

// per-bucket exclusive scan across blocks -> offT (u16); totals -> cnt (u32)
__global__ void __launch_bounds__(256) bcolscan_kernel(
    const u16* histmat, u16* offT, u32* cnt, Batch bt) {
  int item = find_item_col(bt, blockIdx.x);
  const Item P = bt.it[item];
  int NB2 = 2 * P.NB;
  int gb = ((int)blockIdx.x - (int)P.col_start) * 256 + threadIdx.x;
  if (gb >= NB2) return;
  u32 run = 0;
  for (int blk = 0; blk < P.nblk; blk++) {
    size_t ix = P.hm_off + (size_t)blk * NB2 + gb;
    offT[ix] = (u16)run;
    run += histmat[ix];
  }
  cnt[P.cnt_off + gb] = run;
}

// one block per item: rank-scan cnt, locate targets, flag buckets (bit31),
// compact-scan flagged -> fbase (0xFFFFFFFF sentinel for unflagged).
__global__ void __launch_bounds__(1024) bplan_kernel(
    const u32* cnt, u32* fbase, const u32* Tbuf, u32* tb, u32* lrarr,
    Batch bt) {
  __shared__ u32 sBase[2 * MAXNB];   // 128KB
  __shared__ u32 part[1024];
  const u32 MASK = 0x7fffffffu;
  const Item P = bt.it[blockIdx.x];
  int NB = P.NB, NB2 = 2 * NB;
  u32 n = P.n;
  const u32* cntp = cnt + P.cnt_off;
  int tid = threadIdx.x;
  int chunk = (NB2 + 1023) >> 10;
  int s = tid * chunk, e = s + chunk;
  if (e > NB2) e = NB2;
  if (s > NB2) s = NB2;
  // phase 1: exclusive scan of cnt into sBase (per-image adjusted)
  u32 sum = 0;
  for (int i = s; i < e; i++) sum += cntp[i];
  part[tid] = sum;
  __syncthreads();
  for (int off = 1; off < 1024; off <<= 1) {
    u32 v = (tid >= off) ? part[tid - off] : 0u;
    __syncthreads();
    part[tid] += v;
    __syncthreads();
  }
  u32 run = part[tid] - sum;
  for (int i = s; i < e; i++) {
    sBase[i] = run - ((i >= NB) ? n : 0u);
    run += cntp[i];
  }
  __syncthreads();
  // phase 2: per-target binary search; flag bucket via bit31
  for (int r = tid; r < 8192; r += 1024) {
    int img = r >> 12;
    u32 t = P.first ? (u32)(r & 4095) : Tbuf[P.t_off + r];
    const u32* B = sBase + img * NB;
    int lo = 0, hi = NB - 1;
    while (lo < hi) {
      int mid = (lo + hi + 1) >> 1;
      if ((B[mid] & MASK) <= t) lo = mid; else hi = mid - 1;
    }
    tb[P.t_off + r] = (u32)(img * NB + lo);
    lrarr[P.t_off + r] = t - (B[lo] & MASK);
    atomicOr(&sBase[img * NB + lo], 0x80000000u);
  }
  __syncthreads();
  // phase 3: compact exclusive scan over flagged bucket counts -> fbase
  u32 vs = 0;
  for (int i = s; i < e; i++) vs += (sBase[i] >> 31) ? cntp[i] : 0u;
  part[tid] = vs;
  __syncthreads();
  for (int off = 1; off < 1024; off <<= 1) {
    u32 v = (tid >= off) ? part[tid - off] : 0u;
    __syncthreads();
    part[tid] += v;
    __syncthreads();
  }
  u32 run2 = part[tid] - vs;
  for (int i = s; i < e; i++) {
    if (sBase[i] >> 31) {
      fbase[P.cnt_off + i] = run2;
      run2 += cntp[i];
    } else {
      fbase[P.cnt_off + i] = 0xFFFFFFFFu;
    }
  }
}

// scatter flagged-bucket elements to compact storage via LDS cursors only
__global__ void __launch_bounds__(256) bscatter_kernel(
    u64* rec, const u16* offT, const u32* fbase, const uint2* keytab,
    Batch bt) {
  __shared__ u32 cursor[MAXNB];
  int item = find_item_blk(bt, blockIdx.x);
  const Item P = bt.it[item];
  int blk = (int)blockIdx.x - (int)P.blk_start;
  int img = blockIdx.y;
  int NB2 = 2 * P.NB;
  const u16* orow = offT + P.hm_off + (size_t)blk * NB2 + (size_t)img * P.NB;
  const u32* frow = fbase + P.cnt_off + (size_t)img * P.NB;
  for (int b = threadIdx.x; b < P.NB; b += 256) {
    u32 fb = frow[b];
    cursor[b] = (fb == 0xFFFFFFFFu) ? 0xFFFFFFFFu : P.rec_off + fb + orow[b];
  }
  __syncthreads();
  uint2 sk = keytab[P.sub_base + img * 3];
  u32 limit = P.rec_off + P.rec_cap;
  u32 q0 = (u32)blk * P.chunk, q1 = q0 + P.chunk;
  if (q1 > P.n) q1 = P.n;
  for (u32 q = q0 + threadIdx.x; q < q1; q += 256) {
    u32 bits = sortbits(sk, q, P.n);
    u32 b = bits >> (32 - P.BB);
    if (cursor[b] != 0xFFFFFFFFu) {
      u32 slot = atomicAdd(&cursor[b], 1u);
      if (slot < limit) rec[slot] = ((u64)bits << 32) | (u64)q;
    }
  }
}

// wave-per-target rank find: 64-lane sub-radix (6 bits), shfl scan, no
// block-wide scans. 4 waves (targets) per 256-thread block.
__global__ void __launch_bounds__(256) brankfind_kernel(
    const u64* rec, const u32* tb, const u32* lrarr, const u32* fbase,
    const u32* cnt, u32* Tbuf, u32* idx, Batch bt) {
  __shared__ u64 kk[4][CAP];
  __shared__ u32 bins[4][64];
  __shared__ u32 cand[4][64];
  __shared__ u32 ncand_s[4];
  const Item P = bt.it[blockIdx.y];
  int w = threadIdx.x >> 6;       // wave id 0..3
  int lane = threadIdx.x & 63;
  int r = blockIdx.x * 4 + w;     // target id 0..8191
  u32 gb = tb[P.t_off + r];
  u32 lr = lrarr[P.t_off + r];
  u32 s0 = P.rec_off + fbase[P.cnt_off + gb];
  u32 m = cnt[P.cnt_off + gb];
  if (m > CAP) m = CAP;
  int shamt = 26 - P.BB;          // 6 sub-radix bits just below bucket bits
  bins[w][lane] = 0u;
  if (lane == 0) ncand_s[w] = 0u;
  for (u32 i = lane; i < m; i += 64) kk[w][i] = rec[s0 + i];
  __syncthreads();
  for (u32 i = lane; i < m; i += 64)
    atomicAdd(&bins[w][((u32)(kk[w][i] >> 32) >> shamt) & 63u], 1u);
  __syncthreads();
  // wave-inclusive scan of 64 bins (lane l holds bin l)
  u32 own = bins[w][lane];
  u32 incl = own;
  #pragma unroll
  for (int d = 1; d < 64; d <<= 1) {
    u32 v = __shfl_up(incl, d, 64);
    if (lane >= d) incl += v;
  }
  u32 excl = incl - own;
  u64 mask = __ballot(excl <= lr && lr < incl);
  int sb = __ffsll((long long)mask) - 1;
  u32 sexcl = __shfl(excl, sb, 64);
  u32 lr2 = lr - sexcl;
  // collect candidate indices (entries whose sub-bucket == sb)
  for (u32 i = lane; i < m; i += 64) {
    if ((((u32)(kk[w][i] >> 32) >> shamt) & 63u) == (u32)sb) {
      u32 pos = atomicAdd(&ncand_s[w], 1u);
      if (pos < 64u) cand[w][pos] = i;
    }
  }
  __syncthreads();
  u32 nc = ncand_s[w];
  if (nc > 64u) nc = 64u;
  u32* outp = P.out_is_idx ? (idx + P.out_off) : (Tbuf + P.t_off);
  if ((u32)lane < nc) {
    u64 me = kk[w][cand[w][lane]];
    u32 c = 0;
    for (u32 j = 0; j < nc; j++) c += (kk[w][cand[w][j]] < me) ? 1u : 0u;
    if (c == lr2) outp[r] = (u32)(me & 0xffffffffu);
  }
}

// gather sampled pixels (bilinear align_corners from 2048x2048 source)
__global__ void gather_kernel(const float* wimg, const float* timg,
                              const u32* idx, float* pix) {
  int t = blockIdx.x * blockDim.x + threadIdx.x;
  if (t >= 65536) return;
  int j = t & 4095;
  int img = (t >> 12) & 1;
  int l = t >> 13;
  int s = 16 << l;
  long long n = (long long)s * s;
  int M = (n < 4096) ? (int)n : 4096;
  if (j >= M) return;
  u32 p = (l < 3) ? (u32)j : idx[((l - 3) * 2 + img) * 4096 + j];
  const float* src = img ? timg : wimg;
  float o0, o1, o2;
  if (l == 7) {
    o0 = src[p];
    o1 = src[4194304 + p];
    o2 = src[8388608 + p];
  } else {
    u32 y = p / (u32)s, xq = p % (u32)s;
    float delta = 2047.0f / (float)(s - 1);
    float yc = (float)y * delta, xc = (float)xq * delta;
    int y0 = (int)floorf(yc); if (y0 > 2047) y0 = 2047;
    int x0 = (int)floorf(xc); if (x0 > 2047) x0 = 2047;
    int y1 = y0 + 1; if (y1 > 2047) y1 = 2047;
    int x1 = x0 + 1; if (x1 > 2047) x1 = 2047;
    float wy = yc - (float)y0, wx = xc - (float)x0;
    float out3[3];
    for (int c = 0; c < 3; c++) {
      const float* b = src + (size_t)c * 4194304;
      float v00 = b[y0 * 2048 + x0], v01 = b[y0 * 2048 + x1];
      float v10 = b[y1 * 2048 + x0], v11 = b[y1 * 2048 + x1];
      float r0 = v00 * (1.0f - wy) + v10 * wy;
      float r1 = v01 * (1.0f - wy) + v11 * wy;
      out3[c] = r0 * (1.0f - wx) + r1 * wx;
    }
    o0 = out3[0]; o1 = out3[1]; o2 = out3[2];
  }
  float* dst = pix + ((size_t)(l * 2 + img) * 4096 + j) * 3;
  dst[0] = o0; dst[1] = o1; dst[2] = o2;
}

// one block per (level, direction): project, bitonic sort, partial SSD.
// 1024 threads: 512 per array; j>=8 via LDS pair-steps, j=4,2,1 in registers.
__global__ void __launch_bounds__(1024) swd_kernel(
    const float* pix, const float* dirs, double* partials) {
  __shared__ float sw[4096];
  __shared__ float st[4096];
  __shared__ double wred[16];
  int b = blockIdx.x;
  int l = b >> 6, k = b & 63;
  int sdim = 16 << l;
  long long nn = (long long)sdim * sdim;
  int M = (nn < 4096) ? (int)nn : 4096;
  int tid = threadIdx.x;  // 1024
  int half = tid >> 9, t = tid & 511;
  float d0 = dirs[l * 192 + k * 3 + 0];
  float d1 = dirs[l * 192 + k * 3 + 1];
  float d2 = dirs[l * 192 + k * 3 + 2];
  float* A = half ? st : sw;
  const float* P = pix + (size_t)(l * 2 + half) * 4096 * 3;
  const float INF = __uint_as_float(0x7f800000u);
  for (int j = t; j < 4096; j += 512)
    A[j] = (j < M) ? (P[j * 3] * d0 + P[j * 3 + 1] * d1 + P[j * 3 + 2] * d2) : INF;
  __syncthreads();
#define CE(x, y, up) { if ((v[x] > v[y]) == (up)) { float tt = v[x]; v[x] = v[y]; v[y] = tt; } }
  for (u32 k2 = 2; k2 <= 4096; k2 <<= 1) {
    for (u32 j = k2 >> 1; j >= 8; j >>= 1) {
      for (u32 p = t; p < 2048; p += 512) {
        u32 i = ((p & ~(j - 1)) << 1) | (p & (j - 1));
        u32 ix = i | j;
        bool up = ((i & k2) == 0);
        float a = A[i], c = A[ix];
        if ((a > c) == up) { A[i] = c; A[ix] = a; }
      }
      __syncthreads();
    }
    // register tail: j = min(4, k2/2) .. 1; each thread owns 8 contiguous
    {
      u32 base = (u32)t * 8;
      float v[8];
      #pragma unroll
      for (int a = 0; a < 8; a++) v[a] = A[base + a];
      if (k2 == 2) {
        CE(0, 1, true) CE(2, 3, false) CE(4, 5, true) CE(6, 7, false)
      } else if (k2 == 4) {
        CE(0, 2, true) CE(1, 3, true) CE(4, 6, false) CE(5, 7, false)
        CE(0, 1, true) CE(2, 3, true) CE(4, 5, false) CE(6, 7, false)
      } else {
        bool up = ((base & k2) == 0);
        CE(0, 4, up) CE(1, 5, up) CE(2, 6, up) CE(3, 7, up)
        CE(0, 2, up) CE(1, 3, up) CE(4, 6, up) CE(5, 7, up)
        CE(0, 1, up) CE(2, 3, up) CE(4, 5, up) CE(6, 7, up)
      }
      #pragma unroll
      for (int a = 0; a < 8; a++) A[base + a] = v[a];
      __syncthreads();
    }
  }
#undef CE
  double sum = 0.0;
  if (half == 0) {
    for (int j = t; j < M; j += 512) {
      double df = (double)sw[j] - (double)st[j];
      sum += df * df;
    }
  }
  for (int off = 32; off >= 1; off >>= 1) sum += __shfl_down(sum, off);
  if ((tid & 63) == 0) wred[tid >> 6] = sum;
  __syncthreads();
  if (tid == 0) {
    double s2 = 0.0;
    for (int i = 0; i < 16; i++) s2 += wred[i];
    partials[b] = s2;
  }
}

__global__ void final_kernel(const double* partials, float* out) {
  if (threadIdx.x == 0 && blockIdx.x == 0) {
    double tot = 0.0;
    for (int l = 0; l < 8; l++) {
      int s = 16 << l;
      long long nn = (long long)s * s;
      int M = (nn < 4096) ? (int)nn : 4096;
      double sm = 0.0;
      for (int k = 0; k < 64; k++) sm += partials[l * 64 + k];
      tot += sm / (64.0 * (double)M);
    }
    out[0] = (float)tot;
  }
}

// ---------------- launch -----------------------------------------------------
extern "C" void kernel_launch(void* const* d_in, const int* in_sizes, int n_in,
                              void* d_out, int out_size, void* d_ws, size_t ws_size,
                              hipStream_t stream) {
  const float* wimg = (const float*)d_in[0];
  const float* timg = (const float*)d_in[1];
  float* out = (float*)d_out;
  char* ws = (char*)d_ws;

  // per-level static tables (lev 0..4 = pyramid levels 3..7)
  static const u32 Ln[5]    = {16384u, 65536u, 262144u, 1048576u, 4194304u};
  static const int LBB[5]   = {7, 9, 11, 13, 14};
  static const int LNB[5]   = {128, 512, 2048, 8192, 16384};
  static const int Lnblk[5] = {4, 8, 16, 32, 64};
  static const u32 Lhm[5]   = {0u, 1024u, 9216u, 74752u, 599040u};      // u16 elems
  static const u32 Lcnt[5]  = {0u, 256u, 1280u, 5376u, 21760u};          // u32 elems
  static const u32 Lrec[5]  = {0u, 32768u, 163840u, 688128u, 1998848u};  // u64 elems
  static const u32 Lcap[5]  = {32768u, 131072u, 524288u, 1310720u, 2621440u};
  const u32 HM_TOTAL = 2696192u;   // Σ nblk*NB2
  const u32 CNT_TOTAL = 54528u;    // Σ NB2
  const u32 REC_TOTAL = 4620288u;  // Σ caps

  size_t off = 0;
  auto alloc = [&](size_t bytes) -> void* {
    void* p = ws + off;
    off = (off + bytes + 255) & ~(size_t)255;
    return p;
  };
  u64* rec     = (u64*)alloc((size_t)REC_TOTAL * 8);   // 36.96 MB
  u16* histmat = (u16*)alloc((size_t)HM_TOTAL * 2);    // 5.39 MB
  u16* offT    = (u16*)alloc((size_t)HM_TOTAL * 2);    // 5.39 MB
  u32* cnt     = (u32*)alloc((size_t)CNT_TOTAL * 4);
  u32* fbase   = (u32*)alloc((size_t)CNT_TOTAL * 4);
  uint2* keyt  = (uint2*)alloc(64 * 8);
  u32* T       = (u32*)alloc(5ull * 8192 * 4);
  u32* tb      = (u32*)alloc(5ull * 8192 * 4);
  u32* lrarr   = (u32*)alloc(5ull * 8192 * 4);
  u32* idx     = (u32*)alloc(5ull * 8192 * 4);
  float* pix   = (float*)alloc(8ull * 2 * 4096 * 3 * 4);
  float* dirs  = (float*)alloc(8ull * 64 * 3 * 4);
  double* part = (double*)alloc(512 * 8);
  (void)ws_size; (void)in_sizes; (void)n_in; (void)out_size;

  hipLaunchKernelGGL(setup_kernel, dim3(1), dim3(512), 0, stream, keyt, dirs);

  // 3 super-rounds; within each: bhist -> bcolscan -> bplan -> bscatter -> brankfind
  for (int sr = 0; sr < 3; sr++) {
    Batch bt;
    int m = 0;
    u32 bs = 0, cs = 0;
    for (int lev = 0; lev < 5; lev++) {
      int R = (lev == 4) ? 3 : 2;
      int jr = R - sr;
      if (jr < 1) continue;
      Item& I = bt.it[m++];
      I.n = Ln[lev]; I.chunk = Ln[lev] / (u32)Lnblk[lev];
      I.BB = LBB[lev]; I.NB = LNB[lev]; I.nblk = Lnblk[lev];
      I.hm_off = Lhm[lev]; I.cnt_off = Lcnt[lev];
      I.rec_off = Lrec[lev]; I.rec_cap = Lcap[lev];
      I.blk_start = bs; bs += (u32)Lnblk[lev];
      I.col_start = cs; cs += (u32)((2 * LNB[lev] + 255) / 256);
      I.sub_base = 8 + lev * 6 + (jr - 1);
      I.first = (jr == R) ? 1 : 0;
      I.out_is_idx = (jr == 1) ? 1 : 0;
      I.t_off = (u32)lev * 8192u;
      I.out_off = (u32)lev * 8192u;
    }
    bt.nitems = m;
    hipLaunchKernelGGL(bhist_kernel, dim3(bs, 2), dim3(256), 0, stream,
                       histmat, keyt, bt);
    hipLaunchKernelGGL(bcolscan_kernel, dim3(cs), dim3(256), 0, stream,
                       histmat, offT, cnt, bt);
    hipLaunchKernelGGL(bplan_kernel, dim3(m), dim3(1024), 0, stream,
                       cnt, fbase, T, tb, lrarr, bt);
    hipLaunchKernelGGL(bscatter_kernel, dim3(bs, 2), dim3(256), 0, stream,
                       rec, offT, fbase, keyt, bt);
    hipLaunchKernelGGL(brankfind_kernel, dim3(2048, m), dim3(256), 0, stream,
                       rec, tb, lrarr, fbase, cnt, T, idx, bt);
  }

  hipLaunchKernelGGL(gather_kernel, dim3(256), dim3(256), 0, stream,
                     wimg, timg, idx, pix);
  hipLaunchKernelGGL(swd_kernel, dim3(512), dim3(1024), 0, stream,
                     pix, dirs, part);
  hipLaunchKernelGGL(final_kernel, dim3(1), dim3(1), 0, stream, part, out);
}

// Round 6
// 768.595 us; speedup vs baseline: 5.2218x; 1.2386x over previous
//
#include <hip/hip_runtime.h>
#include <stdint.h>

// ============================================================================
// DistributionLoss: SWD pyramid loss, exact JAX-RNG replication.
// Round 6: occupancy fix for hist/scatter — 1024-thread blocks (16 waves each,
// 2 blocks/CU = 100% wave occupancy) and 2x finer chunking (496-block grids).
// Selection math identical to round 5 (absmax 0.0).
// ============================================================================
#define JAX_PARTITIONABLE 1

typedef unsigned int u32;
typedef unsigned short u16;
typedef unsigned long long u64;

#define CAP     512         // max bucket entries in rankfind
#define MAXNB   16384       // max buckets per image (64KB LDS)

// ---------------- threefry2x32 (20 rounds), matches jax exactly -------------
__device__ __forceinline__ uint2 tf2(uint2 k, u32 x0, u32 x1) {
  u32 ks0 = k.x, ks1 = k.y, ks2 = k.x ^ k.y ^ 0x1BD11BDAu;
  x0 += ks0; x1 += ks1;
#define TF_RND(R) { x0 += x1; x1 = (x1 << (R)) | (x1 >> (32 - (R))); x1 ^= x0; }
  TF_RND(13) TF_RND(15) TF_RND(26) TF_RND(6)
  x0 += ks1; x1 += ks2 + 1u;
  TF_RND(17) TF_RND(29) TF_RND(16) TF_RND(24)
  x0 += ks2; x1 += ks0 + 2u;
  TF_RND(13) TF_RND(15) TF_RND(26) TF_RND(6)
  x0 += ks0; x1 += ks1 + 3u;
  TF_RND(17) TF_RND(29) TF_RND(16) TF_RND(24)
  x0 += ks1; x1 += ks2 + 4u;
  TF_RND(13) TF_RND(15) TF_RND(26) TF_RND(6)
  x0 += ks2; x1 += ks0 + 5u;
#undef TF_RND
  return make_uint2(x0, x1);
}

__device__ inline void split3(uint2 k, uint2* a, uint2* b, uint2* c) {
#if JAX_PARTITIONABLE
  *a = tf2(k, 0u, 0u); *b = tf2(k, 0u, 1u); *c = tf2(k, 0u, 2u);
#else
  uint2 p0 = tf2(k, 0u, 3u), p1 = tf2(k, 1u, 4u), p2 = tf2(k, 2u, 5u);
  *a = make_uint2(p0.x, p1.x); *b = make_uint2(p2.x, p0.y); *c = make_uint2(p1.y, p2.y);
#endif
}
__device__ inline void split2(uint2 k, uint2* nk, uint2* sub) {
#if JAX_PARTITIONABLE
  *nk = tf2(k, 0u, 0u); *sub = tf2(k, 0u, 1u);
#else
  uint2 p0 = tf2(k, 0u, 2u), p1 = tf2(k, 1u, 3u);
  *nk = make_uint2(p0.x, p1.x); *sub = make_uint2(p0.y, p1.y);
#endif
}
__device__ inline u32 normbits(uint2 kd, u32 idx) {
#if JAX_PARTITIONABLE
  uint2 o = tf2(kd, 0u, idx); return o.x ^ o.y;
#else
  if (idx < 96u) return tf2(kd, idx, idx + 96u).x;
  return tf2(kd, idx - 96u, idx).y;
#endif
}
__device__ inline u32 sortbits(uint2 sk, u32 p, u32 n) {
#if JAX_PARTITIONABLE
  uint2 o = tf2(sk, 0u, p); return o.x ^ o.y;
#else
  u32 h = n >> 1;
  if (p < h) return tf2(sk, p, p + h).x;
  return tf2(sk, p - h, p).y;
#endif
}

// ---------------- erfinv ----------------------------------------------------
__device__ inline double erfinv_d(double x) {
  double w = -log1p(-x * x);
  double p;
  if (w < 5.0) {
    w -= 2.5;
    p = 2.81022636e-08;
    p = 3.43273939e-07 + p * w;
    p = -3.5233877e-06 + p * w;
    p = -4.39150654e-06 + p * w;
    p = 0.00021858087 + p * w;
    p = -0.00125372503 + p * w;
    p = -0.00417768164 + p * w;
    p = 0.246640727 + p * w;
    p = 1.50140941 + p * w;
  } else {
    w = sqrt(w) - 3.0;
    p = -0.000200214257;
    p = 0.000100950558 + p * w;
    p = 0.00134934322 + p * w;
    p = -0.00367342844 + p * w;
    p = 0.00573950773 + p * w;
    p = -0.0076224613 + p * w;
    p = 0.00943887047 + p * w;
    p = 1.00167406 + p * w;
    p = 2.83297682 + p * w;
  }
  double y = p * x;
  for (int it = 0; it < 2; ++it) {
    double e = erf(y) - x;
    y -= e * 0.88622692545275801364 * exp(y * y);
  }
  return y;
}

// ---------------- batched pipeline descriptors ------------------------------
struct Item {
  u32 n, chunk;
  int BB, NB, nblk;
  u32 hm_off;     // u16-element offset into histmat/offT
  u32 cnt_off;    // u32-element offset into cnt/fbase
  u32 rec_off;    // u64-element offset into rec
  u32 rec_cap;
  u32 blk_start;  // hist/scatter grid.x prefix
  u32 col_start;  // colscan grid.x prefix
  int sub_base;   // keytab index: 8 + lev*6 + (jr-1); +img*3 at runtime
  int first;      // targets are ranks 0..4095 (first round)
  int out_is_idx; // final round -> write idx, else write T
  u32 t_off;      // per-level offset into T/tb/lrarr (lev*8192)
  u32 out_off;    // per-level offset into idx (lev*8192)
};
struct Batch { int nitems; Item it[5]; };

__device__ inline int find_item_blk(const Batch& bt, u32 bx) {
  int it = 0;
  for (int i = 1; i < bt.nitems; i++) if (bx >= bt.it[i].blk_start) it = i;
  return it;
}
__device__ inline int find_item_col(const Batch& bt, u32 bx) {
  int it = 0;
  for (int i = 1; i < bt.nitems; i++) if (bx >= bt.it[i].col_start) it = i;
  return it;
}

// ---------------- kernels ---------------------------------------------------

// keytab: [0..7] kd per level; [8 + lev*6 + img*3 + (r-1)] sort subkeys.
// Also computes the 8*64 unit directions.
__global__ void __launch_bounds__(512) setup_kernel(uint2* keytab, float* dirs) {
  __shared__ uint2 kt[64];
  if (threadIdx.x == 0) {
    uint2 base = make_uint2(0u, 42u);
    for (int l = 0; l < 8; l++) {
      uint2 kl = tf2(base, 0u, (u32)l);
      uint2 kd, kw, kt3;
      split3(kl, &kd, &kw, &kt3);
      kt[l] = kd;
      if (l >= 3) {
        for (int img = 0; img < 2; img++) {
          uint2 kp = img ? kt3 : kw;
          for (int r = 0; r < 3; r++) {
            uint2 nk, sub;
            split2(kp, &nk, &sub);
            kt[8 + (l - 3) * 6 + img * 3 + r] = sub;
            kp = nk;
          }
        }
      }
    }
  }
  __syncthreads();
  if (threadIdx.x < 38) keytab[threadIdx.x] = kt[threadIdx.x];
  int t = threadIdx.x;  // 512 = 8 levels * 64 dirs
  int l = t >> 6, k = t & 63;
  uint2 kd = kt[l];
  const float lo = -0.9999999403953552f;
  float dv[3];
  for (int c = 0; c < 3; c++) {
    u32 bits = normbits(kd, (u32)(k * 3 + c));
    float f = __uint_as_float((bits >> 9) | 0x3f800000u) - 1.0f;
    float u = f * 2.0f + lo;
    if (u < lo) u = lo;
    dv[c] = 1.4142135f * (float)erfinv_d((double)u);
  }
  float nrm = sqrtf(dv[0] * dv[0] + dv[1] * dv[1] + dv[2] * dv[2]);
  for (int c = 0; c < 3; c++) dirs[l * 192 + k * 3 + c] = dv[c] / nrm;
}

// per-block LDS histogram, flushed to a private u16 row (no global atomics)
// 1024 threads (16 waves) -> 2 blocks/CU fills all 32 wave slots.
__global__ void __launch_bounds__(1024, 8) bhist_kernel(
    u16* histmat, const uint2* keytab, Batch bt) {
  __shared__ u32 lh[MAXNB];
  int item = find_item_blk(bt, blockIdx.x);
  const Item P = bt.it[item];
  int blk = (int)blockIdx.x - (int)P.blk_start;
  int img = blockIdx.y;
  for (int b = threadIdx.x; b < P.NB; b += 1024) lh[b] = 0u;
  __syncthreads();
  uint2 sk = keytab[P.sub_base + img * 3];
  u32 q0 = (u32)blk * P.chunk, q1 = q0 + P.chunk;
  if (q1 > P.n) q1 = P.n;
  for (u32 q = q0 + threadIdx.x; q < q1; q += 1024) {
    u32 b = sortbits(sk, q, P.n) >> (32 - P.BB);
    atomicAdd(&lh[b], 1u);
  }
  __syncthreads();
  u16* row = histmat + P.hm_off + ((size_t)blk * 2 + img) * P.NB;
  for (int b = threadIdx.x; b < P.NB; b += 1024) row[b] = (u16)lh[b];
}

// per-bucket exclusive scan across blocks -> offT (u16); totals -> cnt (u32)
__global__ void __launch_bounds__(256) bcolscan_kernel(
    const u16* histmat, u16* offT, u32* cnt, Batch bt) {
  int item = find_item_col(bt, blockIdx.x);
  const Item P = bt.it[item];
  int NB2 = 2 * P.NB;
  int gb = ((int)blockIdx.x - (int)P.col_start) * 256 + threadIdx.x;
  if (gb >= NB2) return;
  u32 run = 0;
  for (int blk = 0; blk < P.nblk; blk++) {
    size_t ix = P.hm_off + (size_t)blk * NB2 + gb;
    offT[ix] = (u16)run;
    run += histmat[ix];
  }
  cnt[P.cnt_off + gb] = run;
}

// one block per item: rank-scan cnt, locate targets, flag buckets (bit31),
// compact-scan flagged -> fbase (0xFFFFFFFF sentinel for unflagged).
__global__ void __launch_bounds__(1024) bplan_kernel(
    const u32* cnt, u32* fbase, const u32* Tbuf, u32* tb, u32* lrarr,
    Batch bt) {
  __shared__ u32 sBase[2 * MAXNB];   // 128KB
  __shared__ u32 part[1024];
  const u32 MASK = 0x7fffffffu;
  const Item P = bt.it[blockIdx.x];
  int NB = P.NB, NB2 = 2 * NB;
  u32 n = P.n;
  const u32* cntp = cnt + P.cnt_off;
  int tid = threadIdx.x;
  int chunk = (NB2 + 1023) >> 10;
  int s = tid * chunk, e = s + chunk;
  if (e > NB2) e = NB2;
  if (s > NB2) s = NB2;
  // phase 1: exclusive scan of cnt into sBase (per-image adjusted)
  u32 sum = 0;
  for (int i = s; i < e; i++) sum += cntp[i];
  part[tid] = sum;
  __syncthreads();
  for (int off = 1; off < 1024; off <<= 1) {
    u32 v = (tid >= off) ? part[tid - off] : 0u;
    __syncthreads();
    part[tid] += v;
    __syncthreads();
  }
  u32 run = part[tid] - sum;
  for (int i = s; i < e; i++) {
    sBase[i] = run - ((i >= NB) ? n : 0u);
    run += cntp[i];
  }
  __syncthreads();
  // phase 2: per-target binary search; flag bucket via bit31
  for (int r = tid; r < 8192; r += 1024) {
    int img = r >> 12;
    u32 t = P.first ? (u32)(r & 4095) : Tbuf[P.t_off + r];
    const u32* B = sBase + img * NB;
    int lo = 0, hi = NB - 1;
    while (lo < hi) {
      int mid = (lo + hi + 1) >> 1;
      if ((B[mid] & MASK) <= t) lo = mid; else hi = mid - 1;
    }
    tb[P.t_off + r] = (u32)(img * NB + lo);
    lrarr[P.t_off + r] = t - (B[lo] & MASK);
    atomicOr(&sBase[img * NB + lo], 0x80000000u);
  }
  __syncthreads();
  // phase 3: compact exclusive scan over flagged bucket counts -> fbase
  u32 vs = 0;
  for (int i = s; i < e; i++) vs += (sBase[i] >> 31) ? cntp[i] : 0u;
  part[tid] = vs;
  __syncthreads();
  for (int off = 1; off < 1024; off <<= 1) {
    u32 v = (tid >= off) ? part[tid - off] : 0u;
    __syncthreads();
    part[tid] += v;
    __syncthreads();
  }
  u32 run2 = part[tid] - vs;
  for (int i = s; i < e; i++) {
    if (sBase[i] >> 31) {
      fbase[P.cnt_off + i] = run2;
      run2 += cntp[i];
    } else {
      fbase[P.cnt_off + i] = 0xFFFFFFFFu;
    }
  }
}

// scatter flagged-bucket elements to compact storage via LDS cursors only
__global__ void __launch_bounds__(1024, 8) bscatter_kernel(
    u64* rec, const u16* offT, const u32* fbase, const uint2* keytab,
    Batch bt) {
  __shared__ u32 cursor[MAXNB];
  int item = find_item_blk(bt, blockIdx.x);
  const Item P = bt.it[item];
  int blk = (int)blockIdx.x - (int)P.blk_start;
  int img = blockIdx.y;
  int NB2 = 2 * P.NB;
  const u16* orow = offT + P.hm_off + (size_t)blk * NB2 + (size_t)img * P.NB;
  const u32* frow = fbase + P.cnt_off + (size_t)img * P.NB;
  for (int b = threadIdx.x; b < P.NB; b += 1024) {
    u32 fb = frow[b];
    cursor[b] = (fb == 0xFFFFFFFFu) ? 0xFFFFFFFFu : P.rec_off + fb + orow[b];
  }
  __syncthreads();
  uint2 sk = keytab[P.sub_base + img * 3];
  u32 limit = P.rec_off + P.rec_cap;
  u32 q0 = (u32)blk * P.chunk, q1 = q0 + P.chunk;
  if (q1 > P.n) q1 = P.n;
  for (u32 q = q0 + threadIdx.x; q < q1; q += 1024) {
    u32 bits = sortbits(sk, q, P.n);
    u32 b = bits >> (32 - P.BB);
    if (cursor[b] != 0xFFFFFFFFu) {
      u32 slot = atomicAdd(&cursor[b], 1u);
      if (slot < limit) rec[slot] = ((u64)bits << 32) | (u64)q;
    }
  }
}

// wave-per-target rank find: 64-lane sub-radix (6 bits), shfl scan, no
// block-wide scans. 4 waves (targets) per 256-thread block.
__global__ void __launch_bounds__(256) brankfind_kernel(
    const u64* rec, const u32* tb, const u32* lrarr, const u32* fbase,
    const u32* cnt, u32* Tbuf, u32* idx, Batch bt) {
  __shared__ u64 kk[4][CAP];
  __shared__ u32 bins[4][64];
  __shared__ u32 cand[4][64];
  __shared__ u32 ncand_s[4];
  const Item P = bt.it[blockIdx.y];
  int w = threadIdx.x >> 6;       // wave id 0..3
  int lane = threadIdx.x & 63;
  int r = blockIdx.x * 4 + w;     // target id 0..8191
  u32 gb = tb[P.t_off + r];
  u32 lr = lrarr[P.t_off + r];
  u32 s0 = P.rec_off + fbase[P.cnt_off + gb];
  u32 m = cnt[P.cnt_off + gb];
  if (m > CAP) m = CAP;
  int shamt = 26 - P.BB;          // 6 sub-radix bits just below bucket bits
  bins[w][lane] = 0u;
  if (lane == 0) ncand_s[w] = 0u;
  for (u32 i = lane; i < m; i += 64) kk[w][i] = rec[s0 + i];
  __syncthreads();
  for (u32 i = lane; i < m; i += 64)
    atomicAdd(&bins[w][((u32)(kk[w][i] >> 32) >> shamt) & 63u], 1u);
  __syncthreads();
  // wave-inclusive scan of 64 bins (lane l holds bin l)
  u32 own = bins[w][lane];
  u32 incl = own;
  #pragma unroll
  for (int d = 1; d < 64; d <<= 1) {
    u32 v = __shfl_up(incl, d, 64);
    if (lane >= d) incl += v;
  }
  u32 excl = incl - own;
  u64 mask = __ballot(excl <= lr && lr < incl);
  int sb = __ffsll((long long)mask) - 1;
  u32 sexcl = __shfl(excl, sb, 64);
  u32 lr2 = lr - sexcl;
  // collect candidate indices (entries whose sub-bucket == sb)
  for (u32 i = lane; i < m; i += 64) {
    if ((((u32)(kk[w][i] >> 32) >> shamt) & 63u) == (u32)sb) {
      u32 pos = atomicAdd(&ncand_s[w], 1u);
      if (pos < 64u) cand[w][pos] = i;
    }
  }
  __syncthreads();
  u32 nc = ncand_s[w];
  if (nc > 64u) nc = 64u;
  u32* outp = P.out_is_idx ? (idx + P.out_off) : (Tbuf + P.t_off);
  if ((u32)lane < nc) {
    u64 me = kk[w][cand[w][lane]];
    u32 c = 0;
    for (u32 j = 0; j < nc; j++) c += (kk[w][cand[w][j]] < me) ? 1u : 0u;
    if (c == lr2) outp[r] = (u32)(me & 0xffffffffu);
  }
}

// gather sampled pixels (bilinear align_corners from 2048x2048 source)
__global__ void gather_kernel(const float* wimg, const float* timg,
                              const u32* idx, float* pix) {
  int t = blockIdx.x * blockDim.x + threadIdx.x;
  if (t >= 65536) return;
  int j = t & 4095;
  int img = (t >> 12) & 1;
  int l = t >> 13;
  int s = 16 << l;
  long long n = (long long)s * s;
  int M = (n < 4096) ? (int)n : 4096;
  if (j >= M) return;
  u32 p = (l < 3) ? (u32)j : idx[((l - 3) * 2 + img) * 4096 + j];
  const float* src = img ? timg : wimg;
  float o0, o1, o2;
  if (l == 7) {
    o0 = src[p];
    o1 = src[4194304 + p];
    o2 = src[8388608 + p];
  } else {
    u32 y = p / (u32)s, xq = p % (u32)s;
    float delta = 2047.0f / (float)(s - 1);
    float yc = (float)y * delta, xc = (float)xq * delta;
    int y0 = (int)floorf(yc); if (y0 > 2047) y0 = 2047;
    int x0 = (int)floorf(xc); if (x0 > 2047) x0 = 2047;
    int y1 = y0 + 1; if (y1 > 2047) y1 = 2047;
    int x1 = x0 + 1; if (x1 > 2047) x1 = 2047;
    float wy = yc - (float)y0, wx = xc - (float)x0;
    float out3[3];
    for (int c = 0; c < 3; c++) {
      const float* b = src + (size_t)c * 4194304;
      float v00 = b[y0 * 2048 + x0], v01 = b[y0 * 2048 + x1];
      float v10 = b[y1 * 2048 + x0], v11 = b[y1 * 2048 + x1];
      float r0 = v00 * (1.0f - wy) + v10 * wy;
      float r1 = v01 * (1.0f - wy) + v11 * wy;
      out3[c] = r0 * (1.0f - wx) + r1 * wx;
    }
    o0 = out3[0]; o1 = out3[1]; o2 = out3[2];
  }
  float* dst = pix + ((size_t)(l * 2 + img) * 4096 + j) * 3;
  dst[0] = o0; dst[1] = o1; dst[2] = o2;
}

// one block per (level, direction): project, bitonic sort, partial SSD.
// 1024 threads: 512 per array; j>=8 via LDS pair-steps, j=4,2,1 in registers.
__global__ void __launch_bounds__(1024) swd_kernel(
    const float* pix, const float* dirs, double* partials) {
  __shared__ float sw[4096];
  __shared__ float st[4096];
  __shared__ double wred[16];
  int b = blockIdx.x;
  int l = b >> 6, k = b & 63;
  int sdim = 16 << l;
  long long nn = (long long)sdim * sdim;
  int M = (nn < 4096) ? (int)nn : 4096;
  int tid = threadIdx.x;  // 1024
  int half = tid >> 9, t = tid & 511;
  float d0 = dirs[l * 192 + k * 3 + 0];
  float d1 = dirs[l * 192 + k * 3 + 1];
  float d2 = dirs[l * 192 + k * 3 + 2];
  float* A = half ? st : sw;
  const float* P = pix + (size_t)(l * 2 + half) * 4096 * 3;
  const float INF = __uint_as_float(0x7f800000u);
  for (int j = t; j < 4096; j += 512)
    A[j] = (j < M) ? (P[j * 3] * d0 + P[j * 3 + 1] * d1 + P[j * 3 + 2] * d2) : INF;
  __syncthreads();
#define CE(x, y, up) { if ((v[x] > v[y]) == (up)) { float tt = v[x]; v[x] = v[y]; v[y] = tt; } }
  for (u32 k2 = 2; k2 <= 4096; k2 <<= 1) {
    for (u32 j = k2 >> 1; j >= 8; j >>= 1) {
      for (u32 p = t; p < 2048; p += 512) {
        u32 i = ((p & ~(j - 1)) << 1) | (p & (j - 1));
        u32 ix = i | j;
        bool up = ((i & k2) == 0);
        float a = A[i], c = A[ix];
        if ((a > c) == up) { A[i] = c; A[ix] = a; }
      }
      __syncthreads();
    }
    // register tail: j = min(4, k2/2) .. 1; each thread owns 8 contiguous
    {
      u32 base = (u32)t * 8;
      float v[8];
      #pragma unroll
      for (int a = 0; a < 8; a++) v[a] = A[base + a];
      if (k2 == 2) {
        CE(0, 1, true) CE(2, 3, false) CE(4, 5, true) CE(6, 7, false)
      } else if (k2 == 4) {
        CE(0, 2, true) CE(1, 3, true) CE(4, 6, false) CE(5, 7, false)
        CE(0, 1, true) CE(2, 3, true) CE(4, 5, false) CE(6, 7, false)
      } else {
        bool up = ((base & k2) == 0);
        CE(0, 4, up) CE(1, 5, up) CE(2, 6, up) CE(3, 7, up)
        CE(0, 2, up) CE(1, 3, up) CE(4, 6, up) CE(5, 7, up)
        CE(0, 1, up) CE(2, 3, up) CE(4, 5, up) CE(6, 7, up)
      }
      #pragma unroll
      for (int a = 0; a < 8; a++) A[base + a] = v[a];
      __syncthreads();
    }
  }
#undef CE
  double sum = 0.0;
  if (half == 0) {
    for (int j = t; j < M; j += 512) {
      double df = (double)sw[j] - (double)st[j];
      sum += df * df;
    }
  }
  for (int off = 32; off >= 1; off >>= 1) sum += __shfl_down(sum, off);
  if ((tid & 63) == 0) wred[tid >> 6] = sum;
  __syncthreads();
  if (tid == 0) {
    double s2 = 0.0;
    for (int i = 0; i < 16; i++) s2 += wred[i];
    partials[b] = s2;
  }
}

__global__ void final_kernel(const double* partials, float* out) {
  if (threadIdx.x == 0 && blockIdx.x == 0) {
    double tot = 0.0;
    for (int l = 0; l < 8; l++) {
      int s = 16 << l;
      long long nn = (long long)s * s;
      int M = (nn < 4096) ? (int)nn : 4096;
      double sm = 0.0;
      for (int k = 0; k < 64; k++) sm += partials[l * 64 + k];
      tot += sm / (64.0 * (double)M);
    }
    out[0] = (float)tot;
  }
}

// ---------------- launch -----------------------------------------------------
extern "C" void kernel_launch(void* const* d_in, const int* in_sizes, int n_in,
                              void* d_out, int out_size, void* d_ws, size_t ws_size,
                              hipStream_t stream) {
  const float* wimg = (const float*)d_in[0];
  const float* timg = (const float*)d_in[1];
  float* out = (float*)d_out;
  char* ws = (char*)d_ws;

  // per-level static tables (lev 0..4 = pyramid levels 3..7)
  static const u32 Ln[5]    = {16384u, 65536u, 262144u, 1048576u, 4194304u};
  static const int LBB[5]   = {7, 9, 11, 13, 14};
  static const int LNB[5]   = {128, 512, 2048, 8192, 16384};
  static const int Lnblk[5] = {8, 16, 32, 64, 128};
  static const u32 Lhm[5]   = {0u, 2048u, 18432u, 149504u, 1198080u};    // u16 elems
  static const u32 Lcnt[5]  = {0u, 256u, 1280u, 5376u, 21760u};          // u32 elems
  static const u32 Lrec[5]  = {0u, 32768u, 163840u, 688128u, 1998848u};  // u64 elems
  static const u32 Lcap[5]  = {32768u, 131072u, 524288u, 1310720u, 2621440u};
  const u32 HM_TOTAL = 5392384u;   // Σ nblk*NB2
  const u32 CNT_TOTAL = 54528u;    // Σ NB2
  const u32 REC_TOTAL = 4620288u;  // Σ caps

  size_t off = 0;
  auto alloc = [&](size_t bytes) -> void* {
    void* p = ws + off;
    off = (off + bytes + 255) & ~(size_t)255;
    return p;
  };
  u64* rec     = (u64*)alloc((size_t)REC_TOTAL * 8);   // 36.96 MB
  u16* histmat = (u16*)alloc((size_t)HM_TOTAL * 2);    // 10.78 MB
  u16* offT    = (u16*)alloc((size_t)HM_TOTAL * 2);    // 10.78 MB
  u32* cnt     = (u32*)alloc((size_t)CNT_TOTAL * 4);
  u32* fbase   = (u32*)alloc((size_t)CNT_TOTAL * 4);
  uint2* keyt  = (uint2*)alloc(64 * 8);
  u32* T       = (u32*)alloc(5ull * 8192 * 4);
  u32* tb      = (u32*)alloc(5ull * 8192 * 4);
  u32* lrarr   = (u32*)alloc(5ull * 8192 * 4);
  u32* idx     = (u32*)alloc(5ull * 8192 * 4);
  float* pix   = (float*)alloc(8ull * 2 * 4096 * 3 * 4);
  float* dirs  = (float*)alloc(8ull * 64 * 3 * 4);
  double* part = (double*)alloc(512 * 8);
  (void)ws_size; (void)in_sizes; (void)n_in; (void)out_size;

  hipLaunchKernelGGL(setup_kernel, dim3(1), dim3(512), 0, stream, keyt, dirs);

  // 3 super-rounds; within each: bhist -> bcolscan -> bplan -> bscatter -> brankfind
  for (int sr = 0; sr < 3; sr++) {
    Batch bt;
    int m = 0;
    u32 bs = 0, cs = 0;
    for (int lev = 0; lev < 5; lev++) {
      int R = (lev == 4) ? 3 : 2;
      int jr = R - sr;
      if (jr < 1) continue;
      Item& I = bt.it[m++];
      I.n = Ln[lev]; I.chunk = Ln[lev] / (u32)Lnblk[lev];
      I.BB = LBB[lev]; I.NB = LNB[lev]; I.nblk = Lnblk[lev];
      I.hm_off = Lhm[lev]; I.cnt_off = Lcnt[lev];
      I.rec_off = Lrec[lev]; I.rec_cap = Lcap[lev];
      I.blk_start = bs; bs += (u32)Lnblk[lev];
      I.col_start = cs; cs += (u32)((2 * LNB[lev] + 255) / 256);
      I.sub_base = 8 + lev * 6 + (jr - 1);
      I.first = (jr == R) ? 1 : 0;
      I.out_is_idx = (jr == 1) ? 1 : 0;
      I.t_off = (u32)lev * 8192u;
      I.out_off = (u32)lev * 8192u;
    }
    bt.nitems = m;
    hipLaunchKernelGGL(bhist_kernel, dim3(bs, 2), dim3(1024), 0, stream,
                       histmat, keyt, bt);
    hipLaunchKernelGGL(bcolscan_kernel, dim3(cs), dim3(256), 0, stream,
                       histmat, offT, cnt, bt);
    hipLaunchKernelGGL(bplan_kernel, dim3(m), dim3(1024), 0, stream,
                       cnt, fbase, T, tb, lrarr, bt);
    hipLaunchKernelGGL(bscatter_kernel, dim3(bs, 2), dim3(1024), 0, stream,
                       rec, offT, fbase, keyt, bt);
    hipLaunchKernelGGL(brankfind_kernel, dim3(2048, m), dim3(256), 0, stream,
                       rec, tb, lrarr, fbase, cnt, T, idx, bt);
  }

  hipLaunchKernelGGL(gather_kernel, dim3(256), dim3(256), 0, stream,
                     wimg, timg, idx, pix);
  hipLaunchKernelGGL(swd_kernel, dim3(512), dim3(1024), 0, stream,
                     pix, dirs, part);
  hipLaunchKernelGGL(final_kernel, dim3(1), dim3(1), 0, stream, part, out);
}

// Round 7
// 716.436 us; speedup vs baseline: 5.6020x; 1.0728x over previous
//
#include <hip/hip_runtime.h>
#include <stdint.h>

// ============================================================================
// DistributionLoss: SWD pyramid loss, exact JAX-RNG replication.
// Round 7: bplan bank-conflict fix — padded sBase indexing (SIDX) turns the
// 64-way same-bank chunk access into a free 2-way alias; two-level shfl scan
// replaces the 20-barrier block scan. Outputs bit-identical to round 6.
// ============================================================================
#define JAX_PARTITIONABLE 1

typedef unsigned int u32;
typedef unsigned short u16;
typedef unsigned long long u64;

#define CAP     512         // max bucket entries in rankfind
#define MAXNB   16384       // max buckets per image (64KB LDS)
#define SIDX(i) ((i) + ((i) >> 5))   // LDS pad map: +1 word per 32

// ---------------- threefry2x32 (20 rounds), matches jax exactly -------------
__device__ __forceinline__ uint2 tf2(uint2 k, u32 x0, u32 x1) {
  u32 ks0 = k.x, ks1 = k.y, ks2 = k.x ^ k.y ^ 0x1BD11BDAu;
  x0 += ks0; x1 += ks1;
#define TF_RND(R) { x0 += x1; x1 = (x1 << (R)) | (x1 >> (32 - (R))); x1 ^= x0; }
  TF_RND(13) TF_RND(15) TF_RND(26) TF_RND(6)
  x0 += ks1; x1 += ks2 + 1u;
  TF_RND(17) TF_RND(29) TF_RND(16) TF_RND(24)
  x0 += ks2; x1 += ks0 + 2u;
  TF_RND(13) TF_RND(15) TF_RND(26) TF_RND(6)
  x0 += ks0; x1 += ks1 + 3u;
  TF_RND(17) TF_RND(29) TF_RND(16) TF_RND(24)
  x0 += ks1; x1 += ks2 + 4u;
  TF_RND(13) TF_RND(15) TF_RND(26) TF_RND(6)
  x0 += ks2; x1 += ks0 + 5u;
#undef TF_RND
  return make_uint2(x0, x1);
}

__device__ inline void split3(uint2 k, uint2* a, uint2* b, uint2* c) {
#if JAX_PARTITIONABLE
  *a = tf2(k, 0u, 0u); *b = tf2(k, 0u, 1u); *c = tf2(k, 0u, 2u);
#else
  uint2 p0 = tf2(k, 0u, 3u), p1 = tf2(k, 1u, 4u), p2 = tf2(k, 2u, 5u);
  *a = make_uint2(p0.x, p1.x); *b = make_uint2(p2.x, p0.y); *c = make_uint2(p1.y, p2.y);
#endif
}
__device__ inline void split2(uint2 k, uint2* nk, uint2* sub) {
#if JAX_PARTITIONABLE
  *nk = tf2(k, 0u, 0u); *sub = tf2(k, 0u, 1u);
#else
  uint2 p0 = tf2(k, 0u, 2u), p1 = tf2(k, 1u, 3u);
  *nk = make_uint2(p0.x, p1.x); *sub = make_uint2(p0.y, p1.y);
#endif
}
__device__ inline u32 normbits(uint2 kd, u32 idx) {
#if JAX_PARTITIONABLE
  uint2 o = tf2(kd, 0u, idx); return o.x ^ o.y;
#else
  if (idx < 96u) return tf2(kd, idx, idx + 96u).x;
  return tf2(kd, idx - 96u, idx).y;
#endif
}
__device__ inline u32 sortbits(uint2 sk, u32 p, u32 n) {
#if JAX_PARTITIONABLE
  uint2 o = tf2(sk, 0u, p); return o.x ^ o.y;
#else
  u32 h = n >> 1;
  if (p < h) return tf2(sk, p, p + h).x;
  return tf2(sk, p - h, p).y;
#endif
}

// ---------------- erfinv ----------------------------------------------------
__device__ inline double erfinv_d(double x) {
  double w = -log1p(-x * x);
  double p;
  if (w < 5.0) {
    w -= 2.5;
    p = 2.81022636e-08;
    p = 3.43273939e-07 + p * w;
    p = -3.5233877e-06 + p * w;
    p = -4.39150654e-06 + p * w;
    p = 0.00021858087 + p * w;
    p = -0.00125372503 + p * w;
    p = -0.00417768164 + p * w;
    p = 0.246640727 + p * w;
    p = 1.50140941 + p * w;
  } else {
    w = sqrt(w) - 3.0;
    p = -0.000200214257;
    p = 0.000100950558 + p * w;
    p = 0.00134934322 + p * w;
    p = -0.00367342844 + p * w;
    p = 0.00573950773 + p * w;
    p = -0.0076224613 + p * w;
    p = 0.00943887047 + p * w;
    p = 1.00167406 + p * w;
    p = 2.83297682 + p * w;
  }
  double y = p * x;
  for (int it = 0; it < 2; ++it) {
    double e = erf(y) - x;
    y -= e * 0.88622692545275801364 * exp(y * y);
  }
  return y;
}

// ---------------- batched pipeline descriptors ------------------------------
struct Item {
  u32 n, chunk;
  int BB, NB, nblk;
  u32 hm_off;     // u16-element offset into histmat/offT
  u32 cnt_off;    // u32-element offset into cnt/fbase
  u32 rec_off;    // u64-element offset into rec
  u32 rec_cap;
  u32 blk_start;  // hist/scatter grid.x prefix
  u32 col_start;  // colscan grid.x prefix
  int sub_base;   // keytab index: 8 + lev*6 + (jr-1); +img*3 at runtime
  int first;      // targets are ranks 0..4095 (first round)
  int out_is_idx; // final round -> write idx, else write T
  u32 t_off;      // per-level offset into T/tb/lrarr (lev*8192)
  u32 out_off;    // per-level offset into idx (lev*8192)
};
struct Batch { int nitems; Item it[5]; };

__device__ inline int find_item_blk(const Batch& bt, u32 bx) {
  int it = 0;
  for (int i = 1; i < bt.nitems; i++) if (bx >= bt.it[i].blk_start) it = i;
  return it;
}
__device__ inline int find_item_col(const Batch& bt, u32 bx) {
  int it = 0;
  for (int i = 1; i < bt.nitems; i++) if (bx >= bt.it[i].col_start) it = i;
  return it;
}

// ---------------- kernels ---------------------------------------------------

// keytab: [0..7] kd per level; [8 + lev*6 + img*3 + (r-1)] sort subkeys.
// Also computes the 8*64 unit directions.
__global__ void __launch_bounds__(512) setup_kernel(uint2* keytab, float* dirs) {
  __shared__ uint2 kt[64];
  if (threadIdx.x == 0) {
    uint2 base = make_uint2(0u, 42u);
    for (int l = 0; l < 8; l++) {
      uint2 kl = tf2(base, 0u, (u32)l);
      uint2 kd, kw, kt3;
      split3(kl, &kd, &kw, &kt3);
      kt[l] = kd;
      if (l >= 3) {
        for (int img = 0; img < 2; img++) {
          uint2 kp = img ? kt3 : kw;
          for (int r = 0; r < 3; r++) {
            uint2 nk, sub;
            split2(kp, &nk, &sub);
            kt[8 + (l - 3) * 6 + img * 3 + r] = sub;
            kp = nk;
          }
        }
      }
    }
  }
  __syncthreads();
  if (threadIdx.x < 38) keytab[threadIdx.x] = kt[threadIdx.x];
  int t = threadIdx.x;  // 512 = 8 levels * 64 dirs
  int l = t >> 6, k = t & 63;
  uint2 kd = kt[l];
  const float lo = -0.9999999403953552f;
  float dv[3];
  for (int c = 0; c < 3; c++) {
    u32 bits = normbits(kd, (u32)(k * 3 + c));
    float f = __uint_as_float((bits >> 9) | 0x3f800000u) - 1.0f;
    float u = f * 2.0f + lo;
    if (u < lo) u = lo;
    dv[c] = 1.4142135f * (float)erfinv_d((double)u);
  }
  float nrm = sqrtf(dv[0] * dv[0] + dv[1] * dv[1] + dv[2] * dv[2]);
  for (int c = 0; c < 3; c++) dirs[l * 192 + k * 3 + c] = dv[c] / nrm;
}

// per-block LDS histogram, flushed to a private u16 row (no global atomics)
// 1024 threads (16 waves) -> 2 blocks/CU fills all 32 wave slots.
__global__ void __launch_bounds__(1024, 8) bhist_kernel(
    u16* histmat, const uint2* keytab, Batch bt) {
  __shared__ u32 lh[MAXNB];
  int item = find_item_blk(bt, blockIdx.x);
  const Item P = bt.it[item];
  int blk = (int)blockIdx.x - (int)P.blk_start;
  int img = blockIdx.y;
  for (int b = threadIdx.x; b < P.NB; b += 1024) lh[b] = 0u;
  __syncthreads();
  uint2 sk = keytab[P.sub_base + img * 3];
  u32 q0 = (u32)blk * P.chunk, q1 = q0 + P.chunk;
  if (q1 > P.n) q1 = P.n;
  for (u32 q = q0 + threadIdx.x; q < q1; q += 1024) {
    u32 b = sortbits(sk, q, P.n) >> (32 - P.BB);
    atomicAdd(&lh[b], 1u);
  }
  __syncthreads();
  u16* row = histmat + P.hm_off + ((size_t)blk * 2 + img) * P.NB;
  for (int b = threadIdx.x; b < P.NB; b += 1024) row[b] = (u16)lh[b];
}

// per-bucket exclusive scan across blocks -> offT (u16); totals -> cnt (u32)
__global__ void __launch_bounds__(256) bcolscan_kernel(
    const u16* histmat, u16* offT, u32* cnt, Batch bt) {
  int item = find_item_col(bt, blockIdx.x);
  const Item P = bt.it[item];
  int NB2 = 2 * P.NB;
  int gb = ((int)blockIdx.x - (int)P.col_start) * 256 + threadIdx.x;
  if (gb >= NB2) return;
  u32 run = 0;
  for (int blk = 0; blk < P.nblk; blk++) {
    size_t ix = P.hm_off + (size_t)blk * NB2 + gb;
    offT[ix] = (u16)run;
    run += histmat[ix];
  }
  cnt[P.cnt_off + gb] = run;
}

// one block per item: rank-scan cnt (two-level shfl scan, padded LDS),
// locate targets, flag buckets (bit31), compact-scan flagged -> fbase.
__global__ void __launch_bounds__(1024) bplan_kernel(
    const u32* cnt, u32* fbase, const u32* Tbuf, u32* tb, u32* lrarr,
    Batch bt) {
  __shared__ u32 sBase[SIDX(2 * MAXNB)];   // 33792 u32 = 132KB (padded)
  __shared__ u32 wsum[16];
  const u32 MASK = 0x7fffffffu;
  const Item P = bt.it[blockIdx.x];
  int NB = P.NB, NB2 = 2 * NB;
  u32 n = P.n;
  const u32* cntp = cnt + P.cnt_off;
  int tid = threadIdx.x;
  int lane = tid & 63, wid = tid >> 6;
  int chunk = (NB2 + 1023) >> 10;
  int s = tid * chunk, e = s + chunk;
  if (e > NB2) e = NB2;
  if (s > NB2) s = NB2;
  // phase 1: exclusive scan of cnt into padded sBase (per-image adjusted)
  u32 own = 0;
  for (int i = s; i < e; i++) own += cntp[i];
  u32 incl = own;
  #pragma unroll
  for (int d = 1; d < 64; d <<= 1) {
    u32 v = __shfl_up(incl, d, 64);
    if (lane >= d) incl += v;
  }
  if (lane == 63) wsum[wid] = incl;
  __syncthreads();
  if (wid == 0) {
    u32 wv = (lane < 16) ? wsum[lane] : 0u;
    u32 wi = wv;
    #pragma unroll
    for (int d = 1; d < 16; d <<= 1) {
      u32 v = __shfl_up(wi, d, 64);
      if (lane >= d) wi += v;
    }
    if (lane < 16) wsum[lane] = wi - wv;   // exclusive wave offset
  }
  __syncthreads();
  u32 run = wsum[wid] + (incl - own);
  for (int i = s; i < e; i++) {
    sBase[SIDX(i)] = run - ((i >= NB) ? n : 0u);
    run += cntp[i];
  }
  __syncthreads();
  // phase 2: per-target binary search; flag bucket via bit31
  for (int r = tid; r < 8192; r += 1024) {
    int img = r >> 12;
    u32 t = P.first ? (u32)(r & 4095) : Tbuf[P.t_off + r];
    int base = img * NB;
    int lo = 0, hi = NB - 1;
    while (lo < hi) {
      int mid = (lo + hi + 1) >> 1;
      if ((sBase[SIDX(base + mid)] & MASK) <= t) lo = mid; else hi = mid - 1;
    }
    tb[P.t_off + r] = (u32)(base + lo);
    lrarr[P.t_off + r] = t - (sBase[SIDX(base + lo)] & MASK);
    atomicOr(&sBase[SIDX(base + lo)], 0x80000000u);
  }
  __syncthreads();
  // phase 3: compact exclusive scan over flagged bucket counts -> fbase
  u32 vs = 0;
  for (int i = s; i < e; i++) vs += (sBase[SIDX(i)] >> 31) ? cntp[i] : 0u;
  u32 vincl = vs;
  #pragma unroll
  for (int d = 1; d < 64; d <<= 1) {
    u32 v = __shfl_up(vincl, d, 64);
    if (lane >= d) vincl += v;
  }
  if (lane == 63) wsum[wid] = vincl;
  __syncthreads();
  if (wid == 0) {
    u32 wv = (lane < 16) ? wsum[lane] : 0u;
    u32 wi = wv;
    #pragma unroll
    for (int d = 1; d < 16; d <<= 1) {
      u32 v = __shfl_up(wi, d, 64);
      if (lane >= d) wi += v;
    }
    if (lane < 16) wsum[lane] = wi - wv;
  }
  __syncthreads();
  u32 run2 = wsum[wid] + (vincl - vs);
  for (int i = s; i < e; i++) {
    if (sBase[SIDX(i)] >> 31) {
      fbase[P.cnt_off + i] = run2;
      run2 += cntp[i];
    } else {
      fbase[P.cnt_off + i] = 0xFFFFFFFFu;
    }
  }
}

// scatter flagged-bucket elements to compact storage via LDS cursors only
__global__ void __launch_bounds__(1024, 8) bscatter_kernel(
    u64* rec, const u16* offT, const u32* fbase, const uint2* keytab,
    Batch bt) {
  __shared__ u32 cursor[MAXNB];
  int item = find_item_blk(bt, blockIdx.x);
  const Item P = bt.it[item];
  int blk = (int)blockIdx.x - (int)P.blk_start;
  int img = blockIdx.y;
  int NB2 = 2 * P.NB;
  const u16* orow = offT + P.hm_off + (size_t)blk * NB2 + (size_t)img * P.NB;
  const u32* frow = fbase + P.cnt_off + (size_t)img * P.NB;
  for (int b = threadIdx.x; b < P.NB; b += 1024) {
    u32 fb = frow[b];
    cursor[b] = (fb == 0xFFFFFFFFu) ? 0xFFFFFFFFu : P.rec_off + fb + orow[b];
  }
  __syncthreads();
  uint2 sk = keytab[P.sub_base + img * 3];
  u32 limit = P.rec_off + P.rec_cap;
  u32 q0 = (u32)blk * P.chunk, q1 = q0 + P.chunk;
  if (q1 > P.n) q1 = P.n;
  for (u32 q = q0 + threadIdx.x; q < q1; q += 1024) {
    u32 bits = sortbits(sk, q, P.n);
    u32 b = bits >> (32 - P.BB);
    if (cursor[b] != 0xFFFFFFFFu) {
      u32 slot = atomicAdd(&cursor[b], 1u);
      if (slot < limit) rec[slot] = ((u64)bits << 32) | (u64)q;
    }
  }
}

// wave-per-target rank find: 64-lane sub-radix (6 bits), shfl scan, no
// block-wide scans. 4 waves (targets) per 256-thread block.
__global__ void __launch_bounds__(256) brankfind_kernel(
    const u64* rec, const u32* tb, const u32* lrarr, const u32* fbase,
    const u32* cnt, u32* Tbuf, u32* idx, Batch bt) {
  __shared__ u64 kk[4][CAP];
  __shared__ u32 bins[4][64];
  __shared__ u32 cand[4][64];
  __shared__ u32 ncand_s[4];
  const Item P = bt.it[blockIdx.y];
  int w = threadIdx.x >> 6;       // wave id 0..3
  int lane = threadIdx.x & 63;
  int r = blockIdx.x * 4 + w;     // target id 0..8191
  u32 gb = tb[P.t_off + r];
  u32 lr = lrarr[P.t_off + r];
  u32 s0 = P.rec_off + fbase[P.cnt_off + gb];
  u32 m = cnt[P.cnt_off + gb];
  if (m > CAP) m = CAP;
  int shamt = 26 - P.BB;          // 6 sub-radix bits just below bucket bits
  bins[w][lane] = 0u;
  if (lane == 0) ncand_s[w] = 0u;
  for (u32 i = lane; i < m; i += 64) kk[w][i] = rec[s0 + i];
  __syncthreads();
  for (u32 i = lane; i < m; i += 64)
    atomicAdd(&bins[w][((u32)(kk[w][i] >> 32) >> shamt) & 63u], 1u);
  __syncthreads();
  // wave-inclusive scan of 64 bins (lane l holds bin l)
  u32 own = bins[w][lane];
  u32 incl = own;
  #pragma unroll
  for (int d = 1; d < 64; d <<= 1) {
    u32 v = __shfl_up(incl, d, 64);
    if (lane >= d) incl += v;
  }
  u32 excl = incl - own;
  u64 mask = __ballot(excl <= lr && lr < incl);
  int sb = __ffsll((long long)mask) - 1;
  u32 sexcl = __shfl(excl, sb, 64);
  u32 lr2 = lr - sexcl;
  // collect candidate indices (entries whose sub-bucket == sb)
  for (u32 i = lane; i < m; i += 64) {
    if ((((u32)(kk[w][i] >> 32) >> shamt) & 63u) == (u32)sb) {
      u32 pos = atomicAdd(&ncand_s[w], 1u);
      if (pos < 64u) cand[w][pos] = i;
    }
  }
  __syncthreads();
  u32 nc = ncand_s[w];
  if (nc > 64u) nc = 64u;
  u32* outp = P.out_is_idx ? (idx + P.out_off) : (Tbuf + P.t_off);
  if ((u32)lane < nc) {
    u64 me = kk[w][cand[w][lane]];
    u32 c = 0;
    for (u32 j = 0; j < nc; j++) c += (kk[w][cand[w][j]] < me) ? 1u : 0u;
    if (c == lr2) outp[r] = (u32)(me & 0xffffffffu);
  }
}

// gather sampled pixels (bilinear align_corners from 2048x2048 source)
__global__ void gather_kernel(const float* wimg, const float* timg,
                              const u32* idx, float* pix) {
  int t = blockIdx.x * blockDim.x + threadIdx.x;
  if (t >= 65536) return;
  int j = t & 4095;
  int img = (t >> 12) & 1;
  int l = t >> 13;
  int s = 16 << l;
  long long n = (long long)s * s;
  int M = (n < 4096) ? (int)n : 4096;
  if (j >= M) return;
  u32 p = (l < 3) ? (u32)j : idx[((l - 3) * 2 + img) * 4096 + j];
  const float* src = img ? timg : wimg;
  float o0, o1, o2;
  if (l == 7) {
    o0 = src[p];
    o1 = src[4194304 + p];
    o2 = src[8388608 + p];
  } else {
    u32 y = p / (u32)s, xq = p % (u32)s;
    float delta = 2047.0f / (float)(s - 1);
    float yc = (float)y * delta, xc = (float)xq * delta;
    int y0 = (int)floorf(yc); if (y0 > 2047) y0 = 2047;
    int x0 = (int)floorf(xc); if (x0 > 2047) x0 = 2047;
    int y1 = y0 + 1; if (y1 > 2047) y1 = 2047;
    int x1 = x0 + 1; if (x1 > 2047) x1 = 2047;
    float wy = yc - (float)y0, wx = xc - (float)x0;
    float out3[3];
    for (int c = 0; c < 3; c++) {
      const float* b = src + (size_t)c * 4194304;
      float v00 = b[y0 * 2048 + x0], v01 = b[y0 * 2048 + x1];
      float v10 = b[y1 * 2048 + x0], v11 = b[y1 * 2048 + x1];
      float r0 = v00 * (1.0f - wy) + v10 * wy;
      float r1 = v01 * (1.0f - wy) + v11 * wy;
      out3[c] = r0 * (1.0f - wx) + r1 * wx;
    }
    o0 = out3[0]; o1 = out3[1]; o2 = out3[2];
  }
  float* dst = pix + ((size_t)(l * 2 + img) * 4096 + j) * 3;
  dst[0] = o0; dst[1] = o1; dst[2] = o2;
}

// one block per (level, direction): project, bitonic sort, partial SSD.
// 1024 threads: 512 per array; j>=8 via LDS pair-steps, j=4,2,1 in registers.
__global__ void __launch_bounds__(1024) swd_kernel(
    const float* pix, const float* dirs, double* partials) {
  __shared__ float sw[4096];
  __shared__ float st[4096];
  __shared__ double wred[16];
  int b = blockIdx.x;
  int l = b >> 6, k = b & 63;
  int sdim = 16 << l;
  long long nn = (long long)sdim * sdim;
  int M = (nn < 4096) ? (int)nn : 4096;
  int tid = threadIdx.x;  // 1024
  int half = tid >> 9, t = tid & 511;
  float d0 = dirs[l * 192 + k * 3 + 0];
  float d1 = dirs[l * 192 + k * 3 + 1];
  float d2 = dirs[l * 192 + k * 3 + 2];
  float* A = half ? st : sw;
  const float* P = pix + (size_t)(l * 2 + half) * 4096 * 3;
  const float INF = __uint_as_float(0x7f800000u);
  for (int j = t; j < 4096; j += 512)
    A[j] = (j < M) ? (P[j * 3] * d0 + P[j * 3 + 1] * d1 + P[j * 3 + 2] * d2) : INF;
  __syncthreads();
#define CE(x, y, up) { if ((v[x] > v[y]) == (up)) { float tt = v[x]; v[x] = v[y]; v[y] = tt; } }
  for (u32 k2 = 2; k2 <= 4096; k2 <<= 1) {
    for (u32 j = k2 >> 1; j >= 8; j >>= 1) {
      for (u32 p = t; p < 2048; p += 512) {
        u32 i = ((p & ~(j - 1)) << 1) | (p & (j - 1));
        u32 ix = i | j;
        bool up = ((i & k2) == 0);
        float a = A[i], c = A[ix];
        if ((a > c) == up) { A[i] = c; A[ix] = a; }
      }
      __syncthreads();
    }
    // register tail: j = min(4, k2/2) .. 1; each thread owns 8 contiguous
    {
      u32 base = (u32)t * 8;
      float v[8];
      #pragma unroll
      for (int a = 0; a < 8; a++) v[a] = A[base + a];
      if (k2 == 2) {
        CE(0, 1, true) CE(2, 3, false) CE(4, 5, true) CE(6, 7, false)
      } else if (k2 == 4) {
        CE(0, 2, true) CE(1, 3, true) CE(4, 6, false) CE(5, 7, false)
        CE(0, 1, true) CE(2, 3, true) CE(4, 5, false) CE(6, 7, false)
      } else {
        bool up = ((base & k2) == 0);
        CE(0, 4, up) CE(1, 5, up) CE(2, 6, up) CE(3, 7, up)
        CE(0, 2, up) CE(1, 3, up) CE(4, 6, up) CE(5, 7, up)
        CE(0, 1, up) CE(2, 3, up) CE(4, 5, up) CE(6, 7, up)
      }
      #pragma unroll
      for (int a = 0; a < 8; a++) A[base + a] = v[a];
      __syncthreads();
    }
  }
#undef CE
  double sum = 0.0;
  if (half == 0) {
    for (int j = t; j < M; j += 512) {
      double df = (double)sw[j] - (double)st[j];
      sum += df * df;
    }
  }
  for (int off = 32; off >= 1; off >>= 1) sum += __shfl_down(sum, off);
  if ((tid & 63) == 0) wred[tid >> 6] = sum;
  __syncthreads();
  if (tid == 0) {
    double s2 = 0.0;
    for (int i = 0; i < 16; i++) s2 += wred[i];
    partials[b] = s2;
  }
}

__global__ void final_kernel(const double* partials, float* out) {
  if (threadIdx.x == 0 && blockIdx.x == 0) {
    double tot = 0.0;
    for (int l = 0; l < 8; l++) {
      int s = 16 << l;
      long long nn = (long long)s * s;
      int M = (nn < 4096) ? (int)nn : 4096;
      double sm = 0.0;
      for (int k = 0; k < 64; k++) sm += partials[l * 64 + k];
      tot += sm / (64.0 * (double)M);
    }
    out[0] = (float)tot;
  }
}

// ---------------- launch -----------------------------------------------------
extern "C" void kernel_launch(void* const* d_in, const int* in_sizes, int n_in,
                              void* d_out, int out_size, void* d_ws, size_t ws_size,
                              hipStream_t stream) {
  const float* wimg = (const float*)d_in[0];
  const float* timg = (const float*)d_in[1];
  float* out = (float*)d_out;
  char* ws = (char*)d_ws;

  // per-level static tables (lev 0..4 = pyramid levels 3..7)
  static const u32 Ln[5]    = {16384u, 65536u, 262144u, 1048576u, 4194304u};
  static const int LBB[5]   = {7, 9, 11, 13, 14};
  static const int LNB[5]   = {128, 512, 2048, 8192, 16384};
  static const int Lnblk[5] = {8, 16, 32, 64, 128};
  static const u32 Lhm[5]   = {0u, 2048u, 18432u, 149504u, 1198080u};    // u16 elems
  static const u32 Lcnt[5]  = {0u, 256u, 1280u, 5376u, 21760u};          // u32 elems
  static const u32 Lrec[5]  = {0u, 32768u, 163840u, 688128u, 1998848u};  // u64 elems
  static const u32 Lcap[5]  = {32768u, 131072u, 524288u, 1310720u, 2621440u};
  const u32 HM_TOTAL = 5392384u;   // Σ nblk*NB2
  const u32 CNT_TOTAL = 54528u;    // Σ NB2
  const u32 REC_TOTAL = 4620288u;  // Σ caps

  size_t off = 0;
  auto alloc = [&](size_t bytes) -> void* {
    void* p = ws + off;
    off = (off + bytes + 255) & ~(size_t)255;
    return p;
  };
  u64* rec     = (u64*)alloc((size_t)REC_TOTAL * 8);   // 36.96 MB
  u16* histmat = (u16*)alloc((size_t)HM_TOTAL * 2);    // 10.78 MB
  u16* offT    = (u16*)alloc((size_t)HM_TOTAL * 2);    // 10.78 MB
  u32* cnt     = (u32*)alloc((size_t)CNT_TOTAL * 4);
  u32* fbase   = (u32*)alloc((size_t)CNT_TOTAL * 4);
  uint2* keyt  = (uint2*)alloc(64 * 8);
  u32* T       = (u32*)alloc(5ull * 8192 * 4);
  u32* tb      = (u32*)alloc(5ull * 8192 * 4);
  u32* lrarr   = (u32*)alloc(5ull * 8192 * 4);
  u32* idx     = (u32*)alloc(5ull * 8192 * 4);
  float* pix   = (float*)alloc(8ull * 2 * 4096 * 3 * 4);
  float* dirs  = (float*)alloc(8ull * 64 * 3 * 4);
  double* part = (double*)alloc(512 * 8);
  (void)ws_size; (void)in_sizes; (void)n_in; (void)out_size;

  hipLaunchKernelGGL(setup_kernel, dim3(1), dim3(512), 0, stream, keyt, dirs);

  // 3 super-rounds; within each: bhist -> bcolscan -> bplan -> bscatter -> brankfind
  for (int sr = 0; sr < 3; sr++) {
    Batch bt;
    int m = 0;
    u32 bs = 0, cs = 0;
    for (int lev = 0; lev < 5; lev++) {
      int R = (lev == 4) ? 3 : 2;
      int jr = R - sr;
      if (jr < 1) continue;
      Item& I = bt.it[m++];
      I.n = Ln[lev]; I.chunk = Ln[lev] / (u32)Lnblk[lev];
      I.BB = LBB[lev]; I.NB = LNB[lev]; I.nblk = Lnblk[lev];
      I.hm_off = Lhm[lev]; I.cnt_off = Lcnt[lev];
      I.rec_off = Lrec[lev]; I.rec_cap = Lcap[lev];
      I.blk_start = bs; bs += (u32)Lnblk[lev];
      I.col_start = cs; cs += (u32)((2 * LNB[lev] + 255) / 256);
      I.sub_base = 8 + lev * 6 + (jr - 1);
      I.first = (jr == R) ? 1 : 0;
      I.out_is_idx = (jr == 1) ? 1 : 0;
      I.t_off = (u32)lev * 8192u;
      I.out_off = (u32)lev * 8192u;
    }
    bt.nitems = m;
    hipLaunchKernelGGL(bhist_kernel, dim3(bs, 2), dim3(1024), 0, stream,
                       histmat, keyt, bt);
    hipLaunchKernelGGL(bcolscan_kernel, dim3(cs), dim3(256), 0, stream,
                       histmat, offT, cnt, bt);
    hipLaunchKernelGGL(bplan_kernel, dim3(m), dim3(1024), 0, stream,
                       cnt, fbase, T, tb, lrarr, bt);
    hipLaunchKernelGGL(bscatter_kernel, dim3(bs, 2), dim3(1024), 0, stream,
                       rec, offT, fbase, keyt, bt);
    hipLaunchKernelGGL(brankfind_kernel, dim3(2048, m), dim3(256), 0, stream,
                       rec, tb, lrarr, fbase, cnt, T, idx, bt);
  }

  hipLaunchKernelGGL(gather_kernel, dim3(256), dim3(256), 0, stream,
                     wimg, timg, idx, pix);
  hipLaunchKernelGGL(swd_kernel, dim3(512), dim3(1024), 0, stream,
                     pix, dirs, part);
  hipLaunchKernelGGL(final_kernel, dim3(1), dim3(1), 0, stream, part, out);
}

// Round 8
// 617.210 us; speedup vs baseline: 6.5026x; 1.1608x over previous
//
#include <hip/hip_runtime.h>
#include <stdint.h>

// ============================================================================
// DistributionLoss: SWD pyramid loss, exact JAX-RNG replication.
// Round 8: bplan coalescing — cnt staged to LDS with coalesced loop; scan and
// compact-scan run from padded LDS in place; fbase written back coalescedly.
// Outputs bit-identical to round 7.
// ============================================================================
#define JAX_PARTITIONABLE 1

typedef unsigned int u32;
typedef unsigned short u16;
typedef unsigned long long u64;

#define CAP     512         // max bucket entries in rankfind
#define MAXNB   16384       // max buckets per image (64KB LDS)
#define SIDX(i) ((i) + ((i) >> 5))   // LDS pad map: +1 word per 32

// ---------------- threefry2x32 (20 rounds), matches jax exactly -------------
__device__ __forceinline__ uint2 tf2(uint2 k, u32 x0, u32 x1) {
  u32 ks0 = k.x, ks1 = k.y, ks2 = k.x ^ k.y ^ 0x1BD11BDAu;
  x0 += ks0; x1 += ks1;
#define TF_RND(R) { x0 += x1; x1 = (x1 << (R)) | (x1 >> (32 - (R))); x1 ^= x0; }
  TF_RND(13) TF_RND(15) TF_RND(26) TF_RND(6)
  x0 += ks1; x1 += ks2 + 1u;
  TF_RND(17) TF_RND(29) TF_RND(16) TF_RND(24)
  x0 += ks2; x1 += ks0 + 2u;
  TF_RND(13) TF_RND(15) TF_RND(26) TF_RND(6)
  x0 += ks0; x1 += ks1 + 3u;
  TF_RND(17) TF_RND(29) TF_RND(16) TF_RND(24)
  x0 += ks1; x1 += ks2 + 4u;
  TF_RND(13) TF_RND(15) TF_RND(26) TF_RND(6)
  x0 += ks2; x1 += ks0 + 5u;
#undef TF_RND
  return make_uint2(x0, x1);
}

__device__ inline void split3(uint2 k, uint2* a, uint2* b, uint2* c) {
#if JAX_PARTITIONABLE
  *a = tf2(k, 0u, 0u); *b = tf2(k, 0u, 1u); *c = tf2(k, 0u, 2u);
#else
  uint2 p0 = tf2(k, 0u, 3u), p1 = tf2(k, 1u, 4u), p2 = tf2(k, 2u, 5u);
  *a = make_uint2(p0.x, p1.x); *b = make_uint2(p2.x, p0.y); *c = make_uint2(p1.y, p2.y);
#endif
}
__device__ inline void split2(uint2 k, uint2* nk, uint2* sub) {
#if JAX_PARTITIONABLE
  *nk = tf2(k, 0u, 0u); *sub = tf2(k, 0u, 1u);
#else
  uint2 p0 = tf2(k, 0u, 2u), p1 = tf2(k, 1u, 3u);
  *nk = make_uint2(p0.x, p1.x); *sub = make_uint2(p0.y, p1.y);
#endif
}
__device__ inline u32 normbits(uint2 kd, u32 idx) {
#if JAX_PARTITIONABLE
  uint2 o = tf2(kd, 0u, idx); return o.x ^ o.y;
#else
  if (idx < 96u) return tf2(kd, idx, idx + 96u).x;
  return tf2(kd, idx - 96u, idx).y;
#endif
}
__device__ inline u32 sortbits(uint2 sk, u32 p, u32 n) {
#if JAX_PARTITIONABLE
  uint2 o = tf2(sk, 0u, p); return o.x ^ o.y;
#else
  u32 h = n >> 1;
  if (p < h) return tf2(sk, p, p + h).x;
  return tf2(sk, p - h, p).y;
#endif
}

// ---------------- erfinv ----------------------------------------------------
__device__ inline double erfinv_d(double x) {
  double w = -log1p(-x * x);
  double p;
  if (w < 5.0) {
    w -= 2.5;
    p = 2.81022636e-08;
    p = 3.43273939e-07 + p * w;
    p = -3.5233877e-06 + p * w;
    p = -4.39150654e-06 + p * w;
    p = 0.00021858087 + p * w;
    p = -0.00125372503 + p * w;
    p = -0.00417768164 + p * w;
    p = 0.246640727 + p * w;
    p = 1.50140941 + p * w;
  } else {
    w = sqrt(w) - 3.0;
    p = -0.000200214257;
    p = 0.000100950558 + p * w;
    p = 0.00134934322 + p * w;
    p = -0.00367342844 + p * w;
    p = 0.00573950773 + p * w;
    p = -0.0076224613 + p * w;
    p = 0.00943887047 + p * w;
    p = 1.00167406 + p * w;
    p = 2.83297682 + p * w;
  }
  double y = p * x;
  for (int it = 0; it < 2; ++it) {
    double e = erf(y) - x;
    y -= e * 0.88622692545275801364 * exp(y * y);
  }
  return y;
}

// ---------------- batched pipeline descriptors ------------------------------
struct Item {
  u32 n, chunk;
  int BB, NB, nblk;
  u32 hm_off;     // u16-element offset into histmat/offT
  u32 cnt_off;    // u32-element offset into cnt/fbase
  u32 rec_off;    // u64-element offset into rec
  u32 rec_cap;
  u32 blk_start;  // hist/scatter grid.x prefix
  u32 col_start;  // colscan grid.x prefix
  int sub_base;   // keytab index: 8 + lev*6 + (jr-1); +img*3 at runtime
  int first;      // targets are ranks 0..4095 (first round)
  int out_is_idx; // final round -> write idx, else write T
  u32 t_off;      // per-level offset into T/tb/lrarr (lev*8192)
  u32 out_off;    // per-level offset into idx (lev*8192)
};
struct Batch { int nitems; Item it[5]; };

__device__ inline int find_item_blk(const Batch& bt, u32 bx) {
  int it = 0;
  for (int i = 1; i < bt.nitems; i++) if (bx >= bt.it[i].blk_start) it = i;
  return it;
}
__device__ inline int find_item_col(const Batch& bt, u32 bx) {
  int it = 0;
  for (int i = 1; i < bt.nitems; i++) if (bx >= bt.it[i].col_start) it = i;
  return it;
}

// ---------------- kernels ---------------------------------------------------

// keytab: [0..7] kd per level; [8 + lev*6 + img*3 + (r-1)] sort subkeys.
// Also computes the 8*64 unit directions.
__global__ void __launch_bounds__(512) setup_kernel(uint2* keytab, float* dirs) {
  __shared__ uint2 kt[64];
  if (threadIdx.x == 0) {
    uint2 base = make_uint2(0u, 42u);
    for (int l = 0; l < 8; l++) {
      uint2 kl = tf2(base, 0u, (u32)l);
      uint2 kd, kw, kt3;
      split3(kl, &kd, &kw, &kt3);
      kt[l] = kd;
      if (l >= 3) {
        for (int img = 0; img < 2; img++) {
          uint2 kp = img ? kt3 : kw;
          for (int r = 0; r < 3; r++) {
            uint2 nk, sub;
            split2(kp, &nk, &sub);
            kt[8 + (l - 3) * 6 + img * 3 + r] = sub;
            kp = nk;
          }
        }
      }
    }
  }
  __syncthreads();
  if (threadIdx.x < 38) keytab[threadIdx.x] = kt[threadIdx.x];
  int t = threadIdx.x;  // 512 = 8 levels * 64 dirs
  int l = t >> 6, k = t & 63;
  uint2 kd = kt[l];
  const float lo = -0.9999999403953552f;
  float dv[3];
  for (int c = 0; c < 3; c++) {
    u32 bits = normbits(kd, (u32)(k * 3 + c));
    float f = __uint_as_float((bits >> 9) | 0x3f800000u) - 1.0f;
    float u = f * 2.0f + lo;
    if (u < lo) u = lo;
    dv[c] = 1.4142135f * (float)erfinv_d((double)u);
  }
  float nrm = sqrtf(dv[0] * dv[0] + dv[1] * dv[1] + dv[2] * dv[2]);
  for (int c = 0; c < 3; c++) dirs[l * 192 + k * 3 + c] = dv[c] / nrm;
}

// per-block LDS histogram, flushed to a private u16 row (no global atomics)
// 1024 threads (16 waves) -> 2 blocks/CU fills all 32 wave slots.
__global__ void __launch_bounds__(1024, 8) bhist_kernel(
    u16* histmat, const uint2* keytab, Batch bt) {
  __shared__ u32 lh[MAXNB];
  int item = find_item_blk(bt, blockIdx.x);
  const Item P = bt.it[item];
  int blk = (int)blockIdx.x - (int)P.blk_start;
  int img = blockIdx.y;
  for (int b = threadIdx.x; b < P.NB; b += 1024) lh[b] = 0u;
  __syncthreads();
  uint2 sk = keytab[P.sub_base + img * 3];
  u32 q0 = (u32)blk * P.chunk, q1 = q0 + P.chunk;
  if (q1 > P.n) q1 = P.n;
  for (u32 q = q0 + threadIdx.x; q < q1; q += 1024) {
    u32 b = sortbits(sk, q, P.n) >> (32 - P.BB);
    atomicAdd(&lh[b], 1u);
  }
  __syncthreads();
  u16* row = histmat + P.hm_off + ((size_t)blk * 2 + img) * P.NB;
  for (int b = threadIdx.x; b < P.NB; b += 1024) row[b] = (u16)lh[b];
}

// per-bucket exclusive scan across blocks -> offT (u16); totals -> cnt (u32)
__global__ void __launch_bounds__(256) bcolscan_kernel(
    const u16* histmat, u16* offT, u32* cnt, Batch bt) {
  int item = find_item_col(bt, blockIdx.x);
  const Item P = bt.it[item];
  int NB2 = 2 * P.NB;
  int gb = ((int)blockIdx.x - (int)P.col_start) * 256 + threadIdx.x;
  if (gb >= NB2) return;
  u32 run = 0;
  for (int blk = 0; blk < P.nblk; blk++) {
    size_t ix = P.hm_off + (size_t)blk * NB2 + gb;
    offT[ix] = (u16)run;
    run += histmat[ix];
  }
  cnt[P.cnt_off + gb] = run;
}

// one block per item: stage cnt->LDS (coalesced), rank-scan in LDS, locate
// targets, flag buckets (bit31), diff-based compact scan, coalesced fbase out.
__global__ void __launch_bounds__(1024) bplan_kernel(
    const u32* cnt, u32* fbase, const u32* Tbuf, u32* tb, u32* lrarr,
    Batch bt) {
  __shared__ u32 sBase[SIDX(2 * MAXNB)];   // 33792 u32 = 132KB (padded)
  __shared__ u32 wsum[16];
  const u32 MASK = 0x7fffffffu;
  const Item P = bt.it[blockIdx.x];
  int NB = P.NB, NB2 = 2 * NB;
  u32 n = P.n;
  const u32* cntp = cnt + P.cnt_off;
  int tid = threadIdx.x;
  int lane = tid & 63, wid = tid >> 6;
  int chunk = (NB2 + 1023) >> 10;
  int s = tid * chunk, e = s + chunk;
  if (e > NB2) e = NB2;
  if (s > NB2) s = NB2;
  // phase 0: coalesced stage of cnt into padded LDS
  for (int i = tid; i < NB2; i += 1024) sBase[SIDX(i)] = cntp[i];
  __syncthreads();
  // phase 1: per-thread chunk sums (LDS) + two-level shfl scan -> bases in place
  u32 own = 0;
  for (int i = s; i < e; i++) own += sBase[SIDX(i)];
  u32 incl = own;
  #pragma unroll
  for (int d = 1; d < 64; d <<= 1) {
    u32 v = __shfl_up(incl, d, 64);
    if (lane >= d) incl += v;
  }
  if (lane == 63) wsum[wid] = incl;
  __syncthreads();
  if (wid == 0) {
    u32 wv = (lane < 16) ? wsum[lane] : 0u;
    u32 wi = wv;
    #pragma unroll
    for (int d = 1; d < 16; d <<= 1) {
      u32 v = __shfl_up(wi, d, 64);
      if (lane >= d) wi += v;
    }
    if (lane < 16) wsum[lane] = wi - wv;   // exclusive wave offset
  }
  __syncthreads();
  u32 run = wsum[wid] + (incl - own);
  for (int i = s; i < e; i++) {
    u32 c = sBase[SIDX(i)];
    sBase[SIDX(i)] = run - ((i >= NB) ? n : 0u);
    run += c;
  }
  __syncthreads();
  // phase 2: per-target binary search; flag bucket via bit31
  for (int r = tid; r < 8192; r += 1024) {
    int img = r >> 12;
    u32 t = P.first ? (u32)(r & 4095) : Tbuf[P.t_off + r];
    int base = img * NB;
    int lo = 0, hi = NB - 1;
    while (lo < hi) {
      int mid = (lo + hi + 1) >> 1;
      if ((sBase[SIDX(base + mid)] & MASK) <= t) lo = mid; else hi = mid - 1;
    }
    tb[P.t_off + r] = (u32)(base + lo);
    lrarr[P.t_off + r] = t - (sBase[SIDX(base + lo)] & MASK);
    atomicOr(&sBase[SIDX(base + lo)], 0x80000000u);
  }
  __syncthreads();
  // phase 3: diff-based compact scan (cnt[i] = A[i+1]-A[i]); fbase via LDS.
  // boundary value read before any overwrite (barriers inside scan protect).
  u32 bvA;
  if (e < NB2) bvA = (sBase[SIDX(e)] & MASK) + ((e >= NB) ? n : 0u);
  else bvA = 2u * n;
  u32 vs = 0;
  for (int i = s; i < e; i++) {
    u32 st = sBase[SIDX(i)];
    u32 Ai = (st & MASK) + ((i >= NB) ? n : 0u);
    u32 Ai1 = (i == e - 1) ? bvA
              : ((sBase[SIDX(i + 1)] & MASK) + ((i + 1 >= NB) ? n : 0u));
    vs += (st >> 31) ? (Ai1 - Ai) : 0u;
  }
  u32 vincl = vs;
  #pragma unroll
  for (int d = 1; d < 64; d <<= 1) {
    u32 v = __shfl_up(vincl, d, 64);
    if (lane >= d) vincl += v;
  }
  if (lane == 63) wsum[wid] = vincl;
  __syncthreads();
  if (wid == 0) {
    u32 wv = (lane < 16) ? wsum[lane] : 0u;
    u32 wi = wv;
    #pragma unroll
    for (int d = 1; d < 16; d <<= 1) {
      u32 v = __shfl_up(wi, d, 64);
      if (lane >= d) wi += v;
    }
    if (lane < 16) wsum[lane] = wi - wv;
  }
  __syncthreads();
  u32 run2 = wsum[wid] + (vincl - vs);
  for (int i = s; i < e; i++) {
    u32 st = sBase[SIDX(i)];
    u32 Ai = (st & MASK) + ((i >= NB) ? n : 0u);
    u32 Ai1 = (i == e - 1) ? bvA
              : ((sBase[SIDX(i + 1)] & MASK) + ((i + 1 >= NB) ? n : 0u));
    u32 ci = Ai1 - Ai;
    if (st >> 31) {
      sBase[SIDX(i)] = run2;
      run2 += ci;
    } else {
      sBase[SIDX(i)] = 0xFFFFFFFFu;
    }
  }
  __syncthreads();
  // coalesced write-out
  for (int i = tid; i < NB2; i += 1024) fbase[P.cnt_off + i] = sBase[SIDX(i)];
}

// scatter flagged-bucket elements to compact storage via LDS cursors only
__global__ void __launch_bounds__(1024, 8) bscatter_kernel(
    u64* rec, const u16* offT, const u32* fbase, const uint2* keytab,
    Batch bt) {
  __shared__ u32 cursor[MAXNB];
  int item = find_item_blk(bt, blockIdx.x);
  const Item P = bt.it[item];
  int blk = (int)blockIdx.x - (int)P.blk_start;
  int img = blockIdx.y;
  int NB2 = 2 * P.NB;
  const u16* orow = offT + P.hm_off + (size_t)blk * NB2 + (size_t)img * P.NB;
  const u32* frow = fbase + P.cnt_off + (size_t)img * P.NB;
  for (int b = threadIdx.x; b < P.NB; b += 1024) {
    u32 fb = frow[b];
    cursor[b] = (fb == 0xFFFFFFFFu) ? 0xFFFFFFFFu : P.rec_off + fb + orow[b];
  }
  __syncthreads();
  uint2 sk = keytab[P.sub_base + img * 3];
  u32 limit = P.rec_off + P.rec_cap;
  u32 q0 = (u32)blk * P.chunk, q1 = q0 + P.chunk;
  if (q1 > P.n) q1 = P.n;
  for (u32 q = q0 + threadIdx.x; q < q1; q += 1024) {
    u32 bits = sortbits(sk, q, P.n);
    u32 b = bits >> (32 - P.BB);
    if (cursor[b] != 0xFFFFFFFFu) {
      u32 slot = atomicAdd(&cursor[b], 1u);
      if (slot < limit) rec[slot] = ((u64)bits << 32) | (u64)q;
    }
  }
}

// wave-per-target rank find: 64-lane sub-radix (6 bits), shfl scan, no
// block-wide scans. 4 waves (targets) per 256-thread block.
__global__ void __launch_bounds__(256) brankfind_kernel(
    const u64* rec, const u32* tb, const u32* lrarr, const u32* fbase,
    const u32* cnt, u32* Tbuf, u32* idx, Batch bt) {
  __shared__ u64 kk[4][CAP];
  __shared__ u32 bins[4][64];
  __shared__ u32 cand[4][64];
  __shared__ u32 ncand_s[4];
  const Item P = bt.it[blockIdx.y];
  int w = threadIdx.x >> 6;       // wave id 0..3
  int lane = threadIdx.x & 63;
  int r = blockIdx.x * 4 + w;     // target id 0..8191
  u32 gb = tb[P.t_off + r];
  u32 lr = lrarr[P.t_off + r];
  u32 s0 = P.rec_off + fbase[P.cnt_off + gb];
  u32 m = cnt[P.cnt_off + gb];
  if (m > CAP) m = CAP;
  int shamt = 26 - P.BB;          // 6 sub-radix bits just below bucket bits
  bins[w][lane] = 0u;
  if (lane == 0) ncand_s[w] = 0u;
  for (u32 i = lane; i < m; i += 64) kk[w][i] = rec[s0 + i];
  __syncthreads();
  for (u32 i = lane; i < m; i += 64)
    atomicAdd(&bins[w][((u32)(kk[w][i] >> 32) >> shamt) & 63u], 1u);
  __syncthreads();
  // wave-inclusive scan of 64 bins (lane l holds bin l)
  u32 own = bins[w][lane];
  u32 incl = own;
  #pragma unroll
  for (int d = 1; d < 64; d <<= 1) {
    u32 v = __shfl_up(incl, d, 64);
    if (lane >= d) incl += v;
  }
  u32 excl = incl - own;
  u64 mask = __ballot(excl <= lr && lr < incl);
  int sb = __ffsll((long long)mask) - 1;
  u32 sexcl = __shfl(excl, sb, 64);
  u32 lr2 = lr - sexcl;
  // collect candidate indices (entries whose sub-bucket == sb)
  for (u32 i = lane; i < m; i += 64) {
    if ((((u32)(kk[w][i] >> 32) >> shamt) & 63u) == (u32)sb) {
      u32 pos = atomicAdd(&ncand_s[w], 1u);
      if (pos < 64u) cand[w][pos] = i;
    }
  }
  __syncthreads();
  u32 nc = ncand_s[w];
  if (nc > 64u) nc = 64u;
  u32* outp = P.out_is_idx ? (idx + P.out_off) : (Tbuf + P.t_off);
  if ((u32)lane < nc) {
    u64 me = kk[w][cand[w][lane]];
    u32 c = 0;
    for (u32 j = 0; j < nc; j++) c += (kk[w][cand[w][j]] < me) ? 1u : 0u;
    if (c == lr2) outp[r] = (u32)(me & 0xffffffffu);
  }
}

// gather sampled pixels (bilinear align_corners from 2048x2048 source)
__global__ void gather_kernel(const float* wimg, const float* timg,
                              const u32* idx, float* pix) {
  int t = blockIdx.x * blockDim.x + threadIdx.x;
  if (t >= 65536) return;
  int j = t & 4095;
  int img = (t >> 12) & 1;
  int l = t >> 13;
  int s = 16 << l;
  long long n = (long long)s * s;
  int M = (n < 4096) ? (int)n : 4096;
  if (j >= M) return;
  u32 p = (l < 3) ? (u32)j : idx[((l - 3) * 2 + img) * 4096 + j];
  const float* src = img ? timg : wimg;
  float o0, o1, o2;
  if (l == 7) {
    o0 = src[p];
    o1 = src[4194304 + p];
    o2 = src[8388608 + p];
  } else {
    u32 y = p / (u32)s, xq = p % (u32)s;
    float delta = 2047.0f / (float)(s - 1);
    float yc = (float)y * delta, xc = (float)xq * delta;
    int y0 = (int)floorf(yc); if (y0 > 2047) y0 = 2047;
    int x0 = (int)floorf(xc); if (x0 > 2047) x0 = 2047;
    int y1 = y0 + 1; if (y1 > 2047) y1 = 2047;
    int x1 = x0 + 1; if (x1 > 2047) x1 = 2047;
    float wy = yc - (float)y0, wx = xc - (float)x0;
    float out3[3];
    for (int c = 0; c < 3; c++) {
      const float* b = src + (size_t)c * 4194304;
      float v00 = b[y0 * 2048 + x0], v01 = b[y0 * 2048 + x1];
      float v10 = b[y1 * 2048 + x0], v11 = b[y1 * 2048 + x1];
      float r0 = v00 * (1.0f - wy) + v10 * wy;
      float r1 = v01 * (1.0f - wy) + v11 * wy;
      out3[c] = r0 * (1.0f - wx) + r1 * wx;
    }
    o0 = out3[0]; o1 = out3[1]; o2 = out3[2];
  }
  float* dst = pix + ((size_t)(l * 2 + img) * 4096 + j) * 3;
  dst[0] = o0; dst[1] = o1; dst[2] = o2;
}

// one block per (level, direction): project, bitonic sort, partial SSD.
// 1024 threads: 512 per array; j>=8 via LDS pair-steps, j=4,2,1 in registers.
__global__ void __launch_bounds__(1024) swd_kernel(
    const float* pix, const float* dirs, double* partials) {
  __shared__ float sw[4096];
  __shared__ float st[4096];
  __shared__ double wred[16];
  int b = blockIdx.x;
  int l = b >> 6, k = b & 63;
  int sdim = 16 << l;
  long long nn = (long long)sdim * sdim;
  int M = (nn < 4096) ? (int)nn : 4096;
  int tid = threadIdx.x;  // 1024
  int half = tid >> 9, t = tid & 511;
  float d0 = dirs[l * 192 + k * 3 + 0];
  float d1 = dirs[l * 192 + k * 3 + 1];
  float d2 = dirs[l * 192 + k * 3 + 2];
  float* A = half ? st : sw;
  const float* P = pix + (size_t)(l * 2 + half) * 4096 * 3;
  const float INF = __uint_as_float(0x7f800000u);
  for (int j = t; j < 4096; j += 512)
    A[j] = (j < M) ? (P[j * 3] * d0 + P[j * 3 + 1] * d1 + P[j * 3 + 2] * d2) : INF;
  __syncthreads();
#define CE(x, y, up) { if ((v[x] > v[y]) == (up)) { float tt = v[x]; v[x] = v[y]; v[y] = tt; } }
  for (u32 k2 = 2; k2 <= 4096; k2 <<= 1) {
    for (u32 j = k2 >> 1; j >= 8; j >>= 1) {
      for (u32 p = t; p < 2048; p += 512) {
        u32 i = ((p & ~(j - 1)) << 1) | (p & (j - 1));
        u32 ix = i | j;
        bool up = ((i & k2) == 0);
        float a = A[i], c = A[ix];
        if ((a > c) == up) { A[i] = c; A[ix] = a; }
      }
      __syncthreads();
    }
    // register tail: j = min(4, k2/2) .. 1; each thread owns 8 contiguous
    {
      u32 base = (u32)t * 8;
      float v[8];
      #pragma unroll
      for (int a = 0; a < 8; a++) v[a] = A[base + a];
      if (k2 == 2) {
        CE(0, 1, true) CE(2, 3, false) CE(4, 5, true) CE(6, 7, false)
      } else if (k2 == 4) {
        CE(0, 2, true) CE(1, 3, true) CE(4, 6, false) CE(5, 7, false)
        CE(0, 1, true) CE(2, 3, true) CE(4, 5, false) CE(6, 7, false)
      } else {
        bool up = ((base & k2) == 0);
        CE(0, 4, up) CE(1, 5, up) CE(2, 6, up) CE(3, 7, up)
        CE(0, 2, up) CE(1, 3, up) CE(4, 6, up) CE(5, 7, up)
        CE(0, 1, up) CE(2, 3, up) CE(4, 5, up) CE(6, 7, up)
      }
      #pragma unroll
      for (int a = 0; a < 8; a++) A[base + a] = v[a];
      __syncthreads();
    }
  }
#undef CE
  double sum = 0.0;
  if (half == 0) {
    for (int j = t; j < M; j += 512) {
      double df = (double)sw[j] - (double)st[j];
      sum += df * df;
    }
  }
  for (int off = 32; off >= 1; off >>= 1) sum += __shfl_down(sum, off);
  if ((tid & 63) == 0) wred[tid >> 6] = sum;
  __syncthreads();
  if (tid == 0) {
    double s2 = 0.0;
    for (int i = 0; i < 16; i++) s2 += wred[i];
    partials[b] = s2;
  }
}

__global__ void final_kernel(const double* partials, float* out) {
  if (threadIdx.x == 0 && blockIdx.x == 0) {
    double tot = 0.0;
    for (int l = 0; l < 8; l++) {
      int s = 16 << l;
      long long nn = (long long)s * s;
      int M = (nn < 4096) ? (int)nn : 4096;
      double sm = 0.0;
      for (int k = 0; k < 64; k++) sm += partials[l * 64 + k];
      tot += sm / (64.0 * (double)M);
    }
    out[0] = (float)tot;
  }
}

// ---------------- launch -----------------------------------------------------
extern "C" void kernel_launch(void* const* d_in, const int* in_sizes, int n_in,
                              void* d_out, int out_size, void* d_ws, size_t ws_size,
                              hipStream_t stream) {
  const float* wimg = (const float*)d_in[0];
  const float* timg = (const float*)d_in[1];
  float* out = (float*)d_out;
  char* ws = (char*)d_ws;

  // per-level static tables (lev 0..4 = pyramid levels 3..7)
  static const u32 Ln[5]    = {16384u, 65536u, 262144u, 1048576u, 4194304u};
  static const int LBB[5]   = {7, 9, 11, 13, 14};
  static const int LNB[5]   = {128, 512, 2048, 8192, 16384};
  static const int Lnblk[5] = {8, 16, 32, 64, 128};
  static const u32 Lhm[5]   = {0u, 2048u, 18432u, 149504u, 1198080u};    // u16 elems
  static const u32 Lcnt[5]  = {0u, 256u, 1280u, 5376u, 21760u};          // u32 elems
  static const u32 Lrec[5]  = {0u, 32768u, 163840u, 688128u, 1998848u};  // u64 elems
  static const u32 Lcap[5]  = {32768u, 131072u, 524288u, 1310720u, 2621440u};
  const u32 HM_TOTAL = 5392384u;   // Σ nblk*NB2
  const u32 CNT_TOTAL = 54528u;    // Σ NB2
  const u32 REC_TOTAL = 4620288u;  // Σ caps

  size_t off = 0;
  auto alloc = [&](size_t bytes) -> void* {
    void* p = ws + off;
    off = (off + bytes + 255) & ~(size_t)255;
    return p;
  };
  u64* rec     = (u64*)alloc((size_t)REC_TOTAL * 8);   // 36.96 MB
  u16* histmat = (u16*)alloc((size_t)HM_TOTAL * 2);    // 10.78 MB
  u16* offT    = (u16*)alloc((size_t)HM_TOTAL * 2);    // 10.78 MB
  u32* cnt     = (u32*)alloc((size_t)CNT_TOTAL * 4);
  u32* fbase   = (u32*)alloc((size_t)CNT_TOTAL * 4);
  uint2* keyt  = (uint2*)alloc(64 * 8);
  u32* T       = (u32*)alloc(5ull * 8192 * 4);
  u32* tb      = (u32*)alloc(5ull * 8192 * 4);
  u32* lrarr   = (u32*)alloc(5ull * 8192 * 4);
  u32* idx     = (u32*)alloc(5ull * 8192 * 4);
  float* pix   = (float*)alloc(8ull * 2 * 4096 * 3 * 4);
  float* dirs  = (float*)alloc(8ull * 64 * 3 * 4);
  double* part = (double*)alloc(512 * 8);
  (void)ws_size; (void)in_sizes; (void)n_in; (void)out_size;

  hipLaunchKernelGGL(setup_kernel, dim3(1), dim3(512), 0, stream, keyt, dirs);

  // 3 super-rounds; within each: bhist -> bcolscan -> bplan -> bscatter -> brankfind
  for (int sr = 0; sr < 3; sr++) {
    Batch bt;
    int m = 0;
    u32 bs = 0, cs = 0;
    for (int lev = 0; lev < 5; lev++) {
      int R = (lev == 4) ? 3 : 2;
      int jr = R - sr;
      if (jr < 1) continue;
      Item& I = bt.it[m++];
      I.n = Ln[lev]; I.chunk = Ln[lev] / (u32)Lnblk[lev];
      I.BB = LBB[lev]; I.NB = LNB[lev]; I.nblk = Lnblk[lev];
      I.hm_off = Lhm[lev]; I.cnt_off = Lcnt[lev];
      I.rec_off = Lrec[lev]; I.rec_cap = Lcap[lev];
      I.blk_start = bs; bs += (u32)Lnblk[lev];
      I.col_start = cs; cs += (u32)((2 * LNB[lev] + 255) / 256);
      I.sub_base = 8 + lev * 6 + (jr - 1);
      I.first = (jr == R) ? 1 : 0;
      I.out_is_idx = (jr == 1) ? 1 : 0;
      I.t_off = (u32)lev * 8192u;
      I.out_off = (u32)lev * 8192u;
    }
    bt.nitems = m;
    hipLaunchKernelGGL(bhist_kernel, dim3(bs, 2), dim3(1024), 0, stream,
                       histmat, keyt, bt);
    hipLaunchKernelGGL(bcolscan_kernel, dim3(cs), dim3(256), 0, stream,
                       histmat, offT, cnt, bt);
    hipLaunchKernelGGL(bplan_kernel, dim3(m), dim3(1024), 0, stream,
                       cnt, fbase, T, tb, lrarr, bt);
    hipLaunchKernelGGL(bscatter_kernel, dim3(bs, 2), dim3(1024), 0, stream,
                       rec, offT, fbase, keyt, bt);
    hipLaunchKernelGGL(brankfind_kernel, dim3(2048, m), dim3(256), 0, stream,
                       rec, tb, lrarr, fbase, cnt, T, idx, bt);
  }

  hipLaunchKernelGGL(gather_kernel, dim3(256), dim3(256), 0, stream,
                     wimg, timg, idx, pix);
  hipLaunchKernelGGL(swd_kernel, dim3(512), dim3(1024), 0, stream,
                     pix, dirs, part);
  hipLaunchKernelGGL(final_kernel, dim3(1), dim3(1), 0, stream, part, out);
}

// Round 9
// 602.050 us; speedup vs baseline: 6.6663x; 1.0252x over previous
//
#include <hip/hip_runtime.h>
#include <stdint.h>

// ============================================================================
// DistributionLoss: SWD pyramid loss, exact JAX-RNG replication.
// Round 9: shfl-bitonic swd — 8 elems/thread in registers, j=8..256 via
// __shfl_xor (intra-wave), only j>=512 via padded LDS; S = M per level.
// Barriers ~57 -> ~11 per block, LDS bank conflicts eliminated.
// Selection pipeline unchanged from round 8.
// ============================================================================
#define JAX_PARTITIONABLE 1

typedef unsigned int u32;
typedef unsigned short u16;
typedef unsigned long long u64;

#define CAP     512         // max bucket entries in rankfind
#define MAXNB   16384       // max buckets per image (64KB LDS)
#define SIDX(i) ((i) + ((i) >> 5))   // LDS pad map: +1 word per 32
#define PIDX(i) ((i) + ((i) >> 3))   // swd pad map: +1 word per 8

// ---------------- threefry2x32 (20 rounds), matches jax exactly -------------
__device__ __forceinline__ uint2 tf2(uint2 k, u32 x0, u32 x1) {
  u32 ks0 = k.x, ks1 = k.y, ks2 = k.x ^ k.y ^ 0x1BD11BDAu;
  x0 += ks0; x1 += ks1;
#define TF_RND(R) { x0 += x1; x1 = (x1 << (R)) | (x1 >> (32 - (R))); x1 ^= x0; }
  TF_RND(13) TF_RND(15) TF_RND(26) TF_RND(6)
  x0 += ks1; x1 += ks2 + 1u;
  TF_RND(17) TF_RND(29) TF_RND(16) TF_RND(24)
  x0 += ks2; x1 += ks0 + 2u;
  TF_RND(13) TF_RND(15) TF_RND(26) TF_RND(6)
  x0 += ks0; x1 += ks1 + 3u;
  TF_RND(17) TF_RND(29) TF_RND(16) TF_RND(24)
  x0 += ks1; x1 += ks2 + 4u;
  TF_RND(13) TF_RND(15) TF_RND(26) TF_RND(6)
  x0 += ks2; x1 += ks0 + 5u;
#undef TF_RND
  return make_uint2(x0, x1);
}

__device__ inline void split3(uint2 k, uint2* a, uint2* b, uint2* c) {
#if JAX_PARTITIONABLE
  *a = tf2(k, 0u, 0u); *b = tf2(k, 0u, 1u); *c = tf2(k, 0u, 2u);
#else
  uint2 p0 = tf2(k, 0u, 3u), p1 = tf2(k, 1u, 4u), p2 = tf2(k, 2u, 5u);
  *a = make_uint2(p0.x, p1.x); *b = make_uint2(p2.x, p0.y); *c = make_uint2(p1.y, p2.y);
#endif
}
__device__ inline void split2(uint2 k, uint2* nk, uint2* sub) {
#if JAX_PARTITIONABLE
  *nk = tf2(k, 0u, 0u); *sub = tf2(k, 0u, 1u);
#else
  uint2 p0 = tf2(k, 0u, 2u), p1 = tf2(k, 1u, 3u);
  *nk = make_uint2(p0.x, p1.x); *sub = make_uint2(p0.y, p1.y);
#endif
}
__device__ inline u32 normbits(uint2 kd, u32 idx) {
#if JAX_PARTITIONABLE
  uint2 o = tf2(kd, 0u, idx); return o.x ^ o.y;
#else
  if (idx < 96u) return tf2(kd, idx, idx + 96u).x;
  return tf2(kd, idx - 96u, idx).y;
#endif
}
__device__ inline u32 sortbits(uint2 sk, u32 p, u32 n) {
#if JAX_PARTITIONABLE
  uint2 o = tf2(sk, 0u, p); return o.x ^ o.y;
#else
  u32 h = n >> 1;
  if (p < h) return tf2(sk, p, p + h).x;
  return tf2(sk, p - h, p).y;
#endif
}

// ---------------- erfinv ----------------------------------------------------
__device__ inline double erfinv_d(double x) {
  double w = -log1p(-x * x);
  double p;
  if (w < 5.0) {
    w -= 2.5;
    p = 2.81022636e-08;
    p = 3.43273939e-07 + p * w;
    p = -3.5233877e-06 + p * w;
    p = -4.39150654e-06 + p * w;
    p = 0.00021858087 + p * w;
    p = -0.00125372503 + p * w;
    p = -0.00417768164 + p * w;
    p = 0.246640727 + p * w;
    p = 1.50140941 + p * w;
  } else {
    w = sqrt(w) - 3.0;
    p = -0.000200214257;
    p = 0.000100950558 + p * w;
    p = 0.00134934322 + p * w;
    p = -0.00367342844 + p * w;
    p = 0.00573950773 + p * w;
    p = -0.0076224613 + p * w;
    p = 0.00943887047 + p * w;
    p = 1.00167406 + p * w;
    p = 2.83297682 + p * w;
  }
  double y = p * x;
  for (int it = 0; it < 2; ++it) {
    double e = erf(y) - x;
    y -= e * 0.88622692545275801364 * exp(y * y);
  }
  return y;
}

// ---------------- batched pipeline descriptors ------------------------------
struct Item {
  u32 n, chunk;
  int BB, NB, nblk;
  u32 hm_off;     // u16-element offset into histmat/offT
  u32 cnt_off;    // u32-element offset into cnt/fbase
  u32 rec_off;    // u64-element offset into rec
  u32 rec_cap;
  u32 blk_start;  // hist/scatter grid.x prefix
  u32 col_start;  // colscan grid.x prefix
  int sub_base;   // keytab index: 8 + lev*6 + (jr-1); +img*3 at runtime
  int first;      // targets are ranks 0..4095 (first round)
  int out_is_idx; // final round -> write idx, else write T
  u32 t_off;      // per-level offset into T/tb/lrarr (lev*8192)
  u32 out_off;    // per-level offset into idx (lev*8192)
};
struct Batch { int nitems; Item it[5]; };

__device__ inline int find_item_blk(const Batch& bt, u32 bx) {
  int it = 0;
  for (int i = 1; i < bt.nitems; i++) if (bx >= bt.it[i].blk_start) it = i;
  return it;
}
__device__ inline int find_item_col(const Batch& bt, u32 bx) {
  int it = 0;
  for (int i = 1; i < bt.nitems; i++) if (bx >= bt.it[i].col_start) it = i;
  return it;
}

// ---------------- kernels ---------------------------------------------------

// keytab: [0..7] kd per level; [8 + lev*6 + img*3 + (r-1)] sort subkeys.
// Also computes the 8*64 unit directions.
__global__ void __launch_bounds__(512) setup_kernel(uint2* keytab, float* dirs) {
  __shared__ uint2 kt[64];
  if (threadIdx.x == 0) {
    uint2 base = make_uint2(0u, 42u);
    for (int l = 0; l < 8; l++) {
      uint2 kl = tf2(base, 0u, (u32)l);
      uint2 kd, kw, kt3;
      split3(kl, &kd, &kw, &kt3);
      kt[l] = kd;
      if (l >= 3) {
        for (int img = 0; img < 2; img++) {
          uint2 kp = img ? kt3 : kw;
          for (int r = 0; r < 3; r++) {
            uint2 nk, sub;
            split2(kp, &nk, &sub);
            kt[8 + (l - 3) * 6 + img * 3 + r] = sub;
            kp = nk;
          }
        }
      }
    }
  }
  __syncthreads();
  if (threadIdx.x < 38) keytab[threadIdx.x] = kt[threadIdx.x];
  int t = threadIdx.x;  // 512 = 8 levels * 64 dirs
  int l = t >> 6, k = t & 63;
  uint2 kd = kt[l];
  const float lo = -0.9999999403953552f;
  float dv[3];
  for (int c = 0; c < 3; c++) {
    u32 bits = normbits(kd, (u32)(k * 3 + c));
    float f = __uint_as_float((bits >> 9) | 0x3f800000u) - 1.0f;
    float u = f * 2.0f + lo;
    if (u < lo) u = lo;
    dv[c] = 1.4142135f * (float)erfinv_d((double)u);
  }
  float nrm = sqrtf(dv[0] * dv[0] + dv[1] * dv[1] + dv[2] * dv[2]);
  for (int c = 0; c < 3; c++) dirs[l * 192 + k * 3 + c] = dv[c] / nrm;
}

// per-block LDS histogram, flushed to a private u16 row (no global atomics)
// 1024 threads (16 waves) -> 2 blocks/CU fills all 32 wave slots.
__global__ void __launch_bounds__(1024, 8) bhist_kernel(
    u16* histmat, const uint2* keytab, Batch bt) {
  __shared__ u32 lh[MAXNB];
  int item = find_item_blk(bt, blockIdx.x);
  const Item P = bt.it[item];
  int blk = (int)blockIdx.x - (int)P.blk_start;
  int img = blockIdx.y;
  for (int b = threadIdx.x; b < P.NB; b += 1024) lh[b] = 0u;
  __syncthreads();
  uint2 sk = keytab[P.sub_base + img * 3];
  u32 q0 = (u32)blk * P.chunk, q1 = q0 + P.chunk;
  if (q1 > P.n) q1 = P.n;
  for (u32 q = q0 + threadIdx.x; q < q1; q += 1024) {
    u32 b = sortbits(sk, q, P.n) >> (32 - P.BB);
    atomicAdd(&lh[b], 1u);
  }
  __syncthreads();
  u16* row = histmat + P.hm_off + ((size_t)blk * 2 + img) * P.NB;
  for (int b = threadIdx.x; b < P.NB; b += 1024) row[b] = (u16)lh[b];
}

// per-bucket exclusive scan across blocks -> offT (u16); totals -> cnt (u32)
__global__ void __launch_bounds__(256) bcolscan_kernel(
    const u16* histmat, u16* offT, u32* cnt, Batch bt) {
  int item = find_item_col(bt, blockIdx.x);
  const Item P = bt.it[item];
  int NB2 = 2 * P.NB;
  int gb = ((int)blockIdx.x - (int)P.col_start) * 256 + threadIdx.x;
  if (gb >= NB2) return;
  u32 run = 0;
  for (int blk = 0; blk < P.nblk; blk++) {
    size_t ix = P.hm_off + (size_t)blk * NB2 + gb;
    offT[ix] = (u16)run;
    run += histmat[ix];
  }
  cnt[P.cnt_off + gb] = run;
}

// one block per item: stage cnt->LDS (coalesced), rank-scan in LDS, locate
// targets, flag buckets (bit31), diff-based compact scan, coalesced fbase out.
__global__ void __launch_bounds__(1024) bplan_kernel(
    const u32* cnt, u32* fbase, const u32* Tbuf, u32* tb, u32* lrarr,
    Batch bt) {
  __shared__ u32 sBase[SIDX(2 * MAXNB)];   // 33792 u32 = 132KB (padded)
  __shared__ u32 wsum[16];
  const u32 MASK = 0x7fffffffu;
  const Item P = bt.it[blockIdx.x];
  int NB = P.NB, NB2 = 2 * NB;
  u32 n = P.n;
  const u32* cntp = cnt + P.cnt_off;
  int tid = threadIdx.x;
  int lane = tid & 63, wid = tid >> 6;
  int chunk = (NB2 + 1023) >> 10;
  int s = tid * chunk, e = s + chunk;
  if (e > NB2) e = NB2;
  if (s > NB2) s = NB2;
  // phase 0: coalesced stage of cnt into padded LDS
  for (int i = tid; i < NB2; i += 1024) sBase[SIDX(i)] = cntp[i];
  __syncthreads();
  // phase 1: per-thread chunk sums (LDS) + two-level shfl scan -> bases in place
  u32 own = 0;
  for (int i = s; i < e; i++) own += sBase[SIDX(i)];
  u32 incl = own;
  #pragma unroll
  for (int d = 1; d < 64; d <<= 1) {
    u32 v = __shfl_up(incl, d, 64);
    if (lane >= d) incl += v;
  }
  if (lane == 63) wsum[wid] = incl;
  __syncthreads();
  if (wid == 0) {
    u32 wv = (lane < 16) ? wsum[lane] : 0u;
    u32 wi = wv;
    #pragma unroll
    for (int d = 1; d < 16; d <<= 1) {
      u32 v = __shfl_up(wi, d, 64);
      if (lane >= d) wi += v;
    }
    if (lane < 16) wsum[lane] = wi - wv;   // exclusive wave offset
  }
  __syncthreads();
  u32 run = wsum[wid] + (incl - own);
  for (int i = s; i < e; i++) {
    u32 c = sBase[SIDX(i)];
    sBase[SIDX(i)] = run - ((i >= NB) ? n : 0u);
    run += c;
  }
  __syncthreads();
  // phase 2: per-target binary search; flag bucket via bit31
  for (int r = tid; r < 8192; r += 1024) {
    int img = r >> 12;
    u32 t = P.first ? (u32)(r & 4095) : Tbuf[P.t_off + r];
    int base = img * NB;
    int lo = 0, hi = NB - 1;
    while (lo < hi) {
      int mid = (lo + hi + 1) >> 1;
      if ((sBase[SIDX(base + mid)] & MASK) <= t) lo = mid; else hi = mid - 1;
    }
    tb[P.t_off + r] = (u32)(base + lo);
    lrarr[P.t_off + r] = t - (sBase[SIDX(base + lo)] & MASK);
    atomicOr(&sBase[SIDX(base + lo)], 0x80000000u);
  }
  __syncthreads();
  // phase 3: diff-based compact scan (cnt[i] = A[i+1]-A[i]); fbase via LDS.
  u32 bvA;
  if (e < NB2) bvA = (sBase[SIDX(e)] & MASK) + ((e >= NB) ? n : 0u);
  else bvA = 2u * n;
  u32 vs = 0;
  for (int i = s; i < e; i++) {
    u32 st = sBase[SIDX(i)];
    u32 Ai = (st & MASK) + ((i >= NB) ? n : 0u);
    u32 Ai1 = (i == e - 1) ? bvA
              : ((sBase[SIDX(i + 1)] & MASK) + ((i + 1 >= NB) ? n : 0u));
    vs += (st >> 31) ? (Ai1 - Ai) : 0u;
  }
  u32 vincl = vs;
  #pragma unroll
  for (int d = 1; d < 64; d <<= 1) {
    u32 v = __shfl_up(vincl, d, 64);
    if (lane >= d) vincl += v;
  }
  if (lane == 63) wsum[wid] = vincl;
  __syncthreads();
  if (wid == 0) {
    u32 wv = (lane < 16) ? wsum[lane] : 0u;
    u32 wi = wv;
    #pragma unroll
    for (int d = 1; d < 16; d <<= 1) {
      u32 v = __shfl_up(wi, d, 64);
      if (lane >= d) wi += v;
    }
    if (lane < 16) wsum[lane] = wi - wv;
  }
  __syncthreads();
  u32 run2 = wsum[wid] + (vincl - vs);
  for (int i = s; i < e; i++) {
    u32 st = sBase[SIDX(i)];
    u32 Ai = (st & MASK) + ((i >= NB) ? n : 0u);
    u32 Ai1 = (i == e - 1) ? bvA
              : ((sBase[SIDX(i + 1)] & MASK) + ((i + 1 >= NB) ? n : 0u));
    u32 ci = Ai1 - Ai;
    if (st >> 31) {
      sBase[SIDX(i)] = run2;
      run2 += ci;
    } else {
      sBase[SIDX(i)] = 0xFFFFFFFFu;
    }
  }
  __syncthreads();
  // coalesced write-out
  for (int i = tid; i < NB2; i += 1024) fbase[P.cnt_off + i] = sBase[SIDX(i)];
}

// scatter flagged-bucket elements to compact storage via LDS cursors only
__global__ void __launch_bounds__(1024, 8) bscatter_kernel(
    u64* rec, const u16* offT, const u32* fbase, const uint2* keytab,
    Batch bt) {
  __shared__ u32 cursor[MAXNB];
  int item = find_item_blk(bt, blockIdx.x);
  const Item P = bt.it[item];
  int blk = (int)blockIdx.x - (int)P.blk_start;
  int img = blockIdx.y;
  int NB2 = 2 * P.NB;
  const u16* orow = offT + P.hm_off + (size_t)blk * NB2 + (size_t)img * P.NB;
  const u32* frow = fbase + P.cnt_off + (size_t)img * P.NB;
  for (int b = threadIdx.x; b < P.NB; b += 1024) {
    u32 fb = frow[b];
    cursor[b] = (fb == 0xFFFFFFFFu) ? 0xFFFFFFFFu : P.rec_off + fb + orow[b];
  }
  __syncthreads();
  uint2 sk = keytab[P.sub_base + img * 3];
  u32 limit = P.rec_off + P.rec_cap;
  u32 q0 = (u32)blk * P.chunk, q1 = q0 + P.chunk;
  if (q1 > P.n) q1 = P.n;
  for (u32 q = q0 + threadIdx.x; q < q1; q += 1024) {
    u32 bits = sortbits(sk, q, P.n);
    u32 b = bits >> (32 - P.BB);
    if (cursor[b] != 0xFFFFFFFFu) {
      u32 slot = atomicAdd(&cursor[b], 1u);
      if (slot < limit) rec[slot] = ((u64)bits << 32) | (u64)q;
    }
  }
}

// wave-per-target rank find: 64-lane sub-radix (6 bits), shfl scan, no
// block-wide scans. 4 waves (targets) per 256-thread block.
__global__ void __launch_bounds__(256) brankfind_kernel(
    const u64* rec, const u32* tb, const u32* lrarr, const u32* fbase,
    const u32* cnt, u32* Tbuf, u32* idx, Batch bt) {
  __shared__ u64 kk[4][CAP];
  __shared__ u32 bins[4][64];
  __shared__ u32 cand[4][64];
  __shared__ u32 ncand_s[4];
  const Item P = bt.it[blockIdx.y];
  int w = threadIdx.x >> 6;       // wave id 0..3
  int lane = threadIdx.x & 63;
  int r = blockIdx.x * 4 + w;     // target id 0..8191
  u32 gb = tb[P.t_off + r];
  u32 lr = lrarr[P.t_off + r];
  u32 s0 = P.rec_off + fbase[P.cnt_off + gb];
  u32 m = cnt[P.cnt_off + gb];
  if (m > CAP) m = CAP;
  int shamt = 26 - P.BB;          // 6 sub-radix bits just below bucket bits
  bins[w][lane] = 0u;
  if (lane == 0) ncand_s[w] = 0u;
  for (u32 i = lane; i < m; i += 64) kk[w][i] = rec[s0 + i];
  __syncthreads();
  for (u32 i = lane; i < m; i += 64)
    atomicAdd(&bins[w][((u32)(kk[w][i] >> 32) >> shamt) & 63u], 1u);
  __syncthreads();
  // wave-inclusive scan of 64 bins (lane l holds bin l)
  u32 own = bins[w][lane];
  u32 incl = own;
  #pragma unroll
  for (int d = 1; d < 64; d <<= 1) {
    u32 v = __shfl_up(incl, d, 64);
    if (lane >= d) incl += v;
  }
  u32 excl = incl - own;
  u64 mask = __ballot(excl <= lr && lr < incl);
  int sb = __ffsll((long long)mask) - 1;
  u32 sexcl = __shfl(excl, sb, 64);
  u32 lr2 = lr - sexcl;
  // collect candidate indices (entries whose sub-bucket == sb)
  for (u32 i = lane; i < m; i += 64) {
    if ((((u32)(kk[w][i] >> 32) >> shamt) & 63u) == (u32)sb) {
      u32 pos = atomicAdd(&ncand_s[w], 1u);
      if (pos < 64u) cand[w][pos] = i;
    }
  }
  __syncthreads();
  u32 nc = ncand_s[w];
  if (nc > 64u) nc = 64u;
  u32* outp = P.out_is_idx ? (idx + P.out_off) : (Tbuf + P.t_off);
  if ((u32)lane < nc) {
    u64 me = kk[w][cand[w][lane]];
    u32 c = 0;
    for (u32 j = 0; j < nc; j++) c += (kk[w][cand[w][j]] < me) ? 1u : 0u;
    if (c == lr2) outp[r] = (u32)(me & 0xffffffffu);
  }
}

// gather sampled pixels (bilinear align_corners from 2048x2048 source)
__global__ void gather_kernel(const float* wimg, const float* timg,
                              const u32* idx, float* pix) {
  int t = blockIdx.x * blockDim.x + threadIdx.x;
  if (t >= 65536) return;
  int j = t & 4095;
  int img = (t >> 12) & 1;
  int l = t >> 13;
  int s = 16 << l;
  long long n = (long long)s * s;
  int M = (n < 4096) ? (int)n : 4096;
  if (j >= M) return;
  u32 p = (l < 3) ? (u32)j : idx[((l - 3) * 2 + img) * 4096 + j];
  const float* src = img ? timg : wimg;
  float o0, o1, o2;
  if (l == 7) {
    o0 = src[p];
    o1 = src[4194304 + p];
    o2 = src[8388608 + p];
  } else {
    u32 y = p / (u32)s, xq = p % (u32)s;
    float delta = 2047.0f / (float)(s - 1);
    float yc = (float)y * delta, xc = (float)xq * delta;
    int y0 = (int)floorf(yc); if (y0 > 2047) y0 = 2047;
    int x0 = (int)floorf(xc); if (x0 > 2047) x0 = 2047;
    int y1 = y0 + 1; if (y1 > 2047) y1 = 2047;
    int x1 = x0 + 1; if (x1 > 2047) x1 = 2047;
    float wy = yc - (float)y0, wx = xc - (float)x0;
    float out3[3];
    for (int c = 0; c < 3; c++) {
      const float* b = src + (size_t)c * 4194304;
      float v00 = b[y0 * 2048 + x0], v01 = b[y0 * 2048 + x1];
      float v10 = b[y1 * 2048 + x0], v11 = b[y1 * 2048 + x1];
      float r0 = v00 * (1.0f - wy) + v10 * wy;
      float r1 = v01 * (1.0f - wy) + v11 * wy;
      out3[c] = r0 * (1.0f - wx) + r1 * wx;
    }
    o0 = out3[0]; o1 = out3[1]; o2 = out3[2];
  }
  float* dst = pix + ((size_t)(l * 2 + img) * 4096 + j) * 3;
  dst[0] = o0; dst[1] = o1; dst[2] = o2;
}

// one block per (level, direction): shfl-bitonic sort of S=M elements,
// 8 elems/thread in registers; j=8..256 via shfl_xor, j>=512 via padded LDS.
__global__ void __launch_bounds__(1024) swd_kernel(
    const float* pix, const float* dirs, double* partials) {
  __shared__ float sw[PIDX(4096)];
  __shared__ float st[PIDX(4096)];
  __shared__ double wred[16];
  int b = blockIdx.x;
  int l = b >> 6, k = b & 63;
  int sdim = 16 << l;
  long long nn = (long long)sdim * sdim;
  u32 S = (nn < 4096) ? (u32)nn : 4096u;   // power of 2: 256/1024/4096
  int tid = threadIdx.x;  // 1024
  int half = tid >> 9, t = tid & 511;
  u32 tpa = S >> 3;                        // threads per array
  bool act = (u32)t < tpa;
  float d0 = dirs[l * 192 + k * 3 + 0];
  float d1 = dirs[l * 192 + k * 3 + 1];
  float d2 = dirs[l * 192 + k * 3 + 2];
  float* A = half ? st : sw;
  const float* P = pix + (size_t)(l * 2 + half) * 4096 * 3;
  float v[8];
  // load 8 projections directly into registers (coalesced 96B/thread)
  if (act) {
    const float* q = P + (size_t)t * 24;
    #pragma unroll
    for (int a = 0; a < 8; a++)
      v[a] = q[a * 3] * d0 + q[a * 3 + 1] * d1 + q[a * 3 + 2] * d2;
  }
#define CEV(x, y, up) { if ((v[x] > v[y]) == (up)) { float tt = v[x]; v[x] = v[y]; v[y] = tt; } }
  if (act) {
    // k2 = 2, 4, 8 fully in registers
    CEV(0, 1, true) CEV(2, 3, false) CEV(4, 5, true) CEV(6, 7, false)
    CEV(0, 2, true) CEV(1, 3, true) CEV(4, 6, false) CEV(5, 7, false)
    CEV(0, 1, true) CEV(2, 3, true) CEV(4, 5, false) CEV(6, 7, false)
    {
      bool up8 = ((t & 1) == 0);
      CEV(0, 4, up8) CEV(1, 5, up8) CEV(2, 6, up8) CEV(3, 7, up8)
      CEV(0, 2, up8) CEV(1, 3, up8) CEV(4, 6, up8) CEV(5, 7, up8)
      CEV(0, 1, up8) CEV(2, 3, up8) CEV(4, 5, up8) CEV(6, 7, up8)
    }
  }
  for (u32 k2 = 16; k2 <= S; k2 <<= 1) {
    u32 j = k2 >> 1;
    if (j >= 512) {
      if (act) {
        #pragma unroll
        for (int a = 0; a < 8; a++) A[PIDX(t * 8 + a)] = v[a];
      }
      __syncthreads();
      for (; j >= 512; j >>= 1) {
        if (act) {
          for (u32 p = (u32)t; p < (S >> 1); p += tpa) {
            u32 i = ((p & ~(j - 1)) << 1) | (p & (j - 1));
            u32 ix = i | j;
            bool up = ((i & k2) == 0);
            float a0 = A[PIDX(i)], c0 = A[PIDX(ix)];
            if ((a0 > c0) == up) { A[PIDX(i)] = c0; A[PIDX(ix)] = a0; }
          }
        }
        __syncthreads();
      }
      if (act) {
        #pragma unroll
        for (int a = 0; a < 8; a++) v[a] = A[PIDX(t * 8 + a)];
      }
    }
    bool up = ((((u32)t << 3) & k2) == 0);
    for (; j >= 8; j >>= 1) {
      u32 m = j >> 3;
      if (act) {
        bool lower = ((t & (int)m) == 0);
        #pragma unroll
        for (int a = 0; a < 8; a++) {
          float o = __shfl_xor(v[a], (int)m, 64);
          v[a] = (lower == up) ? fminf(v[a], o) : fmaxf(v[a], o);
        }
      }
    }
    if (act) {
      CEV(0, 4, up) CEV(1, 5, up) CEV(2, 6, up) CEV(3, 7, up)
      CEV(0, 2, up) CEV(1, 3, up) CEV(4, 6, up) CEV(5, 7, up)
      CEV(0, 1, up) CEV(2, 3, up) CEV(4, 5, up) CEV(6, 7, up)
    }
  }
#undef CEV
  // half 1 publishes sorted target values; half 0 computes SSD from regs
  __syncthreads();
  if (act && half == 1) {
    #pragma unroll
    for (int a = 0; a < 8; a++) st[PIDX(t * 8 + a)] = v[a];
  }
  __syncthreads();
  double sum = 0.0;
  if (act && half == 0) {
    #pragma unroll
    for (int a = 0; a < 8; a++) {
      double df = (double)v[a] - (double)st[PIDX(t * 8 + a)];
      sum += df * df;
    }
  }
  for (int off = 32; off >= 1; off >>= 1) sum += __shfl_down(sum, off);
  if ((tid & 63) == 0) wred[tid >> 6] = sum;
  __syncthreads();
  if (tid == 0) {
    double s2 = 0.0;
    for (int i = 0; i < 16; i++) s2 += wred[i];
    partials[b] = s2;
  }
}

__global__ void final_kernel(const double* partials, float* out) {
  if (threadIdx.x == 0 && blockIdx.x == 0) {
    double tot = 0.0;
    for (int l = 0; l < 8; l++) {
      int s = 16 << l;
      long long nn = (long long)s * s;
      int M = (nn < 4096) ? (int)nn : 4096;
      double sm = 0.0;
      for (int k = 0; k < 64; k++) sm += partials[l * 64 + k];
      tot += sm / (64.0 * (double)M);
    }
    out[0] = (float)tot;
  }
}

// ---------------- launch -----------------------------------------------------
extern "C" void kernel_launch(void* const* d_in, const int* in_sizes, int n_in,
                              void* d_out, int out_size, void* d_ws, size_t ws_size,
                              hipStream_t stream) {
  const float* wimg = (const float*)d_in[0];
  const float* timg = (const float*)d_in[1];
  float* out = (float*)d_out;
  char* ws = (char*)d_ws;

  // per-level static tables (lev 0..4 = pyramid levels 3..7)
  static const u32 Ln[5]    = {16384u, 65536u, 262144u, 1048576u, 4194304u};
  static const int LBB[5]   = {7, 9, 11, 13, 14};
  static const int LNB[5]   = {128, 512, 2048, 8192, 16384};
  static const int Lnblk[5] = {8, 16, 32, 64, 128};
  static const u32 Lhm[5]   = {0u, 2048u, 18432u, 149504u, 1198080u};    // u16 elems
  static const u32 Lcnt[5]  = {0u, 256u, 1280u, 5376u, 21760u};          // u32 elems
  static const u32 Lrec[5]  = {0u, 32768u, 163840u, 688128u, 1998848u};  // u64 elems
  static const u32 Lcap[5]  = {32768u, 131072u, 524288u, 1310720u, 2621440u};
  const u32 HM_TOTAL = 5392384u;   // Σ nblk*NB2
  const u32 CNT_TOTAL = 54528u;    // Σ NB2
  const u32 REC_TOTAL = 4620288u;  // Σ caps

  size_t off = 0;
  auto alloc = [&](size_t bytes) -> void* {
    void* p = ws + off;
    off = (off + bytes + 255) & ~(size_t)255;
    return p;
  };
  u64* rec     = (u64*)alloc((size_t)REC_TOTAL * 8);   // 36.96 MB
  u16* histmat = (u16*)alloc((size_t)HM_TOTAL * 2);    // 10.78 MB
  u16* offT    = (u16*)alloc((size_t)HM_TOTAL * 2);    // 10.78 MB
  u32* cnt     = (u32*)alloc((size_t)CNT_TOTAL * 4);
  u32* fbase   = (u32*)alloc((size_t)CNT_TOTAL * 4);
  uint2* keyt  = (uint2*)alloc(64 * 8);
  u32* T       = (u32*)alloc(5ull * 8192 * 4);
  u32* tb      = (u32*)alloc(5ull * 8192 * 4);
  u32* lrarr   = (u32*)alloc(5ull * 8192 * 4);
  u32* idx     = (u32*)alloc(5ull * 8192 * 4);
  float* pix   = (float*)alloc(8ull * 2 * 4096 * 3 * 4);
  float* dirs  = (float*)alloc(8ull * 64 * 3 * 4);
  double* part = (double*)alloc(512 * 8);
  (void)ws_size; (void)in_sizes; (void)n_in; (void)out_size;

  hipLaunchKernelGGL(setup_kernel, dim3(1), dim3(512), 0, stream, keyt, dirs);

  // 3 super-rounds; within each: bhist -> bcolscan -> bplan -> bscatter -> brankfind
  for (int sr = 0; sr < 3; sr++) {
    Batch bt;
    int m = 0;
    u32 bs = 0, cs = 0;
    for (int lev = 0; lev < 5; lev++) {
      int R = (lev == 4) ? 3 : 2;
      int jr = R - sr;
      if (jr < 1) continue;
      Item& I = bt.it[m++];
      I.n = Ln[lev]; I.chunk = Ln[lev] / (u32)Lnblk[lev];
      I.BB = LBB[lev]; I.NB = LNB[lev]; I.nblk = Lnblk[lev];
      I.hm_off = Lhm[lev]; I.cnt_off = Lcnt[lev];
      I.rec_off = Lrec[lev]; I.rec_cap = Lcap[lev];
      I.blk_start = bs; bs += (u32)Lnblk[lev];
      I.col_start = cs; cs += (u32)((2 * LNB[lev] + 255) / 256);
      I.sub_base = 8 + lev * 6 + (jr - 1);
      I.first = (jr == R) ? 1 : 0;
      I.out_is_idx = (jr == 1) ? 1 : 0;
      I.t_off = (u32)lev * 8192u;
      I.out_off = (u32)lev * 8192u;
    }
    bt.nitems = m;
    hipLaunchKernelGGL(bhist_kernel, dim3(bs, 2), dim3(1024), 0, stream,
                       histmat, keyt, bt);
    hipLaunchKernelGGL(bcolscan_kernel, dim3(cs), dim3(256), 0, stream,
                       histmat, offT, cnt, bt);
    hipLaunchKernelGGL(bplan_kernel, dim3(m), dim3(1024), 0, stream,
                       cnt, fbase, T, tb, lrarr, bt);
    hipLaunchKernelGGL(bscatter_kernel, dim3(bs, 2), dim3(1024), 0, stream,
                       rec, offT, fbase, keyt, bt);
    hipLaunchKernelGGL(brankfind_kernel, dim3(2048, m), dim3(256), 0, stream,
                       rec, tb, lrarr, fbase, cnt, T, idx, bt);
  }

  hipLaunchKernelGGL(gather_kernel, dim3(256), dim3(256), 0, stream,
                     wimg, timg, idx, pix);
  hipLaunchKernelGGL(swd_kernel, dim3(512), dim3(1024), 0, stream,
                     pix, dirs, part);
  hipLaunchKernelGGL(final_kernel, dim3(1), dim3(1), 0, stream, part, out);
}

// Round 10
// 598.926 us; speedup vs baseline: 6.7011x; 1.0052x over previous
//
#include <hip/hip_runtime.h>
#include <stdint.h>

// ============================================================================
// DistributionLoss: SWD pyramid loss, exact JAX-RNG replication.
// Round 10: u32 records (rankfind recomputes bits), coarse-chunk scatter
// (nblk/2 blocks, 2 fine chunks each -> longer per-bucket runs, less write
// amplification), per-image bplan (grid m x 2, per-image rec halves).
// ============================================================================
#define JAX_PARTITIONABLE 1

typedef unsigned int u32;
typedef unsigned short u16;
typedef unsigned long long u64;

#define CAP     512         // max bucket entries in rankfind
#define MAXNB   16384       // max buckets per image (64KB LDS)
#define SIDX(i) ((i) + ((i) >> 5))   // LDS pad map: +1 word per 32
#define PIDX(i) ((i) + ((i) >> 3))   // swd pad map: +1 word per 8

// ---------------- threefry2x32 (20 rounds), matches jax exactly -------------
__device__ __forceinline__ uint2 tf2(uint2 k, u32 x0, u32 x1) {
  u32 ks0 = k.x, ks1 = k.y, ks2 = k.x ^ k.y ^ 0x1BD11BDAu;
  x0 += ks0; x1 += ks1;
#define TF_RND(R) { x0 += x1; x1 = (x1 << (R)) | (x1 >> (32 - (R))); x1 ^= x0; }
  TF_RND(13) TF_RND(15) TF_RND(26) TF_RND(6)
  x0 += ks1; x1 += ks2 + 1u;
  TF_RND(17) TF_RND(29) TF_RND(16) TF_RND(24)
  x0 += ks2; x1 += ks0 + 2u;
  TF_RND(13) TF_RND(15) TF_RND(26) TF_RND(6)
  x0 += ks0; x1 += ks1 + 3u;
  TF_RND(17) TF_RND(29) TF_RND(16) TF_RND(24)
  x0 += ks1; x1 += ks2 + 4u;
  TF_RND(13) TF_RND(15) TF_RND(26) TF_RND(6)
  x0 += ks2; x1 += ks0 + 5u;
#undef TF_RND
  return make_uint2(x0, x1);
}

__device__ inline void split3(uint2 k, uint2* a, uint2* b, uint2* c) {
#if JAX_PARTITIONABLE
  *a = tf2(k, 0u, 0u); *b = tf2(k, 0u, 1u); *c = tf2(k, 0u, 2u);
#else
  uint2 p0 = tf2(k, 0u, 3u), p1 = tf2(k, 1u, 4u), p2 = tf2(k, 2u, 5u);
  *a = make_uint2(p0.x, p1.x); *b = make_uint2(p2.x, p0.y); *c = make_uint2(p1.y, p2.y);
#endif
}
__device__ inline void split2(uint2 k, uint2* nk, uint2* sub) {
#if JAX_PARTITIONABLE
  *nk = tf2(k, 0u, 0u); *sub = tf2(k, 0u, 1u);
#else
  uint2 p0 = tf2(k, 0u, 2u), p1 = tf2(k, 1u, 3u);
  *nk = make_uint2(p0.x, p1.x); *sub = make_uint2(p0.y, p1.y);
#endif
}
__device__ inline u32 normbits(uint2 kd, u32 idx) {
#if JAX_PARTITIONABLE
  uint2 o = tf2(kd, 0u, idx); return o.x ^ o.y;
#else
  if (idx < 96u) return tf2(kd, idx, idx + 96u).x;
  return tf2(kd, idx - 96u, idx).y;
#endif
}
__device__ inline u32 sortbits(uint2 sk, u32 p, u32 n) {
#if JAX_PARTITIONABLE
  uint2 o = tf2(sk, 0u, p); return o.x ^ o.y;
#else
  u32 h = n >> 1;
  if (p < h) return tf2(sk, p, p + h).x;
  return tf2(sk, p - h, p).y;
#endif
}

// ---------------- erfinv ----------------------------------------------------
__device__ inline double erfinv_d(double x) {
  double w = -log1p(-x * x);
  double p;
  if (w < 5.0) {
    w -= 2.5;
    p = 2.81022636e-08;
    p = 3.43273939e-07 + p * w;
    p = -3.5233877e-06 + p * w;
    p = -4.39150654e-06 + p * w;
    p = 0.00021858087 + p * w;
    p = -0.00125372503 + p * w;
    p = -0.00417768164 + p * w;
    p = 0.246640727 + p * w;
    p = 1.50140941 + p * w;
  } else {
    w = sqrt(w) - 3.0;
    p = -0.000200214257;
    p = 0.000100950558 + p * w;
    p = 0.00134934322 + p * w;
    p = -0.00367342844 + p * w;
    p = 0.00573950773 + p * w;
    p = -0.0076224613 + p * w;
    p = 0.00943887047 + p * w;
    p = 1.00167406 + p * w;
    p = 2.83297682 + p * w;
  }
  double y = p * x;
  for (int it = 0; it < 2; ++it) {
    double e = erf(y) - x;
    y -= e * 0.88622692545275801364 * exp(y * y);
  }
  return y;
}

// ---------------- batched pipeline descriptors ------------------------------
struct Item {
  u32 n, chunk;
  int BB, NB, nblk;
  u32 hm_off;     // u16-element offset into histmat/offT
  u32 cnt_off;    // u32-element offset into cnt/fbase
  u32 rec_off;    // u32-element offset into rec
  u32 rec_cap;    // total cap (both images); per-image = cap>>1
  u32 blk_start;  // bhist grid.x prefix (fine blocks)
  u32 sblk_start; // bscatter grid.x prefix (coarse blocks = nblk/2)
  u32 col_start;  // colscan grid.x prefix
  int sub_base;   // keytab index: 8 + lev*6 + (jr-1); +img*3 at runtime
  int first;      // targets are ranks 0..4095 (first round)
  int out_is_idx; // final round -> write idx, else write T
  u32 t_off;      // per-level offset into T/tb/lrarr (lev*8192)
  u32 out_off;    // per-level offset into idx (lev*8192)
};
struct Batch { int nitems; Item it[5]; };

__device__ inline int find_item_blk(const Batch& bt, u32 bx) {
  int it = 0;
  for (int i = 1; i < bt.nitems; i++) if (bx >= bt.it[i].blk_start) it = i;
  return it;
}
__device__ inline int find_item_sblk(const Batch& bt, u32 bx) {
  int it = 0;
  for (int i = 1; i < bt.nitems; i++) if (bx >= bt.it[i].sblk_start) it = i;
  return it;
}
__device__ inline int find_item_col(const Batch& bt, u32 bx) {
  int it = 0;
  for (int i = 1; i < bt.nitems; i++) if (bx >= bt.it[i].col_start) it = i;
  return it;
}

// ---------------- kernels ---------------------------------------------------

// keytab: [0..7] kd per level; [8 + lev*6 + img*3 + (r-1)] sort subkeys.
// Also computes the 8*64 unit directions.
__global__ void __launch_bounds__(512) setup_kernel(uint2* keytab, float* dirs) {
  __shared__ uint2 kt[64];
  if (threadIdx.x == 0) {
    uint2 base = make_uint2(0u, 42u);
    for (int l = 0; l < 8; l++) {
      uint2 kl = tf2(base, 0u, (u32)l);
      uint2 kd, kw, kt3;
      split3(kl, &kd, &kw, &kt3);
      kt[l] = kd;
      if (l >= 3) {
        for (int img = 0; img < 2; img++) {
          uint2 kp = img ? kt3 : kw;
          for (int r = 0; r < 3; r++) {
            uint2 nk, sub;
            split2(kp, &nk, &sub);
            kt[8 + (l - 3) * 6 + img * 3 + r] = sub;
            kp = nk;
          }
        }
      }
    }
  }
  __syncthreads();
  if (threadIdx.x < 38) keytab[threadIdx.x] = kt[threadIdx.x];
  int t = threadIdx.x;  // 512 = 8 levels * 64 dirs
  int l = t >> 6, k = t & 63;
  uint2 kd = kt[l];
  const float lo = -0.9999999403953552f;
  float dv[3];
  for (int c = 0; c < 3; c++) {
    u32 bits = normbits(kd, (u32)(k * 3 + c));
    float f = __uint_as_float((bits >> 9) | 0x3f800000u) - 1.0f;
    float u = f * 2.0f + lo;
    if (u < lo) u = lo;
    dv[c] = 1.4142135f * (float)erfinv_d((double)u);
  }
  float nrm = sqrtf(dv[0] * dv[0] + dv[1] * dv[1] + dv[2] * dv[2]);
  for (int c = 0; c < 3; c++) dirs[l * 192 + k * 3 + c] = dv[c] / nrm;
}

// per-block LDS histogram, flushed to a private u16 row (no global atomics)
__global__ void __launch_bounds__(1024, 8) bhist_kernel(
    u16* histmat, const uint2* keytab, Batch bt) {
  __shared__ u32 lh[MAXNB];
  int item = find_item_blk(bt, blockIdx.x);
  const Item P = bt.it[item];
  int blk = (int)blockIdx.x - (int)P.blk_start;
  int img = blockIdx.y;
  for (int b = threadIdx.x; b < P.NB; b += 1024) lh[b] = 0u;
  __syncthreads();
  uint2 sk = keytab[P.sub_base + img * 3];
  u32 q0 = (u32)blk * P.chunk, q1 = q0 + P.chunk;
  if (q1 > P.n) q1 = P.n;
  for (u32 q = q0 + threadIdx.x; q < q1; q += 1024) {
    u32 b = sortbits(sk, q, P.n) >> (32 - P.BB);
    atomicAdd(&lh[b], 1u);
  }
  __syncthreads();
  u16* row = histmat + P.hm_off + ((size_t)blk * 2 + img) * P.NB;
  for (int b = threadIdx.x; b < P.NB; b += 1024) row[b] = (u16)lh[b];
}

// per-bucket exclusive scan across blocks -> offT (u16); totals -> cnt (u32)
__global__ void __launch_bounds__(256) bcolscan_kernel(
    const u16* histmat, u16* offT, u32* cnt, Batch bt) {
  int item = find_item_col(bt, blockIdx.x);
  const Item P = bt.it[item];
  int NB2 = 2 * P.NB;
  int gb = ((int)blockIdx.x - (int)P.col_start) * 256 + threadIdx.x;
  if (gb >= NB2) return;
  u32 run = 0;
  for (int blk = 0; blk < P.nblk; blk++) {
    size_t ix = P.hm_off + (size_t)blk * NB2 + gb;
    offT[ix] = (u16)run;
    run += histmat[ix];
  }
  cnt[P.cnt_off + gb] = run;
}

// one block per (item, image): stage cnt->LDS, rank-scan, locate targets,
// flag buckets (bit31), diff-based compact scan (per-image rec half).
__global__ void __launch_bounds__(1024) bplan_kernel(
    const u32* cnt, u32* fbase, const u32* Tbuf, u32* tb, u32* lrarr,
    Batch bt) {
  __shared__ u32 sBase[SIDX(MAXNB)];   // 16896 u32 = 66KB (padded)
  __shared__ u32 wsum[16];
  const u32 MASK = 0x7fffffffu;
  const Item P = bt.it[blockIdx.x];
  int img = blockIdx.y;
  int NB = P.NB;
  u32 n = P.n;
  const u32* cntp = cnt + P.cnt_off + (size_t)img * NB;
  u32* fbp = fbase + P.cnt_off + (size_t)img * NB;
  int tid = threadIdx.x;
  int lane = tid & 63, wid = tid >> 6;
  int chunk = (NB + 1023) >> 10;
  int s = tid * chunk, e = s + chunk;
  if (e > NB) e = NB;
  if (s > NB) s = NB;
  // phase 0: coalesced stage of cnt into padded LDS
  for (int i = tid; i < NB; i += 1024) sBase[SIDX(i)] = cntp[i];
  __syncthreads();
  // phase 1: chunk sums + two-level shfl scan -> zero-based bases in place
  u32 own = 0;
  for (int i = s; i < e; i++) own += sBase[SIDX(i)];
  u32 incl = own;
  #pragma unroll
  for (int d = 1; d < 64; d <<= 1) {
    u32 v = __shfl_up(incl, d, 64);
    if (lane >= d) incl += v;
  }
  if (lane == 63) wsum[wid] = incl;
  __syncthreads();
  if (wid == 0) {
    u32 wv = (lane < 16) ? wsum[lane] : 0u;
    u32 wi = wv;
    #pragma unroll
    for (int d = 1; d < 16; d <<= 1) {
      u32 v = __shfl_up(wi, d, 64);
      if (lane >= d) wi += v;
    }
    if (lane < 16) wsum[lane] = wi - wv;   // exclusive wave offset
  }
  __syncthreads();
  u32 run = wsum[wid] + (incl - own);
  for (int i = s; i < e; i++) {
    u32 c = sBase[SIDX(i)];
    sBase[SIDX(i)] = run;
    run += c;
  }
  __syncthreads();
  // phase 2: per-target binary search (4096 targets of this image)
  for (int rl = tid; rl < 4096; rl += 1024) {
    int rg = img * 4096 + rl;
    u32 t = P.first ? (u32)rl : Tbuf[P.t_off + rg];
    int lo = 0, hi = NB - 1;
    while (lo < hi) {
      int mid = (lo + hi + 1) >> 1;
      if ((sBase[SIDX(mid)] & MASK) <= t) lo = mid; else hi = mid - 1;
    }
    tb[P.t_off + rg] = (u32)(img * NB + lo);
    lrarr[P.t_off + rg] = t - (sBase[SIDX(lo)] & MASK);
    atomicOr(&sBase[SIDX(lo)], 0x80000000u);
  }
  __syncthreads();
  // phase 3: diff-based compact scan (cnt[i] = A[i+1]-A[i]); img-local fbase
  u32 bvA = (e < NB) ? (sBase[SIDX(e)] & MASK) : n;
  u32 vs = 0;
  for (int i = s; i < e; i++) {
    u32 st = sBase[SIDX(i)];
    u32 Ai = st & MASK;
    u32 Ai1 = (i == e - 1) ? bvA : (sBase[SIDX(i + 1)] & MASK);
    vs += (st >> 31) ? (Ai1 - Ai) : 0u;
  }
  u32 vincl = vs;
  #pragma unroll
  for (int d = 1; d < 64; d <<= 1) {
    u32 v = __shfl_up(vincl, d, 64);
    if (lane >= d) vincl += v;
  }
  if (lane == 63) wsum[wid] = vincl;
  __syncthreads();
  if (wid == 0) {
    u32 wv = (lane < 16) ? wsum[lane] : 0u;
    u32 wi = wv;
    #pragma unroll
    for (int d = 1; d < 16; d <<= 1) {
      u32 v = __shfl_up(wi, d, 64);
      if (lane >= d) wi += v;
    }
    if (lane < 16) wsum[lane] = wi - wv;
  }
  __syncthreads();
  u32 run2 = wsum[wid] + (vincl - vs);
  for (int i = s; i < e; i++) {
    u32 st = sBase[SIDX(i)];
    u32 Ai = st & MASK;
    u32 Ai1 = (i == e - 1) ? bvA : (sBase[SIDX(i + 1)] & MASK);
    u32 ci = Ai1 - Ai;
    if (st >> 31) {
      sBase[SIDX(i)] = run2;
      run2 += ci;
    } else {
      sBase[SIDX(i)] = 0xFFFFFFFFu;
    }
  }
  __syncthreads();
  for (int i = tid; i < NB; i += 1024) fbp[i] = sBase[SIDX(i)];
}

// coarse-chunk scatter: each block covers 2 fine hist chunks; cursors seeded
// from offT at the fine boundary. Records are u32 (position only).
__global__ void __launch_bounds__(1024, 8) bscatter_kernel(
    u32* rec, const u16* offT, const u32* fbase, const uint2* keytab,
    Batch bt) {
  __shared__ u32 cursor[MAXNB];
  int item = find_item_sblk(bt, blockIdx.x);
  const Item P = bt.it[item];
  int cb = (int)blockIdx.x - (int)P.sblk_start;
  int img = blockIdx.y;
  int NB2 = 2 * P.NB;
  int fb0 = cb * 2;
  u32 recbase = P.rec_off + (u32)img * (P.rec_cap >> 1);
  const u16* orow = offT + P.hm_off + (size_t)fb0 * NB2 + (size_t)img * P.NB;
  const u32* frow = fbase + P.cnt_off + (size_t)img * P.NB;
  for (int b = threadIdx.x; b < P.NB; b += 1024) {
    u32 fb = frow[b];
    cursor[b] = (fb == 0xFFFFFFFFu) ? 0xFFFFFFFFu : recbase + fb + orow[b];
  }
  __syncthreads();
  uint2 sk = keytab[P.sub_base + img * 3];
  u32 limit = recbase + (P.rec_cap >> 1);
  u32 q0 = (u32)fb0 * P.chunk, q1 = q0 + 2u * P.chunk;
  if (q1 > P.n) q1 = P.n;
  for (u32 q = q0 + threadIdx.x; q < q1; q += 1024) {
    u32 bits = sortbits(sk, q, P.n);
    u32 b = bits >> (32 - P.BB);
    if (cursor[b] != 0xFFFFFFFFu) {
      u32 slot = atomicAdd(&cursor[b], 1u);
      if (slot < limit) rec[slot] = q;
    }
  }
}

// wave-per-target rank find: recompute bits from q; 64-bin sub-radix; shfl scan
__global__ void __launch_bounds__(256) brankfind_kernel(
    const u32* rec, const u32* tb, const u32* lrarr, const u32* fbase,
    const u32* cnt, const uint2* keytab, u32* Tbuf, u32* idx, Batch bt) {
  __shared__ u64 kk[4][CAP];
  __shared__ u32 bins[4][64];
  __shared__ u32 cand[4][64];
  __shared__ u32 ncand_s[4];
  const Item P = bt.it[blockIdx.y];
  int w = threadIdx.x >> 6;       // wave id 0..3
  int lane = threadIdx.x & 63;
  int r = blockIdx.x * 4 + w;     // target id 0..8191
  u32 gb = tb[P.t_off + r];
  u32 lr = lrarr[P.t_off + r];
  int img = (gb >= (u32)P.NB) ? 1 : 0;
  uint2 sk = keytab[P.sub_base + img * 3];
  u32 s0 = P.rec_off + (u32)img * (P.rec_cap >> 1) + fbase[P.cnt_off + gb];
  u32 m = cnt[P.cnt_off + gb];
  if (m > CAP) m = CAP;
  int shamt = 26 - P.BB;          // 6 sub-radix bits just below bucket bits
  bins[w][lane] = 0u;
  if (lane == 0) ncand_s[w] = 0u;
  for (u32 i = lane; i < m; i += 64) {
    u32 q = rec[s0 + i];
    kk[w][i] = ((u64)sortbits(sk, q, P.n) << 32) | (u64)q;
  }
  __syncthreads();
  for (u32 i = lane; i < m; i += 64)
    atomicAdd(&bins[w][((u32)(kk[w][i] >> 32) >> shamt) & 63u], 1u);
  __syncthreads();
  // wave-inclusive scan of 64 bins (lane l holds bin l)
  u32 own = bins[w][lane];
  u32 incl = own;
  #pragma unroll
  for (int d = 1; d < 64; d <<= 1) {
    u32 v = __shfl_up(incl, d, 64);
    if (lane >= d) incl += v;
  }
  u32 excl = incl - own;
  u64 mask = __ballot(excl <= lr && lr < incl);
  int sb = __ffsll((long long)mask) - 1;
  u32 sexcl = __shfl(excl, sb, 64);
  u32 lr2 = lr - sexcl;
  // collect candidate indices (entries whose sub-bucket == sb)
  for (u32 i = lane; i < m; i += 64) {
    if ((((u32)(kk[w][i] >> 32) >> shamt) & 63u) == (u32)sb) {
      u32 pos = atomicAdd(&ncand_s[w], 1u);
      if (pos < 64u) cand[w][pos] = i;
    }
  }
  __syncthreads();
  u32 nc = ncand_s[w];
  if (nc > 64u) nc = 64u;
  u32* outp = P.out_is_idx ? (idx + P.out_off) : (Tbuf + P.t_off);
  if ((u32)lane < nc) {
    u64 me = kk[w][cand[w][lane]];
    u32 c = 0;
    for (u32 j = 0; j < nc; j++) c += (kk[w][cand[w][j]] < me) ? 1u : 0u;
    if (c == lr2) outp[r] = (u32)(me & 0xffffffffu);
  }
}

// gather sampled pixels (bilinear align_corners from 2048x2048 source)
__global__ void gather_kernel(const float* wimg, const float* timg,
                              const u32* idx, float* pix) {
  int t = blockIdx.x * blockDim.x + threadIdx.x;
  if (t >= 65536) return;
  int j = t & 4095;
  int img = (t >> 12) & 1;
  int l = t >> 13;
  int s = 16 << l;
  long long n = (long long)s * s;
  int M = (n < 4096) ? (int)n : 4096;
  if (j >= M) return;
  u32 p = (l < 3) ? (u32)j : idx[((l - 3) * 2 + img) * 4096 + j];
  const float* src = img ? timg : wimg;
  float o0, o1, o2;
  if (l == 7) {
    o0 = src[p];
    o1 = src[4194304 + p];
    o2 = src[8388608 + p];
  } else {
    u32 y = p / (u32)s, xq = p % (u32)s;
    float delta = 2047.0f / (float)(s - 1);
    float yc = (float)y * delta, xc = (float)xq * delta;
    int y0 = (int)floorf(yc); if (y0 > 2047) y0 = 2047;
    int x0 = (int)floorf(xc); if (x0 > 2047) x0 = 2047;
    int y1 = y0 + 1; if (y1 > 2047) y1 = 2047;
    int x1 = x0 + 1; if (x1 > 2047) x1 = 2047;
    float wy = yc - (float)y0, wx = xc - (float)x0;
    float out3[3];
    for (int c = 0; c < 3; c++) {
      const float* b = src + (size_t)c * 4194304;
      float v00 = b[y0 * 2048 + x0], v01 = b[y0 * 2048 + x1];
      float v10 = b[y1 * 2048 + x0], v11 = b[y1 * 2048 + x1];
      float r0 = v00 * (1.0f - wy) + v10 * wy;
      float r1 = v01 * (1.0f - wy) + v11 * wy;
      out3[c] = r0 * (1.0f - wx) + r1 * wx;
    }
    o0 = out3[0]; o1 = out3[1]; o2 = out3[2];
  }
  float* dst = pix + ((size_t)(l * 2 + img) * 4096 + j) * 3;
  dst[0] = o0; dst[1] = o1; dst[2] = o2;
}

// one block per (level, direction): shfl-bitonic sort of S=M elements,
// 8 elems/thread in registers; j=8..256 via shfl_xor, j>=512 via padded LDS.
__global__ void __launch_bounds__(1024) swd_kernel(
    const float* pix, const float* dirs, double* partials) {
  __shared__ float sw[PIDX(4096)];
  __shared__ float st[PIDX(4096)];
  __shared__ double wred[16];
  int b = blockIdx.x;
  int l = b >> 6, k = b & 63;
  int sdim = 16 << l;
  long long nn = (long long)sdim * sdim;
  u32 S = (nn < 4096) ? (u32)nn : 4096u;   // power of 2: 256/1024/4096
  int tid = threadIdx.x;  // 1024
  int half = tid >> 9, t = tid & 511;
  u32 tpa = S >> 3;                        // threads per array
  bool act = (u32)t < tpa;
  float d0 = dirs[l * 192 + k * 3 + 0];
  float d1 = dirs[l * 192 + k * 3 + 1];
  float d2 = dirs[l * 192 + k * 3 + 2];
  float* A = half ? st : sw;
  const float* P = pix + (size_t)(l * 2 + half) * 4096 * 3;
  float v[8];
  if (act) {
    const float* q = P + (size_t)t * 24;
    #pragma unroll
    for (int a = 0; a < 8; a++)
      v[a] = q[a * 3] * d0 + q[a * 3 + 1] * d1 + q[a * 3 + 2] * d2;
  }
#define CEV(x, y, up) { if ((v[x] > v[y]) == (up)) { float tt = v[x]; v[x] = v[y]; v[y] = tt; } }
  if (act) {
    CEV(0, 1, true) CEV(2, 3, false) CEV(4, 5, true) CEV(6, 7, false)
    CEV(0, 2, true) CEV(1, 3, true) CEV(4, 6, false) CEV(5, 7, false)
    CEV(0, 1, true) CEV(2, 3, true) CEV(4, 5, false) CEV(6, 7, false)
    {
      bool up8 = ((t & 1) == 0);
      CEV(0, 4, up8) CEV(1, 5, up8) CEV(2, 6, up8) CEV(3, 7, up8)
      CEV(0, 2, up8) CEV(1, 3, up8) CEV(4, 6, up8) CEV(5, 7, up8)
      CEV(0, 1, up8) CEV(2, 3, up8) CEV(4, 5, up8) CEV(6, 7, up8)
    }
  }
  for (u32 k2 = 16; k2 <= S; k2 <<= 1) {
    u32 j = k2 >> 1;
    if (j >= 512) {
      if (act) {
        #pragma unroll
        for (int a = 0; a < 8; a++) A[PIDX(t * 8 + a)] = v[a];
      }
      __syncthreads();
      for (; j >= 512; j >>= 1) {
        if (act) {
          for (u32 p = (u32)t; p < (S >> 1); p += tpa) {
            u32 i = ((p & ~(j - 1)) << 1) | (p & (j - 1));
            u32 ix = i | j;
            bool up = ((i & k2) == 0);
            float a0 = A[PIDX(i)], c0 = A[PIDX(ix)];
            if ((a0 > c0) == up) { A[PIDX(i)] = c0; A[PIDX(ix)] = a0; }
          }
        }
        __syncthreads();
      }
      if (act) {
        #pragma unroll
        for (int a = 0; a < 8; a++) v[a] = A[PIDX(t * 8 + a)];
      }
    }
    bool up = ((((u32)t << 3) & k2) == 0);
    for (; j >= 8; j >>= 1) {
      u32 m = j >> 3;
      if (act) {
        bool lower = ((t & (int)m) == 0);
        #pragma unroll
        for (int a = 0; a < 8; a++) {
          float o = __shfl_xor(v[a], (int)m, 64);
          v[a] = (lower == up) ? fminf(v[a], o) : fmaxf(v[a], o);
        }
      }
    }
    if (act) {
      CEV(0, 4, up) CEV(1, 5, up) CEV(2, 6, up) CEV(3, 7, up)
      CEV(0, 2, up) CEV(1, 3, up) CEV(4, 6, up) CEV(5, 7, up)
      CEV(0, 1, up) CEV(2, 3, up) CEV(4, 5, up) CEV(6, 7, up)
    }
  }
#undef CEV
  __syncthreads();
  if (act && half == 1) {
    #pragma unroll
    for (int a = 0; a < 8; a++) st[PIDX(t * 8 + a)] = v[a];
  }
  __syncthreads();
  double sum = 0.0;
  if (act && half == 0) {
    #pragma unroll
    for (int a = 0; a < 8; a++) {
      double df = (double)v[a] - (double)st[PIDX(t * 8 + a)];
      sum += df * df;
    }
  }
  for (int off = 32; off >= 1; off >>= 1) sum += __shfl_down(sum, off);
  if ((tid & 63) == 0) wred[tid >> 6] = sum;
  __syncthreads();
  if (tid == 0) {
    double s2 = 0.0;
    for (int i = 0; i < 16; i++) s2 += wred[i];
    partials[b] = s2;
  }
}

__global__ void final_kernel(const double* partials, float* out) {
  if (threadIdx.x == 0 && blockIdx.x == 0) {
    double tot = 0.0;
    for (int l = 0; l < 8; l++) {
      int s = 16 << l;
      long long nn = (long long)s * s;
      int M = (nn < 4096) ? (int)nn : 4096;
      double sm = 0.0;
      for (int k = 0; k < 64; k++) sm += partials[l * 64 + k];
      tot += sm / (64.0 * (double)M);
    }
    out[0] = (float)tot;
  }
}

// ---------------- launch -----------------------------------------------------
extern "C" void kernel_launch(void* const* d_in, const int* in_sizes, int n_in,
                              void* d_out, int out_size, void* d_ws, size_t ws_size,
                              hipStream_t stream) {
  const float* wimg = (const float*)d_in[0];
  const float* timg = (const float*)d_in[1];
  float* out = (float*)d_out;
  char* ws = (char*)d_ws;

  // per-level static tables (lev 0..4 = pyramid levels 3..7)
  static const u32 Ln[5]    = {16384u, 65536u, 262144u, 1048576u, 4194304u};
  static const int LBB[5]   = {7, 9, 11, 13, 14};
  static const int LNB[5]   = {128, 512, 2048, 8192, 16384};
  static const int Lnblk[5] = {8, 16, 32, 64, 128};
  static const u32 Lhm[5]   = {0u, 2048u, 18432u, 149504u, 1198080u};    // u16 elems
  static const u32 Lcnt[5]  = {0u, 256u, 1280u, 5376u, 21760u};          // u32 elems
  static const u32 Lrec[5]  = {0u, 32768u, 163840u, 688128u, 1998848u};  // u32 elems
  static const u32 Lcap[5]  = {32768u, 131072u, 524288u, 1310720u, 2621440u};
  const u32 HM_TOTAL = 5392384u;   // Σ nblk*NB2
  const u32 CNT_TOTAL = 54528u;    // Σ NB2
  const u32 REC_TOTAL = 4620288u;  // Σ caps

  size_t off = 0;
  auto alloc = [&](size_t bytes) -> void* {
    void* p = ws + off;
    off = (off + bytes + 255) & ~(size_t)255;
    return p;
  };
  u32* rec     = (u32*)alloc((size_t)REC_TOTAL * 4);   // 18.5 MB
  u16* histmat = (u16*)alloc((size_t)HM_TOTAL * 2);    // 10.78 MB
  u16* offT    = (u16*)alloc((size_t)HM_TOTAL * 2);    // 10.78 MB
  u32* cnt     = (u32*)alloc((size_t)CNT_TOTAL * 4);
  u32* fbase   = (u32*)alloc((size_t)CNT_TOTAL * 4);
  uint2* keyt  = (uint2*)alloc(64 * 8);
  u32* T       = (u32*)alloc(5ull * 8192 * 4);
  u32* tb      = (u32*)alloc(5ull * 8192 * 4);
  u32* lrarr   = (u32*)alloc(5ull * 8192 * 4);
  u32* idx     = (u32*)alloc(5ull * 8192 * 4);
  float* pix   = (float*)alloc(8ull * 2 * 4096 * 3 * 4);
  float* dirs  = (float*)alloc(8ull * 64 * 3 * 4);
  double* part = (double*)alloc(512 * 8);
  (void)ws_size; (void)in_sizes; (void)n_in; (void)out_size;

  hipLaunchKernelGGL(setup_kernel, dim3(1), dim3(512), 0, stream, keyt, dirs);

  // 3 super-rounds; within each: bhist -> bcolscan -> bplan -> bscatter -> brankfind
  for (int sr = 0; sr < 3; sr++) {
    Batch bt;
    int m = 0;
    u32 bs = 0, bs2 = 0, cs = 0;
    for (int lev = 0; lev < 5; lev++) {
      int R = (lev == 4) ? 3 : 2;
      int jr = R - sr;
      if (jr < 1) continue;
      Item& I = bt.it[m++];
      I.n = Ln[lev]; I.chunk = Ln[lev] / (u32)Lnblk[lev];
      I.BB = LBB[lev]; I.NB = LNB[lev]; I.nblk = Lnblk[lev];
      I.hm_off = Lhm[lev]; I.cnt_off = Lcnt[lev];
      I.rec_off = Lrec[lev]; I.rec_cap = Lcap[lev];
      I.blk_start = bs; bs += (u32)Lnblk[lev];
      I.sblk_start = bs2; bs2 += (u32)(Lnblk[lev] >> 1);
      I.col_start = cs; cs += (u32)((2 * LNB[lev] + 255) / 256);
      I.sub_base = 8 + lev * 6 + (jr - 1);
      I.first = (jr == R) ? 1 : 0;
      I.out_is_idx = (jr == 1) ? 1 : 0;
      I.t_off = (u32)lev * 8192u;
      I.out_off = (u32)lev * 8192u;
    }
    bt.nitems = m;
    hipLaunchKernelGGL(bhist_kernel, dim3(bs, 2), dim3(1024), 0, stream,
                       histmat, keyt, bt);
    hipLaunchKernelGGL(bcolscan_kernel, dim3(cs), dim3(256), 0, stream,
                       histmat, offT, cnt, bt);
    hipLaunchKernelGGL(bplan_kernel, dim3(m, 2), dim3(1024), 0, stream,
                       cnt, fbase, T, tb, lrarr, bt);
    hipLaunchKernelGGL(bscatter_kernel, dim3(bs2, 2), dim3(1024), 0, stream,
                       rec, offT, fbase, keyt, bt);
    hipLaunchKernelGGL(brankfind_kernel, dim3(2048, m), dim3(256), 0, stream,
                       rec, tb, lrarr, fbase, cnt, keyt, T, idx, bt);
  }

  hipLaunchKernelGGL(gather_kernel, dim3(256), dim3(256), 0, stream,
                     wimg, timg, idx, pix);
  hipLaunchKernelGGL(swd_kernel, dim3(512), dim3(1024), 0, stream,
                     pix, dirs, part);
  hipLaunchKernelGGL(final_kernel, dim3(1), dim3(1), 0, stream, part, out);
}